// Round 10
// baseline (1089.639 us; speedup 1.0000x reference)
//
#include <hip/hip_runtime.h>
#include <hip/hip_bf16.h>

// Problem constants (RWKV-7 Tmix: B=2, T=1024, C=2048, H=32, N=64)
#define BB 2
#define TT 1024
#define CC 2048
#define HH 32
#define BT 2048          // BB*TT tokens
#define GN_EPS 6.4e-4f   // 1e-5 * 8^2

typedef __attribute__((ext_vector_type(8))) __bf16 bf16x8;
typedef __attribute__((ext_vector_type(4))) float f32x4;

__device__ __forceinline__ float sigf(float x) { return 1.0f / (1.0f + expf(-x)); }

__device__ __forceinline__ void split_bf16(float x, __hip_bfloat16& hi, __hip_bfloat16& lo) {
  __hip_bfloat16 h = __float2bfloat16(x);
  hi = h;
  lo = __float2bfloat16(x - __bfloat162float(h));
}

// Sum over each aligned 16-lane group, pure DPP (no LDS pipe on the chain).
__device__ __forceinline__ float red16(float x) {
  x += __int_as_float(__builtin_amdgcn_update_dpp(
      0, __float_as_int(x), 0xB1 /*quad_perm [1,0,3,2]*/, 0xF, 0xF, true));
  x += __int_as_float(__builtin_amdgcn_update_dpp(
      0, __float_as_int(x), 0x4E /*quad_perm [2,3,0,1]*/, 0xF, 0xF, true));
  x += __int_as_float(__builtin_amdgcn_update_dpp(
      0, __float_as_int(x), 0x141 /*row_half_mirror*/, 0xF, 0xF, true));
  x += __int_as_float(__builtin_amdgcn_update_dpp(
      0, __float_as_int(x), 0x140 /*row_mirror*/, 0xF, 0xF, true));
  return x;
}

// ---------------------------------------------------------------------------
// K1: token shift + six lerped projections. r/k/v hi+lo split; w/a/g bf16.
// ---------------------------------------------------------------------------
__global__ __launch_bounds__(256) void k_prepx(
    const float* __restrict__ hid, const float* __restrict__ shift,
    const float* __restrict__ xrc, const float* __restrict__ xwc,
    const float* __restrict__ xkc, const float* __restrict__ xvc,
    const float* __restrict__ xac, const float* __restrict__ xgc,
    __hip_bfloat16* __restrict__ xrh, __hip_bfloat16* __restrict__ xrl,
    __hip_bfloat16* __restrict__ xw,
    __hip_bfloat16* __restrict__ xkh, __hip_bfloat16* __restrict__ xkl,
    __hip_bfloat16* __restrict__ xvh, __hip_bfloat16* __restrict__ xvl,
    __hip_bfloat16* __restrict__ xa, __hip_bfloat16* __restrict__ xg) {
  int idx = blockIdx.x * 256 + threadIdx.x;   // < BT*CC
  int c  = idx & (CC - 1);
  int bt = idx >> 11;
  int t  = bt & (TT - 1);
  int b  = bt >> 10;
  float hcur  = hid[idx];
  float hprev = (t == 0) ? shift[b * CC + c] : hid[idx - CC];
  float xx = hprev - hcur;
  split_bf16(fmaf(xx, xrc[c], hcur), xrh[idx], xrl[idx]);
  split_bf16(fmaf(xx, xkc[c], hcur), xkh[idx], xkl[idx]);
  split_bf16(fmaf(xx, xvc[c], hcur), xvh[idx], xvl[idx]);
  xw[idx] = __float2bfloat16(fmaf(xx, xwc[c], hcur));
  xa[idx] = __float2bfloat16(fmaf(xx, xac[c], hcur));
  xg[idx] = __float2bfloat16(fmaf(xx, xgc[c], hcur));
}

// ---------------------------------------------------------------------------
// K2: f32 -> hi+lo bf16 split (for Wr/Wk/Wv/Wo)
// ---------------------------------------------------------------------------
__global__ __launch_bounds__(256) void k_cvt2(const float* __restrict__ in,
                                              __hip_bfloat16* __restrict__ oh,
                                              __hip_bfloat16* __restrict__ ol) {
  int i = blockIdx.x * 256 + threadIdx.x;
  split_bf16(in[i], oh[i], ol[i]);
}

// ---------------------------------------------------------------------------
// K3: transpose-convert small LoRA "up" weights: in [2048][N0] f32 ->
//     out [NP][2048] bf16 (rows >= N0 zero-padded).  (stage-1 B operands)
// ---------------------------------------------------------------------------
__global__ __launch_bounds__(256) void k_tr(const float* __restrict__ in,
                                            __hip_bfloat16* __restrict__ out,
                                            int N0) {
  int i = blockIdx.x * 256 + threadIdx.x;   // over NP*2048, grid exact
  int n = i >> 11;
  int k = i & 2047;
  float v = (n < N0) ? in[k * N0 + n] : 0.0f;
  out[i] = __float2bfloat16(v);
}

// ---------------------------------------------------------------------------
// K3b: transpose + hi/lo split of stage-2 "down" weights:
//   in [N0][CC] f32 -> out [CC][K0] bf16 hi+lo (K0 = 1<<lgK, rows>=N0 zero).
// ---------------------------------------------------------------------------
__global__ __launch_bounds__(256) void k_trs(const float* __restrict__ in,
                                             __hip_bfloat16* __restrict__ oh,
                                             __hip_bfloat16* __restrict__ ol,
                                             int N0, int lgK) {
  int i = blockIdx.x * 256 + threadIdx.x;   // over CC*K0, grid exact
  int n = i >> lgK;
  int k = i & ((1 << lgK) - 1);
  float v = (k < N0) ? in[k * CC + n] : 0.0f;
  split_bf16(v, oh[i], ol[i]);
}

// ---------------------------------------------------------------------------
// K4: plain bf16 MFMA GEMM, C[M,N] f32 = A[M,K] @ B[N,K]^T  (stage-1 LoRA)
// (direct loads; tiny grids, not the bottleneck)
// ---------------------------------------------------------------------------
__global__ __launch_bounds__(256) void k_gemm_bt(
    const __hip_bfloat16* __restrict__ A, const __hip_bfloat16* __restrict__ Bm,
    float* __restrict__ Cm, int M, int Nn, int K) {
  int tid  = threadIdx.x;
  int lane = tid & 63;
  int wv   = tid >> 6;
  int l15  = lane & 15;
  int quad = lane >> 4;
  int m0 = blockIdx.x * 128 + wv * 32;
  int n0 = blockIdx.y * 64;
  const __hip_bfloat16* ap0 = A + (size_t)(m0 + l15) * K + quad * 8;
  const __hip_bfloat16* ap1 = ap0 + (size_t)16 * K;
  const __hip_bfloat16* bp  = Bm + (size_t)(n0 + l15) * K + quad * 8;
  f32x4 z = {0.f, 0.f, 0.f, 0.f};
  f32x4 c00 = z, c01 = z, c02 = z, c03 = z;
  f32x4 c10 = z, c11 = z, c12 = z, c13 = z;
  for (int k0 = 0; k0 < K; k0 += 32) {
    bf16x8 a0v = *(const bf16x8*)(ap0 + k0);
    bf16x8 a1v = *(const bf16x8*)(ap1 + k0);
    bf16x8 b0v = *(const bf16x8*)(bp + k0);
    bf16x8 b1v = *(const bf16x8*)(bp + (size_t)16 * K + k0);
    bf16x8 b2v = *(const bf16x8*)(bp + (size_t)32 * K + k0);
    bf16x8 b3v = *(const bf16x8*)(bp + (size_t)48 * K + k0);
    c00 = __builtin_amdgcn_mfma_f32_16x16x32_bf16(a0v, b0v, c00, 0, 0, 0);
    c01 = __builtin_amdgcn_mfma_f32_16x16x32_bf16(a0v, b1v, c01, 0, 0, 0);
    c02 = __builtin_amdgcn_mfma_f32_16x16x32_bf16(a0v, b2v, c02, 0, 0, 0);
    c03 = __builtin_amdgcn_mfma_f32_16x16x32_bf16(a0v, b3v, c03, 0, 0, 0);
    c10 = __builtin_amdgcn_mfma_f32_16x16x32_bf16(a1v, b0v, c10, 0, 0, 0);
    c11 = __builtin_amdgcn_mfma_f32_16x16x32_bf16(a1v, b1v, c11, 0, 0, 0);
    c12 = __builtin_amdgcn_mfma_f32_16x16x32_bf16(a1v, b2v, c12, 0, 0, 0);
    c13 = __builtin_amdgcn_mfma_f32_16x16x32_bf16(a1v, b3v, c13, 0, 0, 0);
  }
  int colb = n0 + l15;
  int row0 = m0 + quad * 4;
#pragma unroll
  for (int r = 0; r < 4; ++r) {
    Cm[(size_t)(row0 + r) * Nn + colb +  0] = c00[r];
    Cm[(size_t)(row0 + r) * Nn + colb + 16] = c01[r];
    Cm[(size_t)(row0 + r) * Nn + colb + 32] = c02[r];
    Cm[(size_t)(row0 + r) * Nn + colb + 48] = c03[r];
    Cm[(size_t)(row0 + 16 + r) * Nn + colb +  0] = c10[r];
    Cm[(size_t)(row0 + 16 + r) * Nn + colb + 16] = c11[r];
    Cm[(size_t)(row0 + 16 + r) * Nn + colb + 32] = c12[r];
    Cm[(size_t)(row0 + 16 + r) * Nn + colb + 48] = c13[r];
  }
}

// ---------------------------------------------------------------------------
// K4b: split-precision GEMM — ROUND-17: 2-PHASE double-buffered LDS staging.
// Round-9's 1-phase (stage -> sync(vmcnt0 drain) -> compute -> sync) exposed
// the full DMA latency every K-step with 2 barriers per 12 MFMAs (MfmaUtil
// 11%). T3-minimum recipe: issue STAGE for the NEXT tile first, compute the
// CURRENT tile, then ONE __syncthreads — its implicit vmcnt(0)+lgkm drain
// lands after ~250cy of ds_read+MFMA, hiding the DMA flight, and it
// simultaneously certifies buf^1 ready and buf safe to overwrite.
// Tile 64x64, BK=32, 4 waves, 2x16KB LDS -> 4 blocks/CU.
// ---------------------------------------------------------------------------
__global__ __launch_bounds__(256, 4) void k_gemm_bt3(
    const __hip_bfloat16* __restrict__ Ah, const __hip_bfloat16* __restrict__ Al,
    const __hip_bfloat16* __restrict__ Bh, const __hip_bfloat16* __restrict__ Bl,
    float* __restrict__ Cm, int M, int Nn, int K) {
  __shared__ __align__(16) __hip_bfloat16 sAh[2][64 * 32], sAl[2][64 * 32];
  __shared__ __align__(16) __hip_bfloat16 sBh[2][64 * 32], sBl[2][64 * 32];
  int tid  = threadIdx.x;
  int lane = tid & 63;
  int wv   = tid >> 6;
  int l15  = lane & 15;
  int quad = lane >> 4;
  int m0 = blockIdx.x * 64;
  int n0 = blockIdx.y * 64;

  // staging: wave wv fills rows wv*16..+15 of each [64][32] tile.
  // lane l: row = wv*16 + (l>>2), col-group = (l&3)*8. DMA dest is
  // wave-uniform base + lane*16 == linear [row][col] layout (r9-verified).
  int srow = wv * 16 + (lane >> 2);
  int scol = (lane & 3) * 8;
  const __hip_bfloat16* gAh = Ah + (size_t)(m0 + srow) * K + scol;
  const __hip_bfloat16* gAl = Al + (size_t)(m0 + srow) * K + scol;
  const __hip_bfloat16* gBh = Bh + (size_t)(n0 + srow) * K + scol;
  const __hip_bfloat16* gBl = Bl + (size_t)(n0 + srow) * K + scol;

  f32x4 z = {0.f, 0.f, 0.f, 0.f};
  f32x4 acc0 = z, acc1 = z, acc2 = z, acc3 = z;

  int aoff = (wv * 16 + l15) * 32 + quad * 8;   // A-frag element offset
  int boff = l15 * 32 + quad * 8;               // B-frag j=0 offset (+16*32/j)

#define STAGE(BUF, KO)                                                       \
  { unsigned db_ = (unsigned)(BUF) * 4096u + (unsigned)wv * 1024u;           \
    __builtin_amdgcn_global_load_lds(                                        \
        (const __attribute__((address_space(1))) void*)(gAh + (KO)),         \
        (__attribute__((address_space(3))) void*)((char*)sAh + db_), 16, 0, 0);\
    __builtin_amdgcn_global_load_lds(                                        \
        (const __attribute__((address_space(1))) void*)(gAl + (KO)),         \
        (__attribute__((address_space(3))) void*)((char*)sAl + db_), 16, 0, 0);\
    __builtin_amdgcn_global_load_lds(                                        \
        (const __attribute__((address_space(1))) void*)(gBh + (KO)),         \
        (__attribute__((address_space(3))) void*)((char*)sBh + db_), 16, 0, 0);\
    __builtin_amdgcn_global_load_lds(                                        \
        (const __attribute__((address_space(1))) void*)(gBl + (KO)),         \
        (__attribute__((address_space(3))) void*)((char*)sBl + db_), 16, 0, 0);}

  STAGE(0, 0)
  __syncthreads();   // buf0 staged (implicit vmcnt(0) drain before barrier)

  for (int k0 = 0; k0 < K; k0 += 32) {
    int cur = (k0 >> 5) & 1;
    if (k0 + 32 < K) STAGE(cur ^ 1, k0 + 32)   // next tile in flight NOW

    const __hip_bfloat16* pA_h = &sAh[cur][0];
    const __hip_bfloat16* pA_l = &sAl[cur][0];
    const __hip_bfloat16* pB_h = &sBh[cur][0];
    const __hip_bfloat16* pB_l = &sBl[cur][0];
    bf16x8 ah = *(const bf16x8*)(pA_h + aoff);
    bf16x8 al = *(const bf16x8*)(pA_l + aoff);
    bf16x8 bh0 = *(const bf16x8*)(pB_h + boff);
    bf16x8 bh1 = *(const bf16x8*)(pB_h + boff + 16 * 32);
    bf16x8 bh2 = *(const bf16x8*)(pB_h + boff + 32 * 32);
    bf16x8 bh3 = *(const bf16x8*)(pB_h + boff + 48 * 32);
    bf16x8 bl0 = *(const bf16x8*)(pB_l + boff);
    bf16x8 bl1 = *(const bf16x8*)(pB_l + boff + 16 * 32);
    bf16x8 bl2 = *(const bf16x8*)(pB_l + boff + 32 * 32);
    bf16x8 bl3 = *(const bf16x8*)(pB_l + boff + 48 * 32);

    acc0 = __builtin_amdgcn_mfma_f32_16x16x32_bf16(ah, bh0, acc0, 0, 0, 0);
    acc1 = __builtin_amdgcn_mfma_f32_16x16x32_bf16(ah, bh1, acc1, 0, 0, 0);
    acc2 = __builtin_amdgcn_mfma_f32_16x16x32_bf16(ah, bh2, acc2, 0, 0, 0);
    acc3 = __builtin_amdgcn_mfma_f32_16x16x32_bf16(ah, bh3, acc3, 0, 0, 0);
    acc0 = __builtin_amdgcn_mfma_f32_16x16x32_bf16(ah, bl0, acc0, 0, 0, 0);
    acc1 = __builtin_amdgcn_mfma_f32_16x16x32_bf16(ah, bl1, acc1, 0, 0, 0);
    acc2 = __builtin_amdgcn_mfma_f32_16x16x32_bf16(ah, bl2, acc2, 0, 0, 0);
    acc3 = __builtin_amdgcn_mfma_f32_16x16x32_bf16(ah, bl3, acc3, 0, 0, 0);
    acc0 = __builtin_amdgcn_mfma_f32_16x16x32_bf16(al, bh0, acc0, 0, 0, 0);
    acc1 = __builtin_amdgcn_mfma_f32_16x16x32_bf16(al, bh1, acc1, 0, 0, 0);
    acc2 = __builtin_amdgcn_mfma_f32_16x16x32_bf16(al, bh2, acc2, 0, 0, 0);
    acc3 = __builtin_amdgcn_mfma_f32_16x16x32_bf16(al, bh3, acc3, 0, 0, 0);

    __syncthreads();   // ONE barrier: next buf staged + this buf reads done
  }
#undef STAGE

  int row0 = m0 + wv * 16 + quad * 4;
  int colb = n0 + l15;
#pragma unroll
  for (int r = 0; r < 4; ++r) {
    Cm[(size_t)(row0 + r) * Nn + colb +  0] = acc0[r];
    Cm[(size_t)(row0 + r) * Nn + colb + 16] = acc1[r];
    Cm[(size_t)(row0 + r) * Nn + colb + 32] = acc2[r];
    Cm[(size_t)(row0 + r) * Nn + colb + 48] = acc3[r];
  }
}

// ---------------------------------------------------------------------------
// K5: activations + hi/lo split of stage-1 LoRA outputs (MFMA stage-2 prep).
// ---------------------------------------------------------------------------
__global__ __launch_bounds__(256) void k_act2(
    const float* __restrict__ h1w, const float* __restrict__ h1a,
    const float* __restrict__ h1v, const float* __restrict__ h1g,
    __hip_bfloat16* __restrict__ wh, __hip_bfloat16* __restrict__ wl,
    __hip_bfloat16* __restrict__ ah, __hip_bfloat16* __restrict__ al,
    __hip_bfloat16* __restrict__ vh, __hip_bfloat16* __restrict__ vl,
    __hip_bfloat16* __restrict__ gh, __hip_bfloat16* __restrict__ gl) {
  int i = blockIdx.x * 256 + threadIdx.x;   // grid covers BT*128 exactly
  if (i < BT * 64) {
    split_bf16(tanhf(h1w[i]), wh[i], wl[i]);
    split_bf16(h1a[i], ah[i], al[i]);
    split_bf16(h1v[i], vh[i], vl[i]);
  }
  split_bf16(sigf(h1g[i]), gh[i], gl[i]);
}

// ---------------------------------------------------------------------------
// K6: elementwise gates + kk-normalize + per-head bonus. wave == head.
// ---------------------------------------------------------------------------
__global__ __launch_bounds__(256) void k_gate(
    const float* __restrict__ h2w, const float* __restrict__ h2a,
    const float* __restrict__ h2v,
    const float* __restrict__ w0, const float* __restrict__ a0,
    const float* __restrict__ v0, const float* __restrict__ kkc,
    const float* __restrict__ kac, float* __restrict__ kbuf,
    float* __restrict__ vbuf, const float* __restrict__ vfirst,
    const float* __restrict__ rbuf, const float* __restrict__ rk,
    float* __restrict__ dec, float* __restrict__ aw,
    float* __restrict__ bw, float* __restrict__ bonb) {
  int idx = blockIdx.x * 256 + threadIdx.x;   // < BT*CC
  int c = idx & (CC - 1);
  float kv = kbuf[idx], vv = vbuf[idx], vf = vfirst[idx];
  float d_ = 0.60653065971f * sigf(w0[c] + h2w[idx]);   // sigmoid * e^-0.5
  float as = sigf(a0[c] + h2a[idx]);
  float vs = sigf(v0[c] + h2v[idx]);
  float vm = vv + (vf - vv) * vs;
  float kfv = kv * (1.0f + kac[c] * (as - 1.0f));
  float kku = kv * kkc[c];
  float s = kku * kku;     // per-head L2 over 64 lanes (wave == head)
  s += __shfl_xor(s, 1);  s += __shfl_xor(s, 2);  s += __shfl_xor(s, 4);
  s += __shfl_xor(s, 8);  s += __shfl_xor(s, 16); s += __shfl_xor(s, 32);
  float nrm = fmaxf(sqrtf(s), 1e-12f);
  float kkn = kku / nrm;
  float bon = rbuf[idx] * kfv * rk[c];
  bon += __shfl_xor(bon, 1);  bon += __shfl_xor(bon, 2);
  bon += __shfl_xor(bon, 4);  bon += __shfl_xor(bon, 8);
  bon += __shfl_xor(bon, 16); bon += __shfl_xor(bon, 32);
  if ((threadIdx.x & 63) == 0) bonb[(idx >> 11) * HH + (c >> 6)] = bon;
  dec[idx] = d_;
  aw[idx]  = -kkn; bw[idx] = kkn * as;
  kbuf[idx] = kfv; vbuf[idx] = vm;
}

// ---------------------------------------------------------------------------
// K7: WKV7 scan — round-14 LDS-DMA-ring version (passing, ~188 µs), unchanged.
// ---------------------------------------------------------------------------
__global__ __launch_bounds__(64, 1) void k_scan(
    const float* __restrict__ rbuf, const float* __restrict__ kf,
    const float* __restrict__ dec, const float* __restrict__ aw,
    const float* __restrict__ bw, const float* __restrict__ vbuf,
    const float* __restrict__ st0, float* __restrict__ ybuf) {
  __shared__ __align__(16) char ldsbuf[16 * 2048];
  int blk = blockIdx.x;                     // 0..1023
  int xcd = blk & 7;
  int q   = blk >> 3;                       // 0..127
  int bh  = xcd * 8 + (q & 7);              // 16 rg-waves of a head share blk%8
  int rg  = q >> 3;                         // 0..15
  int b = bh >> 5, h = bh & 31;
  int lane = threadIdx.x;
  int l15  = lane & 15;
  int row  = rg * 4 + (lane >> 4);
  size_t tokbase = (size_t)b * TT * CC + h * 64;

  f32x4 S = *(const f32x4*)(st0 + ((size_t)bh * 64 + row) * 64 + l15 * 4);
  bool writer = (l15 == 0);
  float* yout = ybuf + tokbase + row;

  // per-lane DMA source pointers (advance +CC per token, all lanes uniform)
  const float* g1 = (lane < 16 ? rbuf : lane < 32 ? kf : lane < 48 ? dec : aw)
                  + tokbase + l15 * 4;
  const float* g2 = (lane < 16) ? (bw + tokbase + l15 * 4)
                                : (vbuf + tokbase + rg * 4);  // lanes>=16: v rows (16 real, rest pad)

  // LDS byte offsets (relative to workgroup LDS base)
  unsigned lbase = (unsigned)(uintptr_t)(__attribute__((address_space(3))) char*)ldsbuf;
  unsigned larr = lbase + (unsigned)(l15 * 16);          // +slot: arrays at 0/256/512/768/1024
  unsigned lvad = lbase + 1280u + (unsigned)((lane >> 4) * 4);  // +slot: v word

#define DMAQ(T)                                                              \
  { char* sb_ = ldsbuf + (((T) & 15) << 11);                                 \
    __builtin_amdgcn_global_load_lds(                                        \
        (const __attribute__((address_space(1))) void*)g1,                   \
        (__attribute__((address_space(3))) void*)sb_, 16, 0, 0);             \
    __builtin_amdgcn_global_load_lds(                                        \
        (const __attribute__((address_space(1))) void*)g2,                   \
        (__attribute__((address_space(3))) void*)(sb_ + 1024), 16, 0, 0);    \
    g1 += CC; g2 += CC; }

#define DSRD(RR, RK, RD, RA, RB, RV, T)                                      \
  { unsigned a_ = larr + (unsigned)(((T) & 15) << 11);                       \
    unsigned v_ = lvad + (unsigned)(((T) & 15) << 11);                       \
    asm volatile("ds_read_b128 %0, %1"             : "=v"(RR) : "v"(a_));    \
    asm volatile("ds_read_b128 %0, %1 offset:256"  : "=v"(RK) : "v"(a_));    \
    asm volatile("ds_read_b128 %0, %1 offset:512"  : "=v"(RD) : "v"(a_));    \
    asm volatile("ds_read_b128 %0, %1 offset:768"  : "=v"(RA) : "v"(a_));    \
    asm volatile("ds_read_b128 %0, %1 offset:1024" : "=v"(RB) : "v"(a_));    \
    asm volatile("ds_read_b32 %0, %1"              : "=v"(RV) : "v"(v_)); }

#define WVM(N) { asm volatile("s_waitcnt vmcnt(" #N ")" ::: "memory");       \
                 __builtin_amdgcn_sched_barrier(0); }
#define WLG    { asm volatile("s_waitcnt lgkmcnt(0)" ::: "memory");          \
                 __builtin_amdgcn_sched_barrier(0); }

#define STEPR(RR, RK, RD, RA, RB, RV, T)                                     \
  { float sa = fmaf(S.w, RA.w, fmaf(S.z, RA.z,                               \
               fmaf(S.y, RA.y, S.x * RA.x)));                                \
    sa = red16(sa);                                                          \
    float vv = RV;                                                           \
    S.x = fmaf(S.x, RD.x, fmaf(sa, RB.x, vv * RK.x));                        \
    S.y = fmaf(S.y, RD.y, fmaf(sa, RB.y, vv * RK.y));                        \
    S.z = fmaf(S.z, RD.z, fmaf(sa, RB.z, vv * RK.z));                        \
    S.w = fmaf(S.w, RD.w, fmaf(sa, RB.w, vv * RK.w));                        \
    float y = fmaf(S.w, RR.w, fmaf(S.z, RR.z,                                \
              fmaf(S.y, RR.y, S.x * RR.x)));                                 \
    y = red16(y);                                                            \
    if (writer) yout[(size_t)(T) * CC] = y; }

  // prologue: DMA tokens 0..15 (32 vmem ops in flight)
  for (int tt = 0; tt < 16; ++tt) DMAQ(tt)

  f32x4 Ar, Ak, Ad, Aa, Ab; float Av;
  f32x4 Br, Bk, Bd, Ba, Bb; float Bv;

  WVM(24)                      // token 0 landed (30 ops after it; 6 slack)
  DSRD(Ar, Ak, Ad, Aa, Ab, Av, 0)
  WLG

  int t = 0;
  // warm-up pairs: t = 0..15 (prologue-issued tokens; exact budget 30+t)
  for (; t < 16; t += 2) {
    DMAQ(t + 16)
    WVM(24)
    DSRD(Br, Bk, Bd, Ba, Bb, Bv, t + 1)
    STEPR(Ar, Ak, Ad, Aa, Ab, Av, t)
    WLG
    DMAQ(t + 17)
    WVM(24)
    DSRD(Ar, Ak, Ad, Aa, Ab, Av, t + 2)
    STEPR(Br, Bk, Bd, Ba, Bb, Bv, t + 1)
    WLG
  }
  // steady pairs: t = 16..1006 (budget 45; 5 slack)
  for (; t < TT - 16; t += 2) {
    DMAQ(t + 16)
    WVM(40)
    DSRD(Br, Bk, Bd, Ba, Bb, Bv, t + 1)
    STEPR(Ar, Ak, Ad, Aa, Ab, Av, t)
    WLG
    DMAQ(t + 17)
    WVM(40)
    DSRD(Ar, Ak, Ad, Aa, Ab, Av, t + 2)
    STEPR(Br, Bk, Bd, Ba, Bb, Bv, t + 1)
    WLG
  }
  // drain, then waitless tail: t = 1008..1023 (all data resident in LDS)
  asm volatile("s_waitcnt vmcnt(0)" ::: "memory");
  __builtin_amdgcn_sched_barrier(0);
  for (; t < TT; t += 2) {
    DSRD(Br, Bk, Bd, Ba, Bb, Bv, t + 1)
    STEPR(Ar, Ak, Ad, Aa, Ab, Av, t)
    WLG
    if (t + 2 < TT) DSRD(Ar, Ak, Ad, Aa, Ab, Av, t + 2)
    STEPR(Br, Bk, Bd, Ba, Bb, Bv, t + 1)
    WLG
  }
#undef DMAQ
#undef DSRD
#undef WVM
#undef WLG
#undef STEPR
}

// ---------------------------------------------------------------------------
// K8: post-scan epilogue: GroupNorm + bonus + g-gate, fully parallel.
// ---------------------------------------------------------------------------
__global__ __launch_bounds__(256) void k_post(
    const float* __restrict__ ybuf, const float* __restrict__ vb,
    const float* __restrict__ gvb, const float* __restrict__ bonb,
    const float* __restrict__ gnw, const float* __restrict__ gnb,
    __hip_bfloat16* __restrict__ xoh, __hip_bfloat16* __restrict__ xol) {
  int tid = threadIdx.x, wv = tid >> 6, lane = tid & 63;
  int id = blockIdx.x * 4 + wv;        // 0..BT*HH-1
  int bt = id >> 5, h = id & 31;
  size_t base = (size_t)bt * CC + h * 64 + lane;
  float y = ybuf[base];
  float s1 = y, s2 = y * y;
#pragma unroll
  for (int off = 1; off < 64; off <<= 1) {
    s1 += __shfl_xor(s1, off);
    s2 += __shfl_xor(s2, off);
  }
  float mean = s1 * (1.0f / 64.0f);
  float var  = s2 * (1.0f / 64.0f) - mean * mean;
  float inv  = rsqrtf(var + GN_EPS);
  float x = fmaf((y - mean) * inv, gnw[h * 64 + lane], gnb[h * 64 + lane])
          + bonb[bt * HH + h] * vb[base];
  split_bf16(x * gvb[base], xoh[base], xol[base]);
}

// ---------------------------------------------------------------------------
extern "C" void kernel_launch(void* const* d_in, const int* in_sizes, int n_in,
                              void* d_out, int out_size, void* d_ws, size_t ws_size,
                              hipStream_t stream) {
  (void)in_sizes; (void)n_in; (void)out_size; (void)ws_size;
  const float* hid    = (const float*)d_in[0];
  const float* shift  = (const float*)d_in[1];
  const float* st0    = (const float*)d_in[2];
  const float* vfirst = (const float*)d_in[3];
  const float* xrc = (const float*)d_in[4];
  const float* xwc = (const float*)d_in[5];
  const float* xkc = (const float*)d_in[6];
  const float* xvc = (const float*)d_in[7];
  const float* xac = (const float*)d_in[8];
  const float* xgc = (const float*)d_in[9];
  const float* w0  = (const float*)d_in[10];
  const float* w1  = (const float*)d_in[11];
  const float* w2  = (const float*)d_in[12];
  const float* a0  = (const float*)d_in[13];
  const float* a1  = (const float*)d_in[14];
  const float* a2  = (const float*)d_in[15];
  const float* v0  = (const float*)d_in[16];
  const float* v1  = (const float*)d_in[17];
  const float* v2  = (const float*)d_in[18];
  const float* g1  = (const float*)d_in[19];
  const float* g2  = (const float*)d_in[20];
  const float* kkc = (const float*)d_in[21];
  const float* kac = (const float*)d_in[22];
  const float* rk  = (const float*)d_in[23];
  const float* Wr  = (const float*)d_in[24];
  const float* Wk  = (const float*)d_in[25];
  const float* Wv  = (const float*)d_in[26];
  const float* Wo  = (const float*)d_in[27];
  const float* gnw = (const float*)d_in[28];
  const float* gnb = (const float*)d_in[29];
  float* out = (float*)d_out;

  char* p = (char*)d_ws;
  auto alloc = [&](size_t n) { char* q = p; p += (n + 255) & ~(size_t)255; return q; };
  const size_t EL = (size_t)BT * CC;

  // --- alias pool: xrh..xvl + Wrh,Wrl dead by k_gate time; db/awb/bwb +
  //     h2g (the old gvb slot) overlay them.
  char* pool = p;
  __hip_bfloat16* xrh = (__hip_bfloat16*)alloc(EL * 2);
  __hip_bfloat16* xrl = (__hip_bfloat16*)alloc(EL * 2);
  __hip_bfloat16* xkh = (__hip_bfloat16*)alloc(EL * 2);
  __hip_bfloat16* xkl = (__hip_bfloat16*)alloc(EL * 2);
  __hip_bfloat16* xvh = (__hip_bfloat16*)alloc(EL * 2);
  __hip_bfloat16* xvl = (__hip_bfloat16*)alloc(EL * 2);
  __hip_bfloat16* Wrh = (__hip_bfloat16*)alloc((size_t)CC * CC * 2);
  __hip_bfloat16* Wrl = (__hip_bfloat16*)alloc((size_t)CC * CC * 2);
  float* db  = (float*)pool;           // overlays xrh+xrl
  float* awb = db + EL;                // overlays xkh+xkl
  float* bwb = db + 2 * EL;            // overlays xvh+xvl
  float* h2g = db + 3 * EL;            // overlays Wrh+Wrl (old gvb slot)

  __hip_bfloat16* Wkh = (__hip_bfloat16*)alloc((size_t)CC * CC * 2);
  __hip_bfloat16* Wkl = (__hip_bfloat16*)alloc((size_t)CC * CC * 2);
  float* ybuf = (float*)Wkh;           // overlays Wkh+Wkl (dead after k-GEMM)
  float* h2v  = (float*)Wkh;           // same region, read by k_gate BEFORE scan writes ybuf

  __hip_bfloat16* Wvh = (__hip_bfloat16*)alloc((size_t)CC * CC * 2);
  __hip_bfloat16* Wvl = (__hip_bfloat16*)alloc((size_t)CC * CC * 2);
  __hip_bfloat16* Woh = (__hip_bfloat16*)alloc((size_t)CC * CC * 2);
  __hip_bfloat16* Wol = (__hip_bfloat16*)alloc((size_t)CC * CC * 2);
  __hip_bfloat16* xw  = (__hip_bfloat16*)alloc(EL * 2);
  __hip_bfloat16* xa  = (__hip_bfloat16*)alloc(EL * 2);
  __hip_bfloat16* xg  = (__hip_bfloat16*)alloc(EL * 2);
  float* h2w = (float*)xw;             // overlays xw+xa (dead after stage-1 GEMMs)
  __hip_bfloat16* w1t = (__hip_bfloat16*)alloc((size_t)64  * CC * 2);
  __hip_bfloat16* a1t = (__hip_bfloat16*)alloc((size_t)64  * CC * 2);
  __hip_bfloat16* v1t = (__hip_bfloat16*)alloc((size_t)64  * CC * 2);
  __hip_bfloat16* g1t = (__hip_bfloat16*)alloc((size_t)128 * CC * 2);
  float* rb  = (float*)alloc(EL * 4);
  float* kb  = (float*)alloc(EL * 4);  // raw k, then k_final in place
  float* vb  = (float*)alloc(EL * 4);  // raw v, then v_mix in place
  float* h1w = (float*)alloc((size_t)BT * 64  * 4);
  float* h1a = (float*)alloc((size_t)BT * 64  * 4);
  float* h1v = (float*)alloc((size_t)BT * 64  * 4);
  float* h1g = (float*)alloc((size_t)BT * 128 * 4);
  __hip_bfloat16* xoh = (__hip_bfloat16*)alloc(EL * 2);
  __hip_bfloat16* xol = (__hip_bfloat16*)alloc(EL * 2);
  float* h2a = (float*)xoh;            // overlays xoh+xol (k_post writes them AFTER k_gate)
  float* bonb = (float*)alloc((size_t)BT * HH * 4);   // per-(token,head) bonus
  // stage-2 split operands (small, fresh):
  __hip_bfloat16* h1wh = (__hip_bfloat16*)alloc((size_t)BT * 64 * 2);
  __hip_bfloat16* h1wl = (__hip_bfloat16*)alloc((size_t)BT * 64 * 2);
  __hip_bfloat16* h1ah = (__hip_bfloat16*)alloc((size_t)BT * 64 * 2);
  __hip_bfloat16* h1al = (__hip_bfloat16*)alloc((size_t)BT * 64 * 2);
  __hip_bfloat16* h1vh = (__hip_bfloat16*)alloc((size_t)BT * 64 * 2);
  __hip_bfloat16* h1vl = (__hip_bfloat16*)alloc((size_t)BT * 64 * 2);
  __hip_bfloat16* h1gh = (__hip_bfloat16*)alloc((size_t)BT * 128 * 2);
  __hip_bfloat16* h1gl = (__hip_bfloat16*)alloc((size_t)BT * 128 * 2);
  __hip_bfloat16* w2th = (__hip_bfloat16*)alloc((size_t)CC * 64 * 2);
  __hip_bfloat16* w2tl = (__hip_bfloat16*)alloc((size_t)CC * 64 * 2);
  __hip_bfloat16* a2th = (__hip_bfloat16*)alloc((size_t)CC * 64 * 2);
  __hip_bfloat16* a2tl = (__hip_bfloat16*)alloc((size_t)CC * 64 * 2);
  __hip_bfloat16* v2th = (__hip_bfloat16*)alloc((size_t)CC * 64 * 2);
  __hip_bfloat16* v2tl = (__hip_bfloat16*)alloc((size_t)CC * 64 * 2);
  __hip_bfloat16* g2th = (__hip_bfloat16*)alloc((size_t)CC * 128 * 2);
  __hip_bfloat16* g2tl = (__hip_bfloat16*)alloc((size_t)CC * 128 * 2);
  // total ~210 MiB (known-OK envelope: 220 OK, 268 crashed)

  k_prepx<<<16384, 256, 0, stream>>>(hid, shift, xrc, xwc, xkc, xvc, xac, xgc,
                                     xrh, xrl, xw, xkh, xkl, xvh, xvl, xa, xg);
  k_cvt2<<<16384, 256, 0, stream>>>(Wr, Wrh, Wrl);
  k_cvt2<<<16384, 256, 0, stream>>>(Wk, Wkh, Wkl);
  k_cvt2<<<16384, 256, 0, stream>>>(Wv, Wvh, Wvl);
  k_cvt2<<<16384, 256, 0, stream>>>(Wo, Woh, Wol);
  k_tr<<<512, 256, 0, stream>>>(w1, w1t, 64);
  k_tr<<<512, 256, 0, stream>>>(a1, a1t, 64);
  k_tr<<<512, 256, 0, stream>>>(v1, v1t, 32);
  k_tr<<<1024, 256, 0, stream>>>(g1, g1t, 128);
  k_trs<<<512, 256, 0, stream>>>(w2, w2th, w2tl, 64, 6);
  k_trs<<<512, 256, 0, stream>>>(a2, a2th, a2tl, 64, 6);
  k_trs<<<512, 256, 0, stream>>>(v2, v2th, v2tl, 32, 6);   // padded K=64
  k_trs<<<1024, 256, 0, stream>>>(g2, g2th, g2tl, 128, 7);

  k_gemm_bt3<<<dim3(32, 32), 256, 0, stream>>>(xrh, xrl, Wrh, Wrl, rb, BT, CC, CC);
  k_gemm_bt3<<<dim3(32, 32), 256, 0, stream>>>(xkh, xkl, Wkh, Wkl, kb, BT, CC, CC);
  k_gemm_bt3<<<dim3(32, 32), 256, 0, stream>>>(xvh, xvl, Wvh, Wvl, vb, BT, CC, CC);
  k_gemm_bt<<<dim3(16, 1),  256, 0, stream>>>(xw,  w1t, h1w, BT, 64, CC);
  k_gemm_bt<<<dim3(16, 1),  256, 0, stream>>>(xa,  a1t, h1a, BT, 64, CC);
  k_gemm_bt<<<dim3(16, 1),  256, 0, stream>>>(xvh, v1t, h1v, BT, 64, CC);
  k_gemm_bt<<<dim3(16, 2),  256, 0, stream>>>(xg,  g1t, h1g, BT, 128, CC);

  k_act2<<<1024, 256, 0, stream>>>(h1w, h1a, h1v, h1g,
                                   h1wh, h1wl, h1ah, h1al,
                                   h1vh, h1vl, h1gh, h1gl);
  // stage-2 LoRA dots on MFMA (split precision). Overlays now live:
  //   h2w->xw+xa, h2a->xoh+xol, h2v->Wkh+Wkl, h2g->Wrh+Wrl.
  k_gemm_bt3<<<dim3(32, 32), 256, 0, stream>>>(h1wh, h1wl, w2th, w2tl, h2w, BT, CC, 64);
  k_gemm_bt3<<<dim3(32, 32), 256, 0, stream>>>(h1ah, h1al, a2th, a2tl, h2a, BT, CC, 64);
  k_gemm_bt3<<<dim3(32, 32), 256, 0, stream>>>(h1vh, h1vl, v2th, v2tl, h2v, BT, CC, 64);
  k_gemm_bt3<<<dim3(32, 32), 256, 0, stream>>>(h1gh, h1gl, g2th, g2tl, h2g, BT, CC, 128);

  k_gate<<<16384, 256, 0, stream>>>(h2w, h2a, h2v, w0, a0, v0, kkc, kac,
                                    kb, vb, vfirst, rb, rk, db, awb, bwb, bonb);
  k_scan<<<1024, 64, 0, stream>>>(rb, kb, db, awb, bwb, vb, st0, ybuf);
  k_post<<<16384, 256, 0, stream>>>(ybuf, vb, h2g, bonb, gnw, gnb, xoh, xol);
  k_gemm_bt3<<<dim3(32, 32), 256, 0, stream>>>(xoh, xol, Woh, Wol, out, BT, CC, CC);
}

// Round 11
// 943.533 us; speedup vs baseline: 1.1549x; 1.1549x over previous
//
#include <hip/hip_runtime.h>
#include <hip/hip_bf16.h>

// Problem constants (RWKV-7 Tmix: B=2, T=1024, C=2048, H=32, N=64)
#define BB 2
#define TT 1024
#define CC 2048
#define HH 32
#define BT 2048          // BB*TT tokens
#define GN_EPS 6.4e-4f   // 1e-5 * 8^2

typedef __attribute__((ext_vector_type(8))) __bf16 bf16x8;
typedef __attribute__((ext_vector_type(4))) float f32x4;

__device__ __forceinline__ float sigf(float x) { return 1.0f / (1.0f + expf(-x)); }

__device__ __forceinline__ void split_bf16(float x, __hip_bfloat16& hi, __hip_bfloat16& lo) {
  __hip_bfloat16 h = __float2bfloat16(x);
  hi = h;
  lo = __float2bfloat16(x - __bfloat162float(h));
}

// Sum over each aligned 16-lane group, pure DPP (no LDS pipe on the chain).
__device__ __forceinline__ float red16(float x) {
  x += __int_as_float(__builtin_amdgcn_update_dpp(
      0, __float_as_int(x), 0xB1 /*quad_perm [1,0,3,2]*/, 0xF, 0xF, true));
  x += __int_as_float(__builtin_amdgcn_update_dpp(
      0, __float_as_int(x), 0x4E /*quad_perm [2,3,0,1]*/, 0xF, 0xF, true));
  x += __int_as_float(__builtin_amdgcn_update_dpp(
      0, __float_as_int(x), 0x141 /*row_half_mirror*/, 0xF, 0xF, true));
  x += __int_as_float(__builtin_amdgcn_update_dpp(
      0, __float_as_int(x), 0x140 /*row_mirror*/, 0xF, 0xF, true));
  return x;
}

// ---------------------------------------------------------------------------
// K1: token shift + six lerped projections. r/k/v hi+lo split; w/a/g bf16.
// ---------------------------------------------------------------------------
__global__ __launch_bounds__(256) void k_prepx(
    const float* __restrict__ hid, const float* __restrict__ shift,
    const float* __restrict__ xrc, const float* __restrict__ xwc,
    const float* __restrict__ xkc, const float* __restrict__ xvc,
    const float* __restrict__ xac, const float* __restrict__ xgc,
    __hip_bfloat16* __restrict__ xrh, __hip_bfloat16* __restrict__ xrl,
    __hip_bfloat16* __restrict__ xw,
    __hip_bfloat16* __restrict__ xkh, __hip_bfloat16* __restrict__ xkl,
    __hip_bfloat16* __restrict__ xvh, __hip_bfloat16* __restrict__ xvl,
    __hip_bfloat16* __restrict__ xa, __hip_bfloat16* __restrict__ xg) {
  int idx = blockIdx.x * 256 + threadIdx.x;   // < BT*CC
  int c  = idx & (CC - 1);
  int bt = idx >> 11;
  int t  = bt & (TT - 1);
  int b  = bt >> 10;
  float hcur  = hid[idx];
  float hprev = (t == 0) ? shift[b * CC + c] : hid[idx - CC];
  float xx = hprev - hcur;
  split_bf16(fmaf(xx, xrc[c], hcur), xrh[idx], xrl[idx]);
  split_bf16(fmaf(xx, xkc[c], hcur), xkh[idx], xkl[idx]);
  split_bf16(fmaf(xx, xvc[c], hcur), xvh[idx], xvl[idx]);
  xw[idx] = __float2bfloat16(fmaf(xx, xwc[c], hcur));
  xa[idx] = __float2bfloat16(fmaf(xx, xac[c], hcur));
  xg[idx] = __float2bfloat16(fmaf(xx, xgc[c], hcur));
}

// ---------------------------------------------------------------------------
// K2: f32 -> hi+lo bf16 split (for Wr/Wk/Wv/Wo)
// ---------------------------------------------------------------------------
__global__ __launch_bounds__(256) void k_cvt2(const float* __restrict__ in,
                                              __hip_bfloat16* __restrict__ oh,
                                              __hip_bfloat16* __restrict__ ol) {
  int i = blockIdx.x * 256 + threadIdx.x;
  split_bf16(in[i], oh[i], ol[i]);
}

// ---------------------------------------------------------------------------
// K3: transpose-convert small LoRA "up" weights: in [2048][N0] f32 ->
//     out [NP][2048] bf16 (rows >= N0 zero-padded).  (stage-1 B operands)
// ---------------------------------------------------------------------------
__global__ __launch_bounds__(256) void k_tr(const float* __restrict__ in,
                                            __hip_bfloat16* __restrict__ out,
                                            int N0) {
  int i = blockIdx.x * 256 + threadIdx.x;   // over NP*2048, grid exact
  int n = i >> 11;
  int k = i & 2047;
  float v = (n < N0) ? in[k * N0 + n] : 0.0f;
  out[i] = __float2bfloat16(v);
}

// ---------------------------------------------------------------------------
// K3b: transpose + hi/lo split of stage-2 "down" weights:
//   in [N0][CC] f32 -> out [CC][K0] bf16 hi+lo (K0 = 1<<lgK, rows>=N0 zero).
// ---------------------------------------------------------------------------
__global__ __launch_bounds__(256) void k_trs(const float* __restrict__ in,
                                             __hip_bfloat16* __restrict__ oh,
                                             __hip_bfloat16* __restrict__ ol,
                                             int N0, int lgK) {
  int i = blockIdx.x * 256 + threadIdx.x;   // over CC*K0, grid exact
  int n = i >> lgK;
  int k = i & ((1 << lgK) - 1);
  float v = (k < N0) ? in[k * CC + n] : 0.0f;
  split_bf16(v, oh[i], ol[i]);
}

// ---------------------------------------------------------------------------
// K4: ROUND-18 — fused stage-1 LoRA GEMM, LDS-staged.
// The four stage-1 GEMMs ran as 16-32 block grids with serialized direct
// loads (~300cy each, round-8 evidence) — est. ~300 µs combined. Fuse into
// ONE dispatch: grid (32 M-tiles, 5 slices): slice = {xw*w1, xa*a1, xv*v1,
// xg*g1[0:64], xg*g1[64:128]} via block-uniform pointer table. Body = the
// r9/r10-proven 64x64/BK=32 global_load_lds 2-phase structure, single
// precision (2 DMA + 5 ds_read + 4 MFMA per wave-step).
// ---------------------------------------------------------------------------
__global__ __launch_bounds__(256, 4) void k_lora1(
    const __hip_bfloat16* __restrict__ xw, const __hip_bfloat16* __restrict__ xa,
    const __hip_bfloat16* __restrict__ xv, const __hip_bfloat16* __restrict__ xg,
    const __hip_bfloat16* __restrict__ w1t, const __hip_bfloat16* __restrict__ a1t,
    const __hip_bfloat16* __restrict__ v1t, const __hip_bfloat16* __restrict__ g1t,
    float* __restrict__ h1w, float* __restrict__ h1a,
    float* __restrict__ h1v, float* __restrict__ h1g) {
  __shared__ __align__(16) __hip_bfloat16 sA[2][64 * 32], sB[2][64 * 32];
  int tid  = threadIdx.x;
  int lane = tid & 63;
  int wv   = tid >> 6;
  int l15  = lane & 15;
  int quad = lane >> 4;
  int m0 = blockIdx.x * 64;
  int bly = blockIdx.y;

  const __hip_bfloat16* Ab;
  const __hip_bfloat16* Bb;
  float* Ob;
  int os, cb;
  if (bly == 0)      { Ab = xw; Bb = w1t;            Ob = h1w; os = 64;  cb = 0;  }
  else if (bly == 1) { Ab = xa; Bb = a1t;            Ob = h1a; os = 64;  cb = 0;  }
  else if (bly == 2) { Ab = xv; Bb = v1t;            Ob = h1v; os = 64;  cb = 0;  }
  else if (bly == 3) { Ab = xg; Bb = g1t;            Ob = h1g; os = 128; cb = 0;  }
  else               { Ab = xg; Bb = g1t + 64 * CC;  Ob = h1g; os = 128; cb = 64; }

  // staging: wave wv fills rows wv*16..+15 of each [64][32] tile.
  int srow = wv * 16 + (lane >> 2);
  int scol = (lane & 3) * 8;
  const __hip_bfloat16* gA = Ab + (size_t)(m0 + srow) * CC + scol;
  const __hip_bfloat16* gB = Bb + (size_t)srow * CC + scol;

  f32x4 z = {0.f, 0.f, 0.f, 0.f};
  f32x4 acc0 = z, acc1 = z, acc2 = z, acc3 = z;

  int aoff = (wv * 16 + l15) * 32 + quad * 8;
  int boff = l15 * 32 + quad * 8;

#define STAGE1(BUF, KO)                                                      \
  { unsigned db_ = (unsigned)(BUF) * 4096u + (unsigned)wv * 1024u;           \
    __builtin_amdgcn_global_load_lds(                                        \
        (const __attribute__((address_space(1))) void*)(gA + (KO)),          \
        (__attribute__((address_space(3))) void*)((char*)sA + db_), 16, 0, 0);\
    __builtin_amdgcn_global_load_lds(                                        \
        (const __attribute__((address_space(1))) void*)(gB + (KO)),          \
        (__attribute__((address_space(3))) void*)((char*)sB + db_), 16, 0, 0);}

  STAGE1(0, 0)
  __syncthreads();

  for (int k0 = 0; k0 < CC; k0 += 32) {
    int cur = (k0 >> 5) & 1;
    if (k0 + 32 < CC) STAGE1(cur ^ 1, k0 + 32)

    const __hip_bfloat16* pA_ = &sA[cur][0];
    const __hip_bfloat16* pB_ = &sB[cur][0];
    bf16x8 av = *(const bf16x8*)(pA_ + aoff);
    bf16x8 b0 = *(const bf16x8*)(pB_ + boff);
    bf16x8 b1 = *(const bf16x8*)(pB_ + boff + 16 * 32);
    bf16x8 b2 = *(const bf16x8*)(pB_ + boff + 32 * 32);
    bf16x8 b3 = *(const bf16x8*)(pB_ + boff + 48 * 32);

    acc0 = __builtin_amdgcn_mfma_f32_16x16x32_bf16(av, b0, acc0, 0, 0, 0);
    acc1 = __builtin_amdgcn_mfma_f32_16x16x32_bf16(av, b1, acc1, 0, 0, 0);
    acc2 = __builtin_amdgcn_mfma_f32_16x16x32_bf16(av, b2, acc2, 0, 0, 0);
    acc3 = __builtin_amdgcn_mfma_f32_16x16x32_bf16(av, b3, acc3, 0, 0, 0);

    __syncthreads();
  }
#undef STAGE1

  int row0 = m0 + wv * 16 + quad * 4;
  int colb = cb + l15;
#pragma unroll
  for (int r = 0; r < 4; ++r) {
    Ob[(size_t)(row0 + r) * os + colb +  0] = acc0[r];
    Ob[(size_t)(row0 + r) * os + colb + 16] = acc1[r];
    Ob[(size_t)(row0 + r) * os + colb + 32] = acc2[r];
    Ob[(size_t)(row0 + r) * os + colb + 48] = acc3[r];
  }
}

// ---------------------------------------------------------------------------
// K4b: split-precision GEMM — 2-phase double-buffered LDS staging (r10 form).
// ---------------------------------------------------------------------------
__global__ __launch_bounds__(256, 4) void k_gemm_bt3(
    const __hip_bfloat16* __restrict__ Ah, const __hip_bfloat16* __restrict__ Al,
    const __hip_bfloat16* __restrict__ Bh, const __hip_bfloat16* __restrict__ Bl,
    float* __restrict__ Cm, int M, int Nn, int K) {
  __shared__ __align__(16) __hip_bfloat16 sAh[2][64 * 32], sAl[2][64 * 32];
  __shared__ __align__(16) __hip_bfloat16 sBh[2][64 * 32], sBl[2][64 * 32];
  int tid  = threadIdx.x;
  int lane = tid & 63;
  int wv   = tid >> 6;
  int l15  = lane & 15;
  int quad = lane >> 4;
  int m0 = blockIdx.x * 64;
  int n0 = blockIdx.y * 64;

  int srow = wv * 16 + (lane >> 2);
  int scol = (lane & 3) * 8;
  const __hip_bfloat16* gAh = Ah + (size_t)(m0 + srow) * K + scol;
  const __hip_bfloat16* gAl = Al + (size_t)(m0 + srow) * K + scol;
  const __hip_bfloat16* gBh = Bh + (size_t)(n0 + srow) * K + scol;
  const __hip_bfloat16* gBl = Bl + (size_t)(n0 + srow) * K + scol;

  f32x4 z = {0.f, 0.f, 0.f, 0.f};
  f32x4 acc0 = z, acc1 = z, acc2 = z, acc3 = z;

  int aoff = (wv * 16 + l15) * 32 + quad * 8;
  int boff = l15 * 32 + quad * 8;

#define STAGE(BUF, KO)                                                       \
  { unsigned db_ = (unsigned)(BUF) * 4096u + (unsigned)wv * 1024u;           \
    __builtin_amdgcn_global_load_lds(                                        \
        (const __attribute__((address_space(1))) void*)(gAh + (KO)),         \
        (__attribute__((address_space(3))) void*)((char*)sAh + db_), 16, 0, 0);\
    __builtin_amdgcn_global_load_lds(                                        \
        (const __attribute__((address_space(1))) void*)(gAl + (KO)),         \
        (__attribute__((address_space(3))) void*)((char*)sAl + db_), 16, 0, 0);\
    __builtin_amdgcn_global_load_lds(                                        \
        (const __attribute__((address_space(1))) void*)(gBh + (KO)),         \
        (__attribute__((address_space(3))) void*)((char*)sBh + db_), 16, 0, 0);\
    __builtin_amdgcn_global_load_lds(                                        \
        (const __attribute__((address_space(1))) void*)(gBl + (KO)),         \
        (__attribute__((address_space(3))) void*)((char*)sBl + db_), 16, 0, 0);}

  STAGE(0, 0)
  __syncthreads();

  for (int k0 = 0; k0 < K; k0 += 32) {
    int cur = (k0 >> 5) & 1;
    if (k0 + 32 < K) STAGE(cur ^ 1, k0 + 32)

    const __hip_bfloat16* pA_h = &sAh[cur][0];
    const __hip_bfloat16* pA_l = &sAl[cur][0];
    const __hip_bfloat16* pB_h = &sBh[cur][0];
    const __hip_bfloat16* pB_l = &sBl[cur][0];
    bf16x8 ah = *(const bf16x8*)(pA_h + aoff);
    bf16x8 al = *(const bf16x8*)(pA_l + aoff);
    bf16x8 bh0 = *(const bf16x8*)(pB_h + boff);
    bf16x8 bh1 = *(const bf16x8*)(pB_h + boff + 16 * 32);
    bf16x8 bh2 = *(const bf16x8*)(pB_h + boff + 32 * 32);
    bf16x8 bh3 = *(const bf16x8*)(pB_h + boff + 48 * 32);
    bf16x8 bl0 = *(const bf16x8*)(pB_l + boff);
    bf16x8 bl1 = *(const bf16x8*)(pB_l + boff + 16 * 32);
    bf16x8 bl2 = *(const bf16x8*)(pB_l + boff + 32 * 32);
    bf16x8 bl3 = *(const bf16x8*)(pB_l + boff + 48 * 32);

    acc0 = __builtin_amdgcn_mfma_f32_16x16x32_bf16(ah, bh0, acc0, 0, 0, 0);
    acc1 = __builtin_amdgcn_mfma_f32_16x16x32_bf16(ah, bh1, acc1, 0, 0, 0);
    acc2 = __builtin_amdgcn_mfma_f32_16x16x32_bf16(ah, bh2, acc2, 0, 0, 0);
    acc3 = __builtin_amdgcn_mfma_f32_16x16x32_bf16(ah, bh3, acc3, 0, 0, 0);
    acc0 = __builtin_amdgcn_mfma_f32_16x16x32_bf16(ah, bl0, acc0, 0, 0, 0);
    acc1 = __builtin_amdgcn_mfma_f32_16x16x32_bf16(ah, bl1, acc1, 0, 0, 0);
    acc2 = __builtin_amdgcn_mfma_f32_16x16x32_bf16(ah, bl2, acc2, 0, 0, 0);
    acc3 = __builtin_amdgcn_mfma_f32_16x16x32_bf16(ah, bl3, acc3, 0, 0, 0);
    acc0 = __builtin_amdgcn_mfma_f32_16x16x32_bf16(al, bh0, acc0, 0, 0, 0);
    acc1 = __builtin_amdgcn_mfma_f32_16x16x32_bf16(al, bh1, acc1, 0, 0, 0);
    acc2 = __builtin_amdgcn_mfma_f32_16x16x32_bf16(al, bh2, acc2, 0, 0, 0);
    acc3 = __builtin_amdgcn_mfma_f32_16x16x32_bf16(al, bh3, acc3, 0, 0, 0);

    __syncthreads();
  }
#undef STAGE

  int row0 = m0 + wv * 16 + quad * 4;
  int colb = n0 + l15;
#pragma unroll
  for (int r = 0; r < 4; ++r) {
    Cm[(size_t)(row0 + r) * Nn + colb +  0] = acc0[r];
    Cm[(size_t)(row0 + r) * Nn + colb + 16] = acc1[r];
    Cm[(size_t)(row0 + r) * Nn + colb + 32] = acc2[r];
    Cm[(size_t)(row0 + r) * Nn + colb + 48] = acc3[r];
  }
}

// ---------------------------------------------------------------------------
// K5: activations + hi/lo split of stage-1 LoRA outputs (MFMA stage-2 prep).
// ---------------------------------------------------------------------------
__global__ __launch_bounds__(256) void k_act2(
    const float* __restrict__ h1w, const float* __restrict__ h1a,
    const float* __restrict__ h1v, const float* __restrict__ h1g,
    __hip_bfloat16* __restrict__ wh, __hip_bfloat16* __restrict__ wl,
    __hip_bfloat16* __restrict__ ah, __hip_bfloat16* __restrict__ al,
    __hip_bfloat16* __restrict__ vh, __hip_bfloat16* __restrict__ vl,
    __hip_bfloat16* __restrict__ gh, __hip_bfloat16* __restrict__ gl) {
  int i = blockIdx.x * 256 + threadIdx.x;   // grid covers BT*128 exactly
  if (i < BT * 64) {
    split_bf16(tanhf(h1w[i]), wh[i], wl[i]);
    split_bf16(h1a[i], ah[i], al[i]);
    split_bf16(h1v[i], vh[i], vl[i]);
  }
  split_bf16(sigf(h1g[i]), gh[i], gl[i]);
}

// ---------------------------------------------------------------------------
// K6: elementwise gates + kk-normalize + per-head bonus. wave == head.
// ---------------------------------------------------------------------------
__global__ __launch_bounds__(256) void k_gate(
    const float* __restrict__ h2w, const float* __restrict__ h2a,
    const float* __restrict__ h2v,
    const float* __restrict__ w0, const float* __restrict__ a0,
    const float* __restrict__ v0, const float* __restrict__ kkc,
    const float* __restrict__ kac, float* __restrict__ kbuf,
    float* __restrict__ vbuf, const float* __restrict__ vfirst,
    const float* __restrict__ rbuf, const float* __restrict__ rk,
    float* __restrict__ dec, float* __restrict__ aw,
    float* __restrict__ bw, float* __restrict__ bonb) {
  int idx = blockIdx.x * 256 + threadIdx.x;   // < BT*CC
  int c = idx & (CC - 1);
  float kv = kbuf[idx], vv = vbuf[idx], vf = vfirst[idx];
  float d_ = 0.60653065971f * sigf(w0[c] + h2w[idx]);   // sigmoid * e^-0.5
  float as = sigf(a0[c] + h2a[idx]);
  float vs = sigf(v0[c] + h2v[idx]);
  float vm = vv + (vf - vv) * vs;
  float kfv = kv * (1.0f + kac[c] * (as - 1.0f));
  float kku = kv * kkc[c];
  float s = kku * kku;     // per-head L2 over 64 lanes (wave == head)
  s += __shfl_xor(s, 1);  s += __shfl_xor(s, 2);  s += __shfl_xor(s, 4);
  s += __shfl_xor(s, 8);  s += __shfl_xor(s, 16); s += __shfl_xor(s, 32);
  float nrm = fmaxf(sqrtf(s), 1e-12f);
  float kkn = kku / nrm;
  float bon = rbuf[idx] * kfv * rk[c];
  bon += __shfl_xor(bon, 1);  bon += __shfl_xor(bon, 2);
  bon += __shfl_xor(bon, 4);  bon += __shfl_xor(bon, 8);
  bon += __shfl_xor(bon, 16); bon += __shfl_xor(bon, 32);
  if ((threadIdx.x & 63) == 0) bonb[(idx >> 11) * HH + (c >> 6)] = bon;
  dec[idx] = d_;
  aw[idx]  = -kkn; bw[idx] = kkn * as;
  kbuf[idx] = kfv; vbuf[idx] = vm;
}

// ---------------------------------------------------------------------------
// K7: WKV7 scan — round-14 LDS-DMA-ring version (passing, ~188 µs), unchanged.
// ---------------------------------------------------------------------------
__global__ __launch_bounds__(64, 1) void k_scan(
    const float* __restrict__ rbuf, const float* __restrict__ kf,
    const float* __restrict__ dec, const float* __restrict__ aw,
    const float* __restrict__ bw, const float* __restrict__ vbuf,
    const float* __restrict__ st0, float* __restrict__ ybuf) {
  __shared__ __align__(16) char ldsbuf[16 * 2048];
  int blk = blockIdx.x;                     // 0..1023
  int xcd = blk & 7;
  int q   = blk >> 3;                       // 0..127
  int bh  = xcd * 8 + (q & 7);              // 16 rg-waves of a head share blk%8
  int rg  = q >> 3;                         // 0..15
  int b = bh >> 5, h = bh & 31;
  int lane = threadIdx.x;
  int l15  = lane & 15;
  int row  = rg * 4 + (lane >> 4);
  size_t tokbase = (size_t)b * TT * CC + h * 64;

  f32x4 S = *(const f32x4*)(st0 + ((size_t)bh * 64 + row) * 64 + l15 * 4);
  bool writer = (l15 == 0);
  float* yout = ybuf + tokbase + row;

  // per-lane DMA source pointers (advance +CC per token, all lanes uniform)
  const float* g1 = (lane < 16 ? rbuf : lane < 32 ? kf : lane < 48 ? dec : aw)
                  + tokbase + l15 * 4;
  const float* g2 = (lane < 16) ? (bw + tokbase + l15 * 4)
                                : (vbuf + tokbase + rg * 4);  // lanes>=16: v rows (16 real, rest pad)

  // LDS byte offsets (relative to workgroup LDS base)
  unsigned lbase = (unsigned)(uintptr_t)(__attribute__((address_space(3))) char*)ldsbuf;
  unsigned larr = lbase + (unsigned)(l15 * 16);          // +slot: arrays at 0/256/512/768/1024
  unsigned lvad = lbase + 1280u + (unsigned)((lane >> 4) * 4);  // +slot: v word

#define DMAQ(T)                                                              \
  { char* sb_ = ldsbuf + (((T) & 15) << 11);                                 \
    __builtin_amdgcn_global_load_lds(                                        \
        (const __attribute__((address_space(1))) void*)g1,                   \
        (__attribute__((address_space(3))) void*)sb_, 16, 0, 0);             \
    __builtin_amdgcn_global_load_lds(                                        \
        (const __attribute__((address_space(1))) void*)g2,                   \
        (__attribute__((address_space(3))) void*)(sb_ + 1024), 16, 0, 0);    \
    g1 += CC; g2 += CC; }

#define DSRD(RR, RK, RD, RA, RB, RV, T)                                      \
  { unsigned a_ = larr + (unsigned)(((T) & 15) << 11);                       \
    unsigned v_ = lvad + (unsigned)(((T) & 15) << 11);                       \
    asm volatile("ds_read_b128 %0, %1"             : "=v"(RR) : "v"(a_));    \
    asm volatile("ds_read_b128 %0, %1 offset:256"  : "=v"(RK) : "v"(a_));    \
    asm volatile("ds_read_b128 %0, %1 offset:512"  : "=v"(RD) : "v"(a_));    \
    asm volatile("ds_read_b128 %0, %1 offset:768"  : "=v"(RA) : "v"(a_));    \
    asm volatile("ds_read_b128 %0, %1 offset:1024" : "=v"(RB) : "v"(a_));    \
    asm volatile("ds_read_b32 %0, %1"              : "=v"(RV) : "v"(v_)); }

#define WVM(N) { asm volatile("s_waitcnt vmcnt(" #N ")" ::: "memory");       \
                 __builtin_amdgcn_sched_barrier(0); }
#define WLG    { asm volatile("s_waitcnt lgkmcnt(0)" ::: "memory");          \
                 __builtin_amdgcn_sched_barrier(0); }

#define STEPR(RR, RK, RD, RA, RB, RV, T)                                     \
  { float sa = fmaf(S.w, RA.w, fmaf(S.z, RA.z,                               \
               fmaf(S.y, RA.y, S.x * RA.x)));                                \
    sa = red16(sa);                                                          \
    float vv = RV;                                                           \
    S.x = fmaf(S.x, RD.x, fmaf(sa, RB.x, vv * RK.x));                        \
    S.y = fmaf(S.y, RD.y, fmaf(sa, RB.y, vv * RK.y));                        \
    S.z = fmaf(S.z, RD.z, fmaf(sa, RB.z, vv * RK.z));                        \
    S.w = fmaf(S.w, RD.w, fmaf(sa, RB.w, vv * RK.w));                        \
    float y = fmaf(S.w, RR.w, fmaf(S.z, RR.z,                                \
              fmaf(S.y, RR.y, S.x * RR.x)));                                 \
    y = red16(y);                                                            \
    if (writer) yout[(size_t)(T) * CC] = y; }

  // prologue: DMA tokens 0..15 (32 vmem ops in flight)
  for (int tt = 0; tt < 16; ++tt) DMAQ(tt)

  f32x4 Ar, Ak, Ad, Aa, Ab; float Av;
  f32x4 Br, Bk, Bd, Ba, Bb; float Bv;

  WVM(24)                      // token 0 landed (30 ops after it; 6 slack)
  DSRD(Ar, Ak, Ad, Aa, Ab, Av, 0)
  WLG

  int t = 0;
  // warm-up pairs: t = 0..15 (prologue-issued tokens; exact budget 30+t)
  for (; t < 16; t += 2) {
    DMAQ(t + 16)
    WVM(24)
    DSRD(Br, Bk, Bd, Ba, Bb, Bv, t + 1)
    STEPR(Ar, Ak, Ad, Aa, Ab, Av, t)
    WLG
    DMAQ(t + 17)
    WVM(24)
    DSRD(Ar, Ak, Ad, Aa, Ab, Av, t + 2)
    STEPR(Br, Bk, Bd, Ba, Bb, Bv, t + 1)
    WLG
  }
  // steady pairs: t = 16..1006 (budget 45; 5 slack)
  for (; t < TT - 16; t += 2) {
    DMAQ(t + 16)
    WVM(40)
    DSRD(Br, Bk, Bd, Ba, Bb, Bv, t + 1)
    STEPR(Ar, Ak, Ad, Aa, Ab, Av, t)
    WLG
    DMAQ(t + 17)
    WVM(40)
    DSRD(Ar, Ak, Ad, Aa, Ab, Av, t + 2)
    STEPR(Br, Bk, Bd, Ba, Bb, Bv, t + 1)
    WLG
  }
  // drain, then waitless tail: t = 1008..1023 (all data resident in LDS)
  asm volatile("s_waitcnt vmcnt(0)" ::: "memory");
  __builtin_amdgcn_sched_barrier(0);
  for (; t < TT; t += 2) {
    DSRD(Br, Bk, Bd, Ba, Bb, Bv, t + 1)
    STEPR(Ar, Ak, Ad, Aa, Ab, Av, t)
    WLG
    if (t + 2 < TT) DSRD(Ar, Ak, Ad, Aa, Ab, Av, t + 2)
    STEPR(Br, Bk, Bd, Ba, Bb, Bv, t + 1)
    WLG
  }
#undef DMAQ
#undef DSRD
#undef WVM
#undef WLG
#undef STEPR
}

// ---------------------------------------------------------------------------
// K8: post-scan epilogue: GroupNorm + bonus + g-gate, fully parallel.
// ---------------------------------------------------------------------------
__global__ __launch_bounds__(256) void k_post(
    const float* __restrict__ ybuf, const float* __restrict__ vb,
    const float* __restrict__ gvb, const float* __restrict__ bonb,
    const float* __restrict__ gnw, const float* __restrict__ gnb,
    __hip_bfloat16* __restrict__ xoh, __hip_bfloat16* __restrict__ xol) {
  int tid = threadIdx.x, wv = tid >> 6, lane = tid & 63;
  int id = blockIdx.x * 4 + wv;        // 0..BT*HH-1
  int bt = id >> 5, h = id & 31;
  size_t base = (size_t)bt * CC + h * 64 + lane;
  float y = ybuf[base];
  float s1 = y, s2 = y * y;
#pragma unroll
  for (int off = 1; off < 64; off <<= 1) {
    s1 += __shfl_xor(s1, off);
    s2 += __shfl_xor(s2, off);
  }
  float mean = s1 * (1.0f / 64.0f);
  float var  = s2 * (1.0f / 64.0f) - mean * mean;
  float inv  = rsqrtf(var + GN_EPS);
  float x = fmaf((y - mean) * inv, gnw[h * 64 + lane], gnb[h * 64 + lane])
          + bonb[bt * HH + h] * vb[base];
  split_bf16(x * gvb[base], xoh[base], xol[base]);
}

// ---------------------------------------------------------------------------
extern "C" void kernel_launch(void* const* d_in, const int* in_sizes, int n_in,
                              void* d_out, int out_size, void* d_ws, size_t ws_size,
                              hipStream_t stream) {
  (void)in_sizes; (void)n_in; (void)out_size; (void)ws_size;
  const float* hid    = (const float*)d_in[0];
  const float* shift  = (const float*)d_in[1];
  const float* st0    = (const float*)d_in[2];
  const float* vfirst = (const float*)d_in[3];
  const float* xrc = (const float*)d_in[4];
  const float* xwc = (const float*)d_in[5];
  const float* xkc = (const float*)d_in[6];
  const float* xvc = (const float*)d_in[7];
  const float* xac = (const float*)d_in[8];
  const float* xgc = (const float*)d_in[9];
  const float* w0  = (const float*)d_in[10];
  const float* w1  = (const float*)d_in[11];
  const float* w2  = (const float*)d_in[12];
  const float* a0  = (const float*)d_in[13];
  const float* a1  = (const float*)d_in[14];
  const float* a2  = (const float*)d_in[15];
  const float* v0  = (const float*)d_in[16];
  const float* v1  = (const float*)d_in[17];
  const float* v2  = (const float*)d_in[18];
  const float* g1  = (const float*)d_in[19];
  const float* g2  = (const float*)d_in[20];
  const float* kkc = (const float*)d_in[21];
  const float* kac = (const float*)d_in[22];
  const float* rk  = (const float*)d_in[23];
  const float* Wr  = (const float*)d_in[24];
  const float* Wk  = (const float*)d_in[25];
  const float* Wv  = (const float*)d_in[26];
  const float* Wo  = (const float*)d_in[27];
  const float* gnw = (const float*)d_in[28];
  const float* gnb = (const float*)d_in[29];
  float* out = (float*)d_out;

  char* p = (char*)d_ws;
  auto alloc = [&](size_t n) { char* q = p; p += (n + 255) & ~(size_t)255; return q; };
  const size_t EL = (size_t)BT * CC;

  // --- alias pool: xrh..xvl + Wrh,Wrl dead by k_gate time; db/awb/bwb +
  //     h2g (the old gvb slot) overlay them.
  char* pool = p;
  __hip_bfloat16* xrh = (__hip_bfloat16*)alloc(EL * 2);
  __hip_bfloat16* xrl = (__hip_bfloat16*)alloc(EL * 2);
  __hip_bfloat16* xkh = (__hip_bfloat16*)alloc(EL * 2);
  __hip_bfloat16* xkl = (__hip_bfloat16*)alloc(EL * 2);
  __hip_bfloat16* xvh = (__hip_bfloat16*)alloc(EL * 2);
  __hip_bfloat16* xvl = (__hip_bfloat16*)alloc(EL * 2);
  __hip_bfloat16* Wrh = (__hip_bfloat16*)alloc((size_t)CC * CC * 2);
  __hip_bfloat16* Wrl = (__hip_bfloat16*)alloc((size_t)CC * CC * 2);
  float* db  = (float*)pool;           // overlays xrh+xrl
  float* awb = db + EL;                // overlays xkh+xkl
  float* bwb = db + 2 * EL;            // overlays xvh+xvl
  float* h2g = db + 3 * EL;            // overlays Wrh+Wrl (old gvb slot)

  __hip_bfloat16* Wkh = (__hip_bfloat16*)alloc((size_t)CC * CC * 2);
  __hip_bfloat16* Wkl = (__hip_bfloat16*)alloc((size_t)CC * CC * 2);
  float* ybuf = (float*)Wkh;           // overlays Wkh+Wkl (dead after k-GEMM)
  float* h2v  = (float*)Wkh;           // same region, read by k_gate BEFORE scan writes ybuf

  __hip_bfloat16* Wvh = (__hip_bfloat16*)alloc((size_t)CC * CC * 2);
  __hip_bfloat16* Wvl = (__hip_bfloat16*)alloc((size_t)CC * CC * 2);
  __hip_bfloat16* Woh = (__hip_bfloat16*)alloc((size_t)CC * CC * 2);
  __hip_bfloat16* Wol = (__hip_bfloat16*)alloc((size_t)CC * CC * 2);
  __hip_bfloat16* xw  = (__hip_bfloat16*)alloc(EL * 2);
  __hip_bfloat16* xa  = (__hip_bfloat16*)alloc(EL * 2);
  __hip_bfloat16* xg  = (__hip_bfloat16*)alloc(EL * 2);
  float* h2w = (float*)xw;             // overlays xw+xa (dead after stage-1 GEMMs)
  __hip_bfloat16* w1t = (__hip_bfloat16*)alloc((size_t)64  * CC * 2);
  __hip_bfloat16* a1t = (__hip_bfloat16*)alloc((size_t)64  * CC * 2);
  __hip_bfloat16* v1t = (__hip_bfloat16*)alloc((size_t)64  * CC * 2);
  __hip_bfloat16* g1t = (__hip_bfloat16*)alloc((size_t)128 * CC * 2);
  float* rb  = (float*)alloc(EL * 4);
  float* kb  = (float*)alloc(EL * 4);  // raw k, then k_final in place
  float* vb  = (float*)alloc(EL * 4);  // raw v, then v_mix in place
  float* h1w = (float*)alloc((size_t)BT * 64  * 4);
  float* h1a = (float*)alloc((size_t)BT * 64  * 4);
  float* h1v = (float*)alloc((size_t)BT * 64  * 4);
  float* h1g = (float*)alloc((size_t)BT * 128 * 4);
  __hip_bfloat16* xoh = (__hip_bfloat16*)alloc(EL * 2);
  __hip_bfloat16* xol = (__hip_bfloat16*)alloc(EL * 2);
  float* h2a = (float*)xoh;            // overlays xoh+xol (k_post writes them AFTER k_gate)
  float* bonb = (float*)alloc((size_t)BT * HH * 4);   // per-(token,head) bonus
  // stage-2 split operands (small, fresh):
  __hip_bfloat16* h1wh = (__hip_bfloat16*)alloc((size_t)BT * 64 * 2);
  __hip_bfloat16* h1wl = (__hip_bfloat16*)alloc((size_t)BT * 64 * 2);
  __hip_bfloat16* h1ah = (__hip_bfloat16*)alloc((size_t)BT * 64 * 2);
  __hip_bfloat16* h1al = (__hip_bfloat16*)alloc((size_t)BT * 64 * 2);
  __hip_bfloat16* h1vh = (__hip_bfloat16*)alloc((size_t)BT * 64 * 2);
  __hip_bfloat16* h1vl = (__hip_bfloat16*)alloc((size_t)BT * 64 * 2);
  __hip_bfloat16* h1gh = (__hip_bfloat16*)alloc((size_t)BT * 128 * 2);
  __hip_bfloat16* h1gl = (__hip_bfloat16*)alloc((size_t)BT * 128 * 2);
  __hip_bfloat16* w2th = (__hip_bfloat16*)alloc((size_t)CC * 64 * 2);
  __hip_bfloat16* w2tl = (__hip_bfloat16*)alloc((size_t)CC * 64 * 2);
  __hip_bfloat16* a2th = (__hip_bfloat16*)alloc((size_t)CC * 64 * 2);
  __hip_bfloat16* a2tl = (__hip_bfloat16*)alloc((size_t)CC * 64 * 2);
  __hip_bfloat16* v2th = (__hip_bfloat16*)alloc((size_t)CC * 64 * 2);
  __hip_bfloat16* v2tl = (__hip_bfloat16*)alloc((size_t)CC * 64 * 2);
  __hip_bfloat16* g2th = (__hip_bfloat16*)alloc((size_t)CC * 128 * 2);
  __hip_bfloat16* g2tl = (__hip_bfloat16*)alloc((size_t)CC * 128 * 2);
  // total ~210 MiB (known-OK envelope: 220 OK, 268 crashed)

  k_prepx<<<16384, 256, 0, stream>>>(hid, shift, xrc, xwc, xkc, xvc, xac, xgc,
                                     xrh, xrl, xw, xkh, xkl, xvh, xvl, xa, xg);
  k_cvt2<<<16384, 256, 0, stream>>>(Wr, Wrh, Wrl);
  k_cvt2<<<16384, 256, 0, stream>>>(Wk, Wkh, Wkl);
  k_cvt2<<<16384, 256, 0, stream>>>(Wv, Wvh, Wvl);
  k_cvt2<<<16384, 256, 0, stream>>>(Wo, Woh, Wol);
  k_tr<<<512, 256, 0, stream>>>(w1, w1t, 64);
  k_tr<<<512, 256, 0, stream>>>(a1, a1t, 64);
  k_tr<<<512, 256, 0, stream>>>(v1, v1t, 32);
  k_tr<<<1024, 256, 0, stream>>>(g1, g1t, 128);
  k_trs<<<512, 256, 0, stream>>>(w2, w2th, w2tl, 64, 6);
  k_trs<<<512, 256, 0, stream>>>(a2, a2th, a2tl, 64, 6);
  k_trs<<<512, 256, 0, stream>>>(v2, v2th, v2tl, 32, 6);   // padded K=64
  k_trs<<<1024, 256, 0, stream>>>(g2, g2th, g2tl, 128, 7);

  k_gemm_bt3<<<dim3(32, 32), 256, 0, stream>>>(xrh, xrl, Wrh, Wrl, rb, BT, CC, CC);
  k_gemm_bt3<<<dim3(32, 32), 256, 0, stream>>>(xkh, xkl, Wkh, Wkl, kb, BT, CC, CC);
  k_gemm_bt3<<<dim3(32, 32), 256, 0, stream>>>(xvh, xvl, Wvh, Wvl, vb, BT, CC, CC);
  k_lora1<<<dim3(32, 5), 256, 0, stream>>>(xw, xa, xvh, xg, w1t, a1t, v1t, g1t,
                                           h1w, h1a, h1v, h1g);

  k_act2<<<1024, 256, 0, stream>>>(h1w, h1a, h1v, h1g,
                                   h1wh, h1wl, h1ah, h1al,
                                   h1vh, h1vl, h1gh, h1gl);
  // stage-2 LoRA dots on MFMA (split precision). Overlays now live:
  //   h2w->xw+xa, h2a->xoh+xol, h2v->Wkh+Wkl, h2g->Wrh+Wrl.
  k_gemm_bt3<<<dim3(32, 32), 256, 0, stream>>>(h1wh, h1wl, w2th, w2tl, h2w, BT, CC, 64);
  k_gemm_bt3<<<dim3(32, 32), 256, 0, stream>>>(h1ah, h1al, a2th, a2tl, h2a, BT, CC, 64);
  k_gemm_bt3<<<dim3(32, 32), 256, 0, stream>>>(h1vh, h1vl, v2th, v2tl, h2v, BT, CC, 64);
  k_gemm_bt3<<<dim3(32, 32), 256, 0, stream>>>(h1gh, h1gl, g2th, g2tl, h2g, BT, CC, 128);

  k_gate<<<16384, 256, 0, stream>>>(h2w, h2a, h2v, w0, a0, v0, kkc, kac,
                                    kb, vb, vfirst, rb, rk, db, awb, bwb, bonb);
  k_scan<<<1024, 64, 0, stream>>>(rb, kb, db, awb, bwb, vb, st0, ybuf);
  k_post<<<16384, 256, 0, stream>>>(ybuf, vb, h2g, bonb, gnw, gnb, xoh, xol);
  k_gemm_bt3<<<dim3(32, 32), 256, 0, stream>>>(xoh, xol, Woh, Wol, out, BT, CC, CC);
}

// Round 12
// 800.819 us; speedup vs baseline: 1.3607x; 1.1782x over previous
//
#include <hip/hip_runtime.h>
#include <hip/hip_bf16.h>

// Problem constants (RWKV-7 Tmix: B=2, T=1024, C=2048, H=32, N=64)
#define BB 2
#define TT 1024
#define CC 2048
#define HH 32
#define BT 2048          // BB*TT tokens
#define GN_EPS 6.4e-4f   // 1e-5 * 8^2

typedef __attribute__((ext_vector_type(8))) __bf16 bf16x8;
typedef __attribute__((ext_vector_type(4))) float f32x4;

__device__ __forceinline__ float sigf(float x) { return 1.0f / (1.0f + expf(-x)); }

__device__ __forceinline__ void split_bf16(float x, __hip_bfloat16& hi, __hip_bfloat16& lo) {
  __hip_bfloat16 h = __float2bfloat16(x);
  hi = h;
  lo = __float2bfloat16(x - __bfloat162float(h));
}

// Sum over each aligned 16-lane group, pure DPP (no LDS pipe on the chain).
__device__ __forceinline__ float red16(float x) {
  x += __int_as_float(__builtin_amdgcn_update_dpp(
      0, __float_as_int(x), 0xB1 /*quad_perm [1,0,3,2]*/, 0xF, 0xF, true));
  x += __int_as_float(__builtin_amdgcn_update_dpp(
      0, __float_as_int(x), 0x4E /*quad_perm [2,3,0,1]*/, 0xF, 0xF, true));
  x += __int_as_float(__builtin_amdgcn_update_dpp(
      0, __float_as_int(x), 0x141 /*row_half_mirror*/, 0xF, 0xF, true));
  x += __int_as_float(__builtin_amdgcn_update_dpp(
      0, __float_as_int(x), 0x140 /*row_mirror*/, 0xF, 0xF, true));
  return x;
}

// ---------------------------------------------------------------------------
// K1: token shift + six lerped projections. r/k/v hi+lo split; w/a/g bf16.
// ---------------------------------------------------------------------------
__global__ __launch_bounds__(256) void k_prepx(
    const float* __restrict__ hid, const float* __restrict__ shift,
    const float* __restrict__ xrc, const float* __restrict__ xwc,
    const float* __restrict__ xkc, const float* __restrict__ xvc,
    const float* __restrict__ xac, const float* __restrict__ xgc,
    __hip_bfloat16* __restrict__ xrh, __hip_bfloat16* __restrict__ xrl,
    __hip_bfloat16* __restrict__ xw,
    __hip_bfloat16* __restrict__ xkh, __hip_bfloat16* __restrict__ xkl,
    __hip_bfloat16* __restrict__ xvh, __hip_bfloat16* __restrict__ xvl,
    __hip_bfloat16* __restrict__ xa, __hip_bfloat16* __restrict__ xg) {
  int idx = blockIdx.x * 256 + threadIdx.x;   // < BT*CC
  int c  = idx & (CC - 1);
  int bt = idx >> 11;
  int t  = bt & (TT - 1);
  int b  = bt >> 10;
  float hcur  = hid[idx];
  float hprev = (t == 0) ? shift[b * CC + c] : hid[idx - CC];
  float xx = hprev - hcur;
  split_bf16(fmaf(xx, xrc[c], hcur), xrh[idx], xrl[idx]);
  split_bf16(fmaf(xx, xkc[c], hcur), xkh[idx], xkl[idx]);
  split_bf16(fmaf(xx, xvc[c], hcur), xvh[idx], xvl[idx]);
  xw[idx] = __float2bfloat16(fmaf(xx, xwc[c], hcur));
  xa[idx] = __float2bfloat16(fmaf(xx, xac[c], hcur));
  xg[idx] = __float2bfloat16(fmaf(xx, xgc[c], hcur));
}

// ---------------------------------------------------------------------------
// K2: f32 -> hi+lo bf16 split for all four big weights, one dispatch.
// ---------------------------------------------------------------------------
__global__ __launch_bounds__(256) void k_cvt2x4(
    const float* __restrict__ i0, const float* __restrict__ i1,
    const float* __restrict__ i2, const float* __restrict__ i3,
    __hip_bfloat16* __restrict__ h0, __hip_bfloat16* __restrict__ l0,
    __hip_bfloat16* __restrict__ h1, __hip_bfloat16* __restrict__ l1,
    __hip_bfloat16* __restrict__ h2, __hip_bfloat16* __restrict__ l2,
    __hip_bfloat16* __restrict__ h3, __hip_bfloat16* __restrict__ l3) {
  int i = blockIdx.x * 256 + threadIdx.x;
  int w = blockIdx.y;
  const float* in = (w == 0) ? i0 : (w == 1) ? i1 : (w == 2) ? i2 : i3;
  __hip_bfloat16* oh = (w == 0) ? h0 : (w == 1) ? h1 : (w == 2) ? h2 : h3;
  __hip_bfloat16* ol = (w == 0) ? l0 : (w == 1) ? l1 : (w == 2) ? l2 : l3;
  split_bf16(in[i], oh[i], ol[i]);
}

// ---------------------------------------------------------------------------
// K3: transpose-convert small LoRA "up" weights: in [2048][N0] f32 ->
//     out [NP][2048] bf16 (rows >= N0 zero-padded).  (stage-1 B operands)
// ---------------------------------------------------------------------------
__global__ __launch_bounds__(256) void k_tr(const float* __restrict__ in,
                                            __hip_bfloat16* __restrict__ out,
                                            int N0) {
  int i = blockIdx.x * 256 + threadIdx.x;   // over NP*2048, grid exact
  int n = i >> 11;
  int k = i & 2047;
  float v = (n < N0) ? in[k * N0 + n] : 0.0f;
  out[i] = __float2bfloat16(v);
}

// ---------------------------------------------------------------------------
// K3b: transpose + hi/lo split of stage-2 "down" weights:
//   in [N0][CC] f32 -> out [CC][K0] bf16 hi+lo (K0 = 1<<lgK, rows>=N0 zero).
// ---------------------------------------------------------------------------
__global__ __launch_bounds__(256) void k_trs(const float* __restrict__ in,
                                             __hip_bfloat16* __restrict__ oh,
                                             __hip_bfloat16* __restrict__ ol,
                                             int N0, int lgK) {
  int i = blockIdx.x * 256 + threadIdx.x;   // over CC*K0, grid exact
  int n = i >> lgK;
  int k = i & ((1 << lgK) - 1);
  float v = (k < N0) ? in[k * CC + n] : 0.0f;
  split_bf16(v, oh[i], ol[i]);
}

// ---------------------------------------------------------------------------
// K4: fused stage-1 LoRA GEMM, LDS-staged (r11 winner, unchanged).
// grid (32 M-tiles, 5 slices): {xw*w1, xa*a1, xv*v1, xg*g1[0:64], xg*g1[64:128]}
// ---------------------------------------------------------------------------
__global__ __launch_bounds__(256, 4) void k_lora1(
    const __hip_bfloat16* __restrict__ xw, const __hip_bfloat16* __restrict__ xa,
    const __hip_bfloat16* __restrict__ xv, const __hip_bfloat16* __restrict__ xg,
    const __hip_bfloat16* __restrict__ w1t, const __hip_bfloat16* __restrict__ a1t,
    const __hip_bfloat16* __restrict__ v1t, const __hip_bfloat16* __restrict__ g1t,
    float* __restrict__ h1w, float* __restrict__ h1a,
    float* __restrict__ h1v, float* __restrict__ h1g) {
  __shared__ __align__(16) __hip_bfloat16 sA[2][64 * 32], sB[2][64 * 32];
  int tid  = threadIdx.x;
  int lane = tid & 63;
  int wv   = tid >> 6;
  int l15  = lane & 15;
  int quad = lane >> 4;
  int m0 = blockIdx.x * 64;
  int bly = blockIdx.y;

  const __hip_bfloat16* Ab;
  const __hip_bfloat16* Bb;
  float* Ob;
  int os, cb;
  if (bly == 0)      { Ab = xw; Bb = w1t;            Ob = h1w; os = 64;  cb = 0;  }
  else if (bly == 1) { Ab = xa; Bb = a1t;            Ob = h1a; os = 64;  cb = 0;  }
  else if (bly == 2) { Ab = xv; Bb = v1t;            Ob = h1v; os = 64;  cb = 0;  }
  else if (bly == 3) { Ab = xg; Bb = g1t;            Ob = h1g; os = 128; cb = 0;  }
  else               { Ab = xg; Bb = g1t + 64 * CC;  Ob = h1g; os = 128; cb = 64; }

  int srow = wv * 16 + (lane >> 2);
  int scol = (lane & 3) * 8;
  const __hip_bfloat16* gA = Ab + (size_t)(m0 + srow) * CC + scol;
  const __hip_bfloat16* gB = Bb + (size_t)srow * CC + scol;

  f32x4 z = {0.f, 0.f, 0.f, 0.f};
  f32x4 acc0 = z, acc1 = z, acc2 = z, acc3 = z;

  int aoff = (wv * 16 + l15) * 32 + quad * 8;
  int boff = l15 * 32 + quad * 8;

#define STAGE1(BUF, KO)                                                      \
  { unsigned db_ = (unsigned)(BUF) * 4096u + (unsigned)wv * 1024u;           \
    __builtin_amdgcn_global_load_lds(                                        \
        (const __attribute__((address_space(1))) void*)(gA + (KO)),          \
        (__attribute__((address_space(3))) void*)((char*)sA + db_), 16, 0, 0);\
    __builtin_amdgcn_global_load_lds(                                        \
        (const __attribute__((address_space(1))) void*)(gB + (KO)),          \
        (__attribute__((address_space(3))) void*)((char*)sB + db_), 16, 0, 0);}

  STAGE1(0, 0)
  __syncthreads();

  for (int k0 = 0; k0 < CC; k0 += 32) {
    int cur = (k0 >> 5) & 1;
    if (k0 + 32 < CC) STAGE1(cur ^ 1, k0 + 32)

    const __hip_bfloat16* pA_ = &sA[cur][0];
    const __hip_bfloat16* pB_ = &sB[cur][0];
    bf16x8 av = *(const bf16x8*)(pA_ + aoff);
    bf16x8 b0 = *(const bf16x8*)(pB_ + boff);
    bf16x8 b1 = *(const bf16x8*)(pB_ + boff + 16 * 32);
    bf16x8 b2 = *(const bf16x8*)(pB_ + boff + 32 * 32);
    bf16x8 b3 = *(const bf16x8*)(pB_ + boff + 48 * 32);

    acc0 = __builtin_amdgcn_mfma_f32_16x16x32_bf16(av, b0, acc0, 0, 0, 0);
    acc1 = __builtin_amdgcn_mfma_f32_16x16x32_bf16(av, b1, acc1, 0, 0, 0);
    acc2 = __builtin_amdgcn_mfma_f32_16x16x32_bf16(av, b2, acc2, 0, 0, 0);
    acc3 = __builtin_amdgcn_mfma_f32_16x16x32_bf16(av, b3, acc3, 0, 0, 0);

    __syncthreads();
  }
#undef STAGE1

  int row0 = m0 + wv * 16 + quad * 4;
  int colb = cb + l15;
#pragma unroll
  for (int r = 0; r < 4; ++r) {
    Ob[(size_t)(row0 + r) * os + colb +  0] = acc0[r];
    Ob[(size_t)(row0 + r) * os + colb + 16] = acc1[r];
    Ob[(size_t)(row0 + r) * os + colb + 32] = acc2[r];
    Ob[(size_t)(row0 + r) * os + colb + 48] = acc3[r];
  }
}

// ---------------------------------------------------------------------------
// K4b: split-precision GEMM — ROUND-19: tile widened to 64x128.
// 64x64 tiles staged 16KB LDS per 0.79 MFLOP (intensity 50 FLOP/B through
// the DMA path) and paid one barrier per 12 MFMAs/wave (MfmaUtil 11%, ~560
// TF effective). 64x128: per wave per K-step 6 DMA / 18 ds_read / 24 MFMA
// -> 2x flops per barrier, 2.6x staged-bytes intensity. LDS 48KB (A 2x8KB,
// B 2x16KB) -> 3 blocks/CU; (256,3) caps VGPR at ~168 (need ~125, no
// round-8-style collapse). Per-acc product order unchanged (bitwise same).
// ---------------------------------------------------------------------------
__global__ __launch_bounds__(256, 3) void k_gemm_bt3(
    const __hip_bfloat16* __restrict__ Ah, const __hip_bfloat16* __restrict__ Al,
    const __hip_bfloat16* __restrict__ Bh, const __hip_bfloat16* __restrict__ Bl,
    float* __restrict__ Cm, int M, int Nn, int K) {
  __shared__ __align__(16) __hip_bfloat16 sAh[2][64 * 32],  sAl[2][64 * 32];
  __shared__ __align__(16) __hip_bfloat16 sBh[2][128 * 32], sBl[2][128 * 32];
  int tid  = threadIdx.x;
  int lane = tid & 63;
  int wv   = tid >> 6;
  int l15  = lane & 15;
  int quad = lane >> 4;
  int m0 = blockIdx.x * 64;
  int n0 = blockIdx.y * 128;

  // A staging: wave wv -> rows wv*16..+15 (one 1KB DMA per array).
  // B staging: wave wv -> rows wv*32..+31 (two 1KB DMAs per array).
  int srowA = wv * 16 + (lane >> 2);
  int srowB = wv * 32 + (lane >> 2);
  int scol  = (lane & 3) * 8;
  const __hip_bfloat16* gAh  = Ah + (size_t)(m0 + srowA) * K + scol;
  const __hip_bfloat16* gAl  = Al + (size_t)(m0 + srowA) * K + scol;
  const __hip_bfloat16* gBh0 = Bh + (size_t)(n0 + srowB) * K + scol;
  const __hip_bfloat16* gBh1 = Bh + (size_t)(n0 + srowB + 16) * K + scol;
  const __hip_bfloat16* gBl0 = Bl + (size_t)(n0 + srowB) * K + scol;
  const __hip_bfloat16* gBl1 = Bl + (size_t)(n0 + srowB + 16) * K + scol;

  f32x4 z = {0.f, 0.f, 0.f, 0.f};
  f32x4 acc[8];
#pragma unroll
  for (int j = 0; j < 8; ++j) acc[j] = z;

  int aoff = (wv * 16 + l15) * 32 + quad * 8;
  int boff = l15 * 32 + quad * 8;

#define STAGE(BUF, KO)                                                       \
  { unsigned dA_ = (unsigned)(BUF) * 4096u + (unsigned)wv * 1024u;           \
    unsigned dB_ = (unsigned)(BUF) * 8192u + (unsigned)wv * 2048u;           \
    __builtin_amdgcn_global_load_lds(                                        \
        (const __attribute__((address_space(1))) void*)(gAh + (KO)),         \
        (__attribute__((address_space(3))) void*)((char*)sAh + dA_), 16, 0, 0);\
    __builtin_amdgcn_global_load_lds(                                        \
        (const __attribute__((address_space(1))) void*)(gAl + (KO)),         \
        (__attribute__((address_space(3))) void*)((char*)sAl + dA_), 16, 0, 0);\
    __builtin_amdgcn_global_load_lds(                                        \
        (const __attribute__((address_space(1))) void*)(gBh0 + (KO)),        \
        (__attribute__((address_space(3))) void*)((char*)sBh + dB_), 16, 0, 0);\
    __builtin_amdgcn_global_load_lds(                                        \
        (const __attribute__((address_space(1))) void*)(gBh1 + (KO)),        \
        (__attribute__((address_space(3))) void*)((char*)sBh + dB_ + 1024u), 16, 0, 0);\
    __builtin_amdgcn_global_load_lds(                                        \
        (const __attribute__((address_space(1))) void*)(gBl0 + (KO)),        \
        (__attribute__((address_space(3))) void*)((char*)sBl + dB_), 16, 0, 0);\
    __builtin_amdgcn_global_load_lds(                                        \
        (const __attribute__((address_space(1))) void*)(gBl1 + (KO)),        \
        (__attribute__((address_space(3))) void*)((char*)sBl + dB_ + 1024u), 16, 0, 0);}

  STAGE(0, 0)
  __syncthreads();   // buf0 staged (implicit vmcnt(0) drain before barrier)

  for (int k0 = 0; k0 < K; k0 += 32) {
    int cur = (k0 >> 5) & 1;
    if (k0 + 32 < K) STAGE(cur ^ 1, k0 + 32)   // next tile in flight NOW

    const __hip_bfloat16* pA_h = &sAh[cur][0];
    const __hip_bfloat16* pA_l = &sAl[cur][0];
    const __hip_bfloat16* pB_h = &sBh[cur][0];
    const __hip_bfloat16* pB_l = &sBl[cur][0];
    bf16x8 ah = *(const bf16x8*)(pA_h + aoff);
    bf16x8 al = *(const bf16x8*)(pA_l + aoff);
#pragma unroll
    for (int j = 0; j < 8; ++j) {
      bf16x8 bh = *(const bf16x8*)(pB_h + boff + j * 16 * 32);
      bf16x8 bl = *(const bf16x8*)(pB_l + boff + j * 16 * 32);
      acc[j] = __builtin_amdgcn_mfma_f32_16x16x32_bf16(ah, bh, acc[j], 0, 0, 0);
      acc[j] = __builtin_amdgcn_mfma_f32_16x16x32_bf16(ah, bl, acc[j], 0, 0, 0);
      acc[j] = __builtin_amdgcn_mfma_f32_16x16x32_bf16(al, bh, acc[j], 0, 0, 0);
    }

    __syncthreads();   // ONE barrier: next buf staged + this buf reads done
  }
#undef STAGE

  int row0 = m0 + wv * 16 + quad * 4;
#pragma unroll
  for (int j = 0; j < 8; ++j) {
    int colb = n0 + j * 16 + l15;
#pragma unroll
    for (int r = 0; r < 4; ++r)
      Cm[(size_t)(row0 + r) * Nn + colb] = acc[j][r];
  }
}

// ---------------------------------------------------------------------------
// K5: activations + hi/lo split of stage-1 LoRA outputs (MFMA stage-2 prep).
// ---------------------------------------------------------------------------
__global__ __launch_bounds__(256) void k_act2(
    const float* __restrict__ h1w, const float* __restrict__ h1a,
    const float* __restrict__ h1v, const float* __restrict__ h1g,
    __hip_bfloat16* __restrict__ wh, __hip_bfloat16* __restrict__ wl,
    __hip_bfloat16* __restrict__ ah, __hip_bfloat16* __restrict__ al,
    __hip_bfloat16* __restrict__ vh, __hip_bfloat16* __restrict__ vl,
    __hip_bfloat16* __restrict__ gh, __hip_bfloat16* __restrict__ gl) {
  int i = blockIdx.x * 256 + threadIdx.x;   // grid covers BT*128 exactly
  if (i < BT * 64) {
    split_bf16(tanhf(h1w[i]), wh[i], wl[i]);
    split_bf16(h1a[i], ah[i], al[i]);
    split_bf16(h1v[i], vh[i], vl[i]);
  }
  split_bf16(sigf(h1g[i]), gh[i], gl[i]);
}

// ---------------------------------------------------------------------------
// K6: elementwise gates + kk-normalize + per-head bonus. wave == head.
// ---------------------------------------------------------------------------
__global__ __launch_bounds__(256) void k_gate(
    const float* __restrict__ h2w, const float* __restrict__ h2a,
    const float* __restrict__ h2v,
    const float* __restrict__ w0, const float* __restrict__ a0,
    const float* __restrict__ v0, const float* __restrict__ kkc,
    const float* __restrict__ kac, float* __restrict__ kbuf,
    float* __restrict__ vbuf, const float* __restrict__ vfirst,
    const float* __restrict__ rbuf, const float* __restrict__ rk,
    float* __restrict__ dec, float* __restrict__ aw,
    float* __restrict__ bw, float* __restrict__ bonb) {
  int idx = blockIdx.x * 256 + threadIdx.x;   // < BT*CC
  int c = idx & (CC - 1);
  float kv = kbuf[idx], vv = vbuf[idx], vf = vfirst[idx];
  float d_ = 0.60653065971f * sigf(w0[c] + h2w[idx]);   // sigmoid * e^-0.5
  float as = sigf(a0[c] + h2a[idx]);
  float vs = sigf(v0[c] + h2v[idx]);
  float vm = vv + (vf - vv) * vs;
  float kfv = kv * (1.0f + kac[c] * (as - 1.0f));
  float kku = kv * kkc[c];
  float s = kku * kku;     // per-head L2 over 64 lanes (wave == head)
  s += __shfl_xor(s, 1);  s += __shfl_xor(s, 2);  s += __shfl_xor(s, 4);
  s += __shfl_xor(s, 8);  s += __shfl_xor(s, 16); s += __shfl_xor(s, 32);
  float nrm = fmaxf(sqrtf(s), 1e-12f);
  float kkn = kku / nrm;
  float bon = rbuf[idx] * kfv * rk[c];
  bon += __shfl_xor(bon, 1);  bon += __shfl_xor(bon, 2);
  bon += __shfl_xor(bon, 4);  bon += __shfl_xor(bon, 8);
  bon += __shfl_xor(bon, 16); bon += __shfl_xor(bon, 32);
  if ((threadIdx.x & 63) == 0) bonb[(idx >> 11) * HH + (c >> 6)] = bon;
  dec[idx] = d_;
  aw[idx]  = -kkn; bw[idx] = kkn * as;
  kbuf[idx] = kfv; vbuf[idx] = vm;
}

// ---------------------------------------------------------------------------
// K7: WKV7 scan — round-14 LDS-DMA-ring version (passing, ~184 µs), unchanged.
// ---------------------------------------------------------------------------
__global__ __launch_bounds__(64, 1) void k_scan(
    const float* __restrict__ rbuf, const float* __restrict__ kf,
    const float* __restrict__ dec, const float* __restrict__ aw,
    const float* __restrict__ bw, const float* __restrict__ vbuf,
    const float* __restrict__ st0, float* __restrict__ ybuf) {
  __shared__ __align__(16) char ldsbuf[16 * 2048];
  int blk = blockIdx.x;                     // 0..1023
  int xcd = blk & 7;
  int q   = blk >> 3;                       // 0..127
  int bh  = xcd * 8 + (q & 7);              // 16 rg-waves of a head share blk%8
  int rg  = q >> 3;                         // 0..15
  int b = bh >> 5, h = bh & 31;
  int lane = threadIdx.x;
  int l15  = lane & 15;
  int row  = rg * 4 + (lane >> 4);
  size_t tokbase = (size_t)b * TT * CC + h * 64;

  f32x4 S = *(const f32x4*)(st0 + ((size_t)bh * 64 + row) * 64 + l15 * 4);
  bool writer = (l15 == 0);
  float* yout = ybuf + tokbase + row;

  // per-lane DMA source pointers (advance +CC per token, all lanes uniform)
  const float* g1 = (lane < 16 ? rbuf : lane < 32 ? kf : lane < 48 ? dec : aw)
                  + tokbase + l15 * 4;
  const float* g2 = (lane < 16) ? (bw + tokbase + l15 * 4)
                                : (vbuf + tokbase + rg * 4);  // lanes>=16: v rows (16 real, rest pad)

  // LDS byte offsets (relative to workgroup LDS base)
  unsigned lbase = (unsigned)(uintptr_t)(__attribute__((address_space(3))) char*)ldsbuf;
  unsigned larr = lbase + (unsigned)(l15 * 16);          // +slot: arrays at 0/256/512/768/1024
  unsigned lvad = lbase + 1280u + (unsigned)((lane >> 4) * 4);  // +slot: v word

#define DMAQ(T)                                                              \
  { char* sb_ = ldsbuf + (((T) & 15) << 11);                                 \
    __builtin_amdgcn_global_load_lds(                                        \
        (const __attribute__((address_space(1))) void*)g1,                   \
        (__attribute__((address_space(3))) void*)sb_, 16, 0, 0);             \
    __builtin_amdgcn_global_load_lds(                                        \
        (const __attribute__((address_space(1))) void*)g2,                   \
        (__attribute__((address_space(3))) void*)(sb_ + 1024), 16, 0, 0);    \
    g1 += CC; g2 += CC; }

#define DSRD(RR, RK, RD, RA, RB, RV, T)                                      \
  { unsigned a_ = larr + (unsigned)(((T) & 15) << 11);                       \
    unsigned v_ = lvad + (unsigned)(((T) & 15) << 11);                       \
    asm volatile("ds_read_b128 %0, %1"             : "=v"(RR) : "v"(a_));    \
    asm volatile("ds_read_b128 %0, %1 offset:256"  : "=v"(RK) : "v"(a_));    \
    asm volatile("ds_read_b128 %0, %1 offset:512"  : "=v"(RD) : "v"(a_));    \
    asm volatile("ds_read_b128 %0, %1 offset:768"  : "=v"(RA) : "v"(a_));    \
    asm volatile("ds_read_b128 %0, %1 offset:1024" : "=v"(RB) : "v"(a_));    \
    asm volatile("ds_read_b32 %0, %1"              : "=v"(RV) : "v"(v_)); }

#define WVM(N) { asm volatile("s_waitcnt vmcnt(" #N ")" ::: "memory");       \
                 __builtin_amdgcn_sched_barrier(0); }
#define WLG    { asm volatile("s_waitcnt lgkmcnt(0)" ::: "memory");          \
                 __builtin_amdgcn_sched_barrier(0); }

#define STEPR(RR, RK, RD, RA, RB, RV, T)                                     \
  { float sa = fmaf(S.w, RA.w, fmaf(S.z, RA.z,                               \
               fmaf(S.y, RA.y, S.x * RA.x)));                                \
    sa = red16(sa);                                                          \
    float vv = RV;                                                           \
    S.x = fmaf(S.x, RD.x, fmaf(sa, RB.x, vv * RK.x));                        \
    S.y = fmaf(S.y, RD.y, fmaf(sa, RB.y, vv * RK.y));                        \
    S.z = fmaf(S.z, RD.z, fmaf(sa, RB.z, vv * RK.z));                        \
    S.w = fmaf(S.w, RD.w, fmaf(sa, RB.w, vv * RK.w));                        \
    float y = fmaf(S.w, RR.w, fmaf(S.z, RR.z,                                \
              fmaf(S.y, RR.y, S.x * RR.x)));                                 \
    y = red16(y);                                                            \
    if (writer) yout[(size_t)(T) * CC] = y; }

  // prologue: DMA tokens 0..15 (32 vmem ops in flight)
  for (int tt = 0; tt < 16; ++tt) DMAQ(tt)

  f32x4 Ar, Ak, Ad, Aa, Ab; float Av;
  f32x4 Br, Bk, Bd, Ba, Bb; float Bv;

  WVM(24)                      // token 0 landed (30 ops after it; 6 slack)
  DSRD(Ar, Ak, Ad, Aa, Ab, Av, 0)
  WLG

  int t = 0;
  // warm-up pairs: t = 0..15 (prologue-issued tokens; exact budget 30+t)
  for (; t < 16; t += 2) {
    DMAQ(t + 16)
    WVM(24)
    DSRD(Br, Bk, Bd, Ba, Bb, Bv, t + 1)
    STEPR(Ar, Ak, Ad, Aa, Ab, Av, t)
    WLG
    DMAQ(t + 17)
    WVM(24)
    DSRD(Ar, Ak, Ad, Aa, Ab, Av, t + 2)
    STEPR(Br, Bk, Bd, Ba, Bb, Bv, t + 1)
    WLG
  }
  // steady pairs: t = 16..1006 (budget 45; 5 slack)
  for (; t < TT - 16; t += 2) {
    DMAQ(t + 16)
    WVM(40)
    DSRD(Br, Bk, Bd, Ba, Bb, Bv, t + 1)
    STEPR(Ar, Ak, Ad, Aa, Ab, Av, t)
    WLG
    DMAQ(t + 17)
    WVM(40)
    DSRD(Ar, Ak, Ad, Aa, Ab, Av, t + 2)
    STEPR(Br, Bk, Bd, Ba, Bb, Bv, t + 1)
    WLG
  }
  // drain, then waitless tail: t = 1008..1023 (all data resident in LDS)
  asm volatile("s_waitcnt vmcnt(0)" ::: "memory");
  __builtin_amdgcn_sched_barrier(0);
  for (; t < TT; t += 2) {
    DSRD(Br, Bk, Bd, Ba, Bb, Bv, t + 1)
    STEPR(Ar, Ak, Ad, Aa, Ab, Av, t)
    WLG
    if (t + 2 < TT) DSRD(Ar, Ak, Ad, Aa, Ab, Av, t + 2)
    STEPR(Br, Bk, Bd, Ba, Bb, Bv, t + 1)
    WLG
  }
#undef DMAQ
#undef DSRD
#undef WVM
#undef WLG
#undef STEPR
}

// ---------------------------------------------------------------------------
// K8: post-scan epilogue: GroupNorm + bonus + g-gate, fully parallel.
// ---------------------------------------------------------------------------
__global__ __launch_bounds__(256) void k_post(
    const float* __restrict__ ybuf, const float* __restrict__ vb,
    const float* __restrict__ gvb, const float* __restrict__ bonb,
    const float* __restrict__ gnw, const float* __restrict__ gnb,
    __hip_bfloat16* __restrict__ xoh, __hip_bfloat16* __restrict__ xol) {
  int tid = threadIdx.x, wv = tid >> 6, lane = tid & 63;
  int id = blockIdx.x * 4 + wv;        // 0..BT*HH-1
  int bt = id >> 5, h = id & 31;
  size_t base = (size_t)bt * CC + h * 64 + lane;
  float y = ybuf[base];
  float s1 = y, s2 = y * y;
#pragma unroll
  for (int off = 1; off < 64; off <<= 1) {
    s1 += __shfl_xor(s1, off);
    s2 += __shfl_xor(s2, off);
  }
  float mean = s1 * (1.0f / 64.0f);
  float var  = s2 * (1.0f / 64.0f) - mean * mean;
  float inv  = rsqrtf(var + GN_EPS);
  float x = fmaf((y - mean) * inv, gnw[h * 64 + lane], gnb[h * 64 + lane])
          + bonb[bt * HH + h] * vb[base];
  split_bf16(x * gvb[base], xoh[base], xol[base]);
}

// ---------------------------------------------------------------------------
extern "C" void kernel_launch(void* const* d_in, const int* in_sizes, int n_in,
                              void* d_out, int out_size, void* d_ws, size_t ws_size,
                              hipStream_t stream) {
  (void)in_sizes; (void)n_in; (void)out_size; (void)ws_size;
  const float* hid    = (const float*)d_in[0];
  const float* shift  = (const float*)d_in[1];
  const float* st0    = (const float*)d_in[2];
  const float* vfirst = (const float*)d_in[3];
  const float* xrc = (const float*)d_in[4];
  const float* xwc = (const float*)d_in[5];
  const float* xkc = (const float*)d_in[6];
  const float* xvc = (const float*)d_in[7];
  const float* xac = (const float*)d_in[8];
  const float* xgc = (const float*)d_in[9];
  const float* w0  = (const float*)d_in[10];
  const float* w1  = (const float*)d_in[11];
  const float* w2  = (const float*)d_in[12];
  const float* a0  = (const float*)d_in[13];
  const float* a1  = (const float*)d_in[14];
  const float* a2  = (const float*)d_in[15];
  const float* v0  = (const float*)d_in[16];
  const float* v1  = (const float*)d_in[17];
  const float* v2  = (const float*)d_in[18];
  const float* g1  = (const float*)d_in[19];
  const float* g2  = (const float*)d_in[20];
  const float* kkc = (const float*)d_in[21];
  const float* kac = (const float*)d_in[22];
  const float* rk  = (const float*)d_in[23];
  const float* Wr  = (const float*)d_in[24];
  const float* Wk  = (const float*)d_in[25];
  const float* Wv  = (const float*)d_in[26];
  const float* Wo  = (const float*)d_in[27];
  const float* gnw = (const float*)d_in[28];
  const float* gnb = (const float*)d_in[29];
  float* out = (float*)d_out;

  char* p = (char*)d_ws;
  auto alloc = [&](size_t n) { char* q = p; p += (n + 255) & ~(size_t)255; return q; };
  const size_t EL = (size_t)BT * CC;

  // --- alias pool: xrh..xvl + Wrh,Wrl dead by k_gate time; db/awb/bwb +
  //     h2g (the old gvb slot) overlay them.
  char* pool = p;
  __hip_bfloat16* xrh = (__hip_bfloat16*)alloc(EL * 2);
  __hip_bfloat16* xrl = (__hip_bfloat16*)alloc(EL * 2);
  __hip_bfloat16* xkh = (__hip_bfloat16*)alloc(EL * 2);
  __hip_bfloat16* xkl = (__hip_bfloat16*)alloc(EL * 2);
  __hip_bfloat16* xvh = (__hip_bfloat16*)alloc(EL * 2);
  __hip_bfloat16* xvl = (__hip_bfloat16*)alloc(EL * 2);
  __hip_bfloat16* Wrh = (__hip_bfloat16*)alloc((size_t)CC * CC * 2);
  __hip_bfloat16* Wrl = (__hip_bfloat16*)alloc((size_t)CC * CC * 2);
  float* db  = (float*)pool;           // overlays xrh+xrl
  float* awb = db + EL;                // overlays xkh+xkl
  float* bwb = db + 2 * EL;            // overlays xvh+xvl
  float* h2g = db + 3 * EL;            // overlays Wrh+Wrl (old gvb slot)

  __hip_bfloat16* Wkh = (__hip_bfloat16*)alloc((size_t)CC * CC * 2);
  __hip_bfloat16* Wkl = (__hip_bfloat16*)alloc((size_t)CC * CC * 2);
  float* ybuf = (float*)Wkh;           // overlays Wkh+Wkl (dead after k-GEMM)
  float* h2v  = (float*)Wkh;           // same region, read by k_gate BEFORE scan writes ybuf

  __hip_bfloat16* Wvh = (__hip_bfloat16*)alloc((size_t)CC * CC * 2);
  __hip_bfloat16* Wvl = (__hip_bfloat16*)alloc((size_t)CC * CC * 2);
  __hip_bfloat16* Woh = (__hip_bfloat16*)alloc((size_t)CC * CC * 2);
  __hip_bfloat16* Wol = (__hip_bfloat16*)alloc((size_t)CC * CC * 2);
  __hip_bfloat16* xw  = (__hip_bfloat16*)alloc(EL * 2);
  __hip_bfloat16* xa  = (__hip_bfloat16*)alloc(EL * 2);
  __hip_bfloat16* xg  = (__hip_bfloat16*)alloc(EL * 2);
  float* h2w = (float*)xw;             // overlays xw+xa (dead after stage-1 GEMMs)
  __hip_bfloat16* w1t = (__hip_bfloat16*)alloc((size_t)64  * CC * 2);
  __hip_bfloat16* a1t = (__hip_bfloat16*)alloc((size_t)64  * CC * 2);
  __hip_bfloat16* v1t = (__hip_bfloat16*)alloc((size_t)64  * CC * 2);
  __hip_bfloat16* g1t = (__hip_bfloat16*)alloc((size_t)128 * CC * 2);
  float* rb  = (float*)alloc(EL * 4);
  float* kb  = (float*)alloc(EL * 4);  // raw k, then k_final in place
  float* vb  = (float*)alloc(EL * 4);  // raw v, then v_mix in place
  float* h1w = (float*)alloc((size_t)BT * 64  * 4);
  float* h1a = (float*)alloc((size_t)BT * 64  * 4);
  float* h1v = (float*)alloc((size_t)BT * 64  * 4);
  float* h1g = (float*)alloc((size_t)BT * 128 * 4);
  __hip_bfloat16* xoh = (__hip_bfloat16*)alloc(EL * 2);
  __hip_bfloat16* xol = (__hip_bfloat16*)alloc(EL * 2);
  float* h2a = (float*)xoh;            // overlays xoh+xol (k_post writes them AFTER k_gate)
  float* bonb = (float*)alloc((size_t)BT * HH * 4);   // per-(token,head) bonus
  // stage-2 split operands (small, fresh):
  __hip_bfloat16* h1wh = (__hip_bfloat16*)alloc((size_t)BT * 64 * 2);
  __hip_bfloat16* h1wl = (__hip_bfloat16*)alloc((size_t)BT * 64 * 2);
  __hip_bfloat16* h1ah = (__hip_bfloat16*)alloc((size_t)BT * 64 * 2);
  __hip_bfloat16* h1al = (__hip_bfloat16*)alloc((size_t)BT * 64 * 2);
  __hip_bfloat16* h1vh = (__hip_bfloat16*)alloc((size_t)BT * 64 * 2);
  __hip_bfloat16* h1vl = (__hip_bfloat16*)alloc((size_t)BT * 64 * 2);
  __hip_bfloat16* h1gh = (__hip_bfloat16*)alloc((size_t)BT * 128 * 2);
  __hip_bfloat16* h1gl = (__hip_bfloat16*)alloc((size_t)BT * 128 * 2);
  __hip_bfloat16* w2th = (__hip_bfloat16*)alloc((size_t)CC * 64 * 2);
  __hip_bfloat16* w2tl = (__hip_bfloat16*)alloc((size_t)CC * 64 * 2);
  __hip_bfloat16* a2th = (__hip_bfloat16*)alloc((size_t)CC * 64 * 2);
  __hip_bfloat16* a2tl = (__hip_bfloat16*)alloc((size_t)CC * 64 * 2);
  __hip_bfloat16* v2th = (__hip_bfloat16*)alloc((size_t)CC * 64 * 2);
  __hip_bfloat16* v2tl = (__hip_bfloat16*)alloc((size_t)CC * 64 * 2);
  __hip_bfloat16* g2th = (__hip_bfloat16*)alloc((size_t)CC * 128 * 2);
  __hip_bfloat16* g2tl = (__hip_bfloat16*)alloc((size_t)CC * 128 * 2);
  // total ~210 MiB (known-OK envelope: 220 OK, 268 crashed)

  k_prepx<<<16384, 256, 0, stream>>>(hid, shift, xrc, xwc, xkc, xvc, xac, xgc,
                                     xrh, xrl, xw, xkh, xkl, xvh, xvl, xa, xg);
  k_cvt2x4<<<dim3(16384, 4), 256, 0, stream>>>(Wr, Wk, Wv, Wo,
                                               Wrh, Wrl, Wkh, Wkl,
                                               Wvh, Wvl, Woh, Wol);
  k_tr<<<512, 256, 0, stream>>>(w1, w1t, 64);
  k_tr<<<512, 256, 0, stream>>>(a1, a1t, 64);
  k_tr<<<512, 256, 0, stream>>>(v1, v1t, 32);
  k_tr<<<1024, 256, 0, stream>>>(g1, g1t, 128);
  k_trs<<<512, 256, 0, stream>>>(w2, w2th, w2tl, 64, 6);
  k_trs<<<512, 256, 0, stream>>>(a2, a2th, a2tl, 64, 6);
  k_trs<<<512, 256, 0, stream>>>(v2, v2th, v2tl, 32, 6);   // padded K=64
  k_trs<<<1024, 256, 0, stream>>>(g2, g2th, g2tl, 128, 7);

  k_gemm_bt3<<<dim3(32, 16), 256, 0, stream>>>(xrh, xrl, Wrh, Wrl, rb, BT, CC, CC);
  k_gemm_bt3<<<dim3(32, 16), 256, 0, stream>>>(xkh, xkl, Wkh, Wkl, kb, BT, CC, CC);
  k_gemm_bt3<<<dim3(32, 16), 256, 0, stream>>>(xvh, xvl, Wvh, Wvl, vb, BT, CC, CC);
  k_lora1<<<dim3(32, 5), 256, 0, stream>>>(xw, xa, xvh, xg, w1t, a1t, v1t, g1t,
                                           h1w, h1a, h1v, h1g);

  k_act2<<<1024, 256, 0, stream>>>(h1w, h1a, h1v, h1g,
                                   h1wh, h1wl, h1ah, h1al,
                                   h1vh, h1vl, h1gh, h1gl);
  // stage-2 LoRA dots on MFMA (split precision). Overlays now live:
  //   h2w->xw+xa, h2a->xoh+xol, h2v->Wkh+Wkl, h2g->Wrh+Wrl.
  k_gemm_bt3<<<dim3(32, 16), 256, 0, stream>>>(h1wh, h1wl, w2th, w2tl, h2w, BT, CC, 64);
  k_gemm_bt3<<<dim3(32, 16), 256, 0, stream>>>(h1ah, h1al, a2th, a2tl, h2a, BT, CC, 64);
  k_gemm_bt3<<<dim3(32, 16), 256, 0, stream>>>(h1vh, h1vl, v2th, v2tl, h2v, BT, CC, 64);
  k_gemm_bt3<<<dim3(32, 16), 256, 0, stream>>>(h1gh, h1gl, g2th, g2tl, h2g, BT, CC, 128);

  k_gate<<<16384, 256, 0, stream>>>(h2w, h2a, h2v, w0, a0, v0, kkc, kac,
                                    kb, vb, vfirst, rb, rk, db, awb, bwb, bonb);
  k_scan<<<1024, 64, 0, stream>>>(rb, kb, db, awb, bwb, vb, st0, ybuf);
  k_post<<<16384, 256, 0, stream>>>(ybuf, vb, h2g, bonb, gnw, gnb, xoh, xol);
  k_gemm_bt3<<<dim3(32, 16), 256, 0, stream>>>(xoh, xol, Woh, Wol, out, BT, CC, CC);
}

// Round 13
// 792.570 us; speedup vs baseline: 1.3748x; 1.0104x over previous
//
#include <hip/hip_runtime.h>
#include <hip/hip_bf16.h>

// Problem constants (RWKV-7 Tmix: B=2, T=1024, C=2048, H=32, N=64)
#define BB 2
#define TT 1024
#define CC 2048
#define HH 32
#define BT 2048          // BB*TT tokens
#define GN_EPS 6.4e-4f   // 1e-5 * 8^2

typedef __attribute__((ext_vector_type(8))) __bf16 bf16x8;
typedef __attribute__((ext_vector_type(4))) float f32x4;

__device__ __forceinline__ float sigf(float x) { return 1.0f / (1.0f + expf(-x)); }

__device__ __forceinline__ void split_bf16(float x, __hip_bfloat16& hi, __hip_bfloat16& lo) {
  __hip_bfloat16 h = __float2bfloat16(x);
  hi = h;
  lo = __float2bfloat16(x - __bfloat162float(h));
}

// Sum over each aligned 16-lane group, pure DPP (no LDS pipe on the chain).
__device__ __forceinline__ float red16(float x) {
  x += __int_as_float(__builtin_amdgcn_update_dpp(
      0, __float_as_int(x), 0xB1 /*quad_perm [1,0,3,2]*/, 0xF, 0xF, true));
  x += __int_as_float(__builtin_amdgcn_update_dpp(
      0, __float_as_int(x), 0x4E /*quad_perm [2,3,0,1]*/, 0xF, 0xF, true));
  x += __int_as_float(__builtin_amdgcn_update_dpp(
      0, __float_as_int(x), 0x141 /*row_half_mirror*/, 0xF, 0xF, true));
  x += __int_as_float(__builtin_amdgcn_update_dpp(
      0, __float_as_int(x), 0x140 /*row_mirror*/, 0xF, 0xF, true));
  return x;
}

// ---------------------------------------------------------------------------
// K1: token shift + six lerped projections. r/k/v hi+lo split; w/a/g bf16.
// ---------------------------------------------------------------------------
__global__ __launch_bounds__(256) void k_prepx(
    const float* __restrict__ hid, const float* __restrict__ shift,
    const float* __restrict__ xrc, const float* __restrict__ xwc,
    const float* __restrict__ xkc, const float* __restrict__ xvc,
    const float* __restrict__ xac, const float* __restrict__ xgc,
    __hip_bfloat16* __restrict__ xrh, __hip_bfloat16* __restrict__ xrl,
    __hip_bfloat16* __restrict__ xw,
    __hip_bfloat16* __restrict__ xkh, __hip_bfloat16* __restrict__ xkl,
    __hip_bfloat16* __restrict__ xvh, __hip_bfloat16* __restrict__ xvl,
    __hip_bfloat16* __restrict__ xa, __hip_bfloat16* __restrict__ xg) {
  int idx = blockIdx.x * 256 + threadIdx.x;   // < BT*CC
  int c  = idx & (CC - 1);
  int bt = idx >> 11;
  int t  = bt & (TT - 1);
  int b  = bt >> 10;
  float hcur  = hid[idx];
  float hprev = (t == 0) ? shift[b * CC + c] : hid[idx - CC];
  float xx = hprev - hcur;
  split_bf16(fmaf(xx, xrc[c], hcur), xrh[idx], xrl[idx]);
  split_bf16(fmaf(xx, xkc[c], hcur), xkh[idx], xkl[idx]);
  split_bf16(fmaf(xx, xvc[c], hcur), xvh[idx], xvl[idx]);
  xw[idx] = __float2bfloat16(fmaf(xx, xwc[c], hcur));
  xa[idx] = __float2bfloat16(fmaf(xx, xac[c], hcur));
  xg[idx] = __float2bfloat16(fmaf(xx, xgc[c], hcur));
}

// ---------------------------------------------------------------------------
// K2: f32 -> hi+lo bf16 split for all four big weights, one dispatch.
// ---------------------------------------------------------------------------
__global__ __launch_bounds__(256) void k_cvt2x4(
    const float* __restrict__ i0, const float* __restrict__ i1,
    const float* __restrict__ i2, const float* __restrict__ i3,
    __hip_bfloat16* __restrict__ h0, __hip_bfloat16* __restrict__ l0,
    __hip_bfloat16* __restrict__ h1, __hip_bfloat16* __restrict__ l1,
    __hip_bfloat16* __restrict__ h2, __hip_bfloat16* __restrict__ l2,
    __hip_bfloat16* __restrict__ h3, __hip_bfloat16* __restrict__ l3) {
  int i = blockIdx.x * 256 + threadIdx.x;
  int w = blockIdx.y;
  const float* in = (w == 0) ? i0 : (w == 1) ? i1 : (w == 2) ? i2 : i3;
  __hip_bfloat16* oh = (w == 0) ? h0 : (w == 1) ? h1 : (w == 2) ? h2 : h3;
  __hip_bfloat16* ol = (w == 0) ? l0 : (w == 1) ? l1 : (w == 2) ? l2 : l3;
  split_bf16(in[i], oh[i], ol[i]);
}

// ---------------------------------------------------------------------------
// K3: transpose-convert small LoRA "up" weights: in [2048][N0] f32 ->
//     out [NP][2048] bf16 (rows >= N0 zero-padded).  (stage-1 B operands)
// ---------------------------------------------------------------------------
__global__ __launch_bounds__(256) void k_tr(const float* __restrict__ in,
                                            __hip_bfloat16* __restrict__ out,
                                            int N0) {
  int i = blockIdx.x * 256 + threadIdx.x;   // over NP*2048, grid exact
  int n = i >> 11;
  int k = i & 2047;
  float v = (n < N0) ? in[k * N0 + n] : 0.0f;
  out[i] = __float2bfloat16(v);
}

// ---------------------------------------------------------------------------
// K3b: transpose + hi/lo split of stage-2 "down" weights:
//   in [N0][CC] f32 -> out [CC][K0] bf16 hi+lo (K0 = 1<<lgK, rows>=N0 zero).
// ---------------------------------------------------------------------------
__global__ __launch_bounds__(256) void k_trs(const float* __restrict__ in,
                                             __hip_bfloat16* __restrict__ oh,
                                             __hip_bfloat16* __restrict__ ol,
                                             int N0, int lgK) {
  int i = blockIdx.x * 256 + threadIdx.x;   // over CC*K0, grid exact
  int n = i >> lgK;
  int k = i & ((1 << lgK) - 1);
  float v = (k < N0) ? in[k * CC + n] : 0.0f;
  split_bf16(v, oh[i], ol[i]);
}

// ---------------------------------------------------------------------------
// K4: fused stage-1 LoRA GEMM, LDS-staged (r11 winner, unchanged).
// grid (32 M-tiles, 5 slices): {xw*w1, xa*a1, xv*v1, xg*g1[0:64], xg*g1[64:128]}
// ---------------------------------------------------------------------------
__global__ __launch_bounds__(256, 4) void k_lora1(
    const __hip_bfloat16* __restrict__ xw, const __hip_bfloat16* __restrict__ xa,
    const __hip_bfloat16* __restrict__ xv, const __hip_bfloat16* __restrict__ xg,
    const __hip_bfloat16* __restrict__ w1t, const __hip_bfloat16* __restrict__ a1t,
    const __hip_bfloat16* __restrict__ v1t, const __hip_bfloat16* __restrict__ g1t,
    float* __restrict__ h1w, float* __restrict__ h1a,
    float* __restrict__ h1v, float* __restrict__ h1g) {
  __shared__ __align__(16) __hip_bfloat16 sA[2][64 * 32], sB[2][64 * 32];
  int tid  = threadIdx.x;
  int lane = tid & 63;
  int wv   = tid >> 6;
  int l15  = lane & 15;
  int quad = lane >> 4;
  int m0 = blockIdx.x * 64;
  int bly = blockIdx.y;

  const __hip_bfloat16* Ab;
  const __hip_bfloat16* Bb;
  float* Ob;
  int os, cb;
  if (bly == 0)      { Ab = xw; Bb = w1t;            Ob = h1w; os = 64;  cb = 0;  }
  else if (bly == 1) { Ab = xa; Bb = a1t;            Ob = h1a; os = 64;  cb = 0;  }
  else if (bly == 2) { Ab = xv; Bb = v1t;            Ob = h1v; os = 64;  cb = 0;  }
  else if (bly == 3) { Ab = xg; Bb = g1t;            Ob = h1g; os = 128; cb = 0;  }
  else               { Ab = xg; Bb = g1t + 64 * CC;  Ob = h1g; os = 128; cb = 64; }

  int srow = wv * 16 + (lane >> 2);
  int scol = (lane & 3) * 8;
  const __hip_bfloat16* gA = Ab + (size_t)(m0 + srow) * CC + scol;
  const __hip_bfloat16* gB = Bb + (size_t)srow * CC + scol;

  f32x4 z = {0.f, 0.f, 0.f, 0.f};
  f32x4 acc0 = z, acc1 = z, acc2 = z, acc3 = z;

  int aoff = (wv * 16 + l15) * 32 + quad * 8;
  int boff = l15 * 32 + quad * 8;

#define STAGE1(BUF, KO)                                                      \
  { unsigned db_ = (unsigned)(BUF) * 4096u + (unsigned)wv * 1024u;           \
    __builtin_amdgcn_global_load_lds(                                        \
        (const __attribute__((address_space(1))) void*)(gA + (KO)),          \
        (__attribute__((address_space(3))) void*)((char*)sA + db_), 16, 0, 0);\
    __builtin_amdgcn_global_load_lds(                                        \
        (const __attribute__((address_space(1))) void*)(gB + (KO)),          \
        (__attribute__((address_space(3))) void*)((char*)sB + db_), 16, 0, 0);}

  STAGE1(0, 0)
  __syncthreads();

  for (int k0 = 0; k0 < CC; k0 += 32) {
    int cur = (k0 >> 5) & 1;
    if (k0 + 32 < CC) STAGE1(cur ^ 1, k0 + 32)

    const __hip_bfloat16* pA_ = &sA[cur][0];
    const __hip_bfloat16* pB_ = &sB[cur][0];
    bf16x8 av = *(const bf16x8*)(pA_ + aoff);
    bf16x8 b0 = *(const bf16x8*)(pB_ + boff);
    bf16x8 b1 = *(const bf16x8*)(pB_ + boff + 16 * 32);
    bf16x8 b2 = *(const bf16x8*)(pB_ + boff + 32 * 32);
    bf16x8 b3 = *(const bf16x8*)(pB_ + boff + 48 * 32);

    acc0 = __builtin_amdgcn_mfma_f32_16x16x32_bf16(av, b0, acc0, 0, 0, 0);
    acc1 = __builtin_amdgcn_mfma_f32_16x16x32_bf16(av, b1, acc1, 0, 0, 0);
    acc2 = __builtin_amdgcn_mfma_f32_16x16x32_bf16(av, b2, acc2, 0, 0, 0);
    acc3 = __builtin_amdgcn_mfma_f32_16x16x32_bf16(av, b3, acc3, 0, 0, 0);

    __syncthreads();
  }
#undef STAGE1

  int row0 = m0 + wv * 16 + quad * 4;
  int colb = cb + l15;
#pragma unroll
  for (int r = 0; r < 4; ++r) {
    Ob[(size_t)(row0 + r) * os + colb +  0] = acc0[r];
    Ob[(size_t)(row0 + r) * os + colb + 16] = acc1[r];
    Ob[(size_t)(row0 + r) * os + colb + 32] = acc2[r];
    Ob[(size_t)(row0 + r) * os + colb + 48] = acc3[r];
  }
}

// ---------------------------------------------------------------------------
// K4b: split-precision GEMM — 64x128 tile, 2-phase LDS staging (r12 winner).
// ---------------------------------------------------------------------------
__global__ __launch_bounds__(256, 3) void k_gemm_bt3(
    const __hip_bfloat16* __restrict__ Ah, const __hip_bfloat16* __restrict__ Al,
    const __hip_bfloat16* __restrict__ Bh, const __hip_bfloat16* __restrict__ Bl,
    float* __restrict__ Cm, int M, int Nn, int K) {
  __shared__ __align__(16) __hip_bfloat16 sAh[2][64 * 32],  sAl[2][64 * 32];
  __shared__ __align__(16) __hip_bfloat16 sBh[2][128 * 32], sBl[2][128 * 32];
  int tid  = threadIdx.x;
  int lane = tid & 63;
  int wv   = tid >> 6;
  int l15  = lane & 15;
  int quad = lane >> 4;
  int m0 = blockIdx.x * 64;
  int n0 = blockIdx.y * 128;

  int srowA = wv * 16 + (lane >> 2);
  int srowB = wv * 32 + (lane >> 2);
  int scol  = (lane & 3) * 8;
  const __hip_bfloat16* gAh  = Ah + (size_t)(m0 + srowA) * K + scol;
  const __hip_bfloat16* gAl  = Al + (size_t)(m0 + srowA) * K + scol;
  const __hip_bfloat16* gBh0 = Bh + (size_t)(n0 + srowB) * K + scol;
  const __hip_bfloat16* gBh1 = Bh + (size_t)(n0 + srowB + 16) * K + scol;
  const __hip_bfloat16* gBl0 = Bl + (size_t)(n0 + srowB) * K + scol;
  const __hip_bfloat16* gBl1 = Bl + (size_t)(n0 + srowB + 16) * K + scol;

  f32x4 z = {0.f, 0.f, 0.f, 0.f};
  f32x4 acc[8];
#pragma unroll
  for (int j = 0; j < 8; ++j) acc[j] = z;

  int aoff = (wv * 16 + l15) * 32 + quad * 8;
  int boff = l15 * 32 + quad * 8;

#define STAGE(BUF, KO)                                                       \
  { unsigned dA_ = (unsigned)(BUF) * 4096u + (unsigned)wv * 1024u;           \
    unsigned dB_ = (unsigned)(BUF) * 8192u + (unsigned)wv * 2048u;           \
    __builtin_amdgcn_global_load_lds(                                        \
        (const __attribute__((address_space(1))) void*)(gAh + (KO)),         \
        (__attribute__((address_space(3))) void*)((char*)sAh + dA_), 16, 0, 0);\
    __builtin_amdgcn_global_load_lds(                                        \
        (const __attribute__((address_space(1))) void*)(gAl + (KO)),         \
        (__attribute__((address_space(3))) void*)((char*)sAl + dA_), 16, 0, 0);\
    __builtin_amdgcn_global_load_lds(                                        \
        (const __attribute__((address_space(1))) void*)(gBh0 + (KO)),        \
        (__attribute__((address_space(3))) void*)((char*)sBh + dB_), 16, 0, 0);\
    __builtin_amdgcn_global_load_lds(                                        \
        (const __attribute__((address_space(1))) void*)(gBh1 + (KO)),        \
        (__attribute__((address_space(3))) void*)((char*)sBh + dB_ + 1024u), 16, 0, 0);\
    __builtin_amdgcn_global_load_lds(                                        \
        (const __attribute__((address_space(1))) void*)(gBl0 + (KO)),        \
        (__attribute__((address_space(3))) void*)((char*)sBl + dB_), 16, 0, 0);\
    __builtin_amdgcn_global_load_lds(                                        \
        (const __attribute__((address_space(1))) void*)(gBl1 + (KO)),        \
        (__attribute__((address_space(3))) void*)((char*)sBl + dB_ + 1024u), 16, 0, 0);}

  STAGE(0, 0)
  __syncthreads();   // buf0 staged (implicit vmcnt(0) drain before barrier)

  for (int k0 = 0; k0 < K; k0 += 32) {
    int cur = (k0 >> 5) & 1;
    if (k0 + 32 < K) STAGE(cur ^ 1, k0 + 32)   // next tile in flight NOW

    const __hip_bfloat16* pA_h = &sAh[cur][0];
    const __hip_bfloat16* pA_l = &sAl[cur][0];
    const __hip_bfloat16* pB_h = &sBh[cur][0];
    const __hip_bfloat16* pB_l = &sBl[cur][0];
    bf16x8 ah = *(const bf16x8*)(pA_h + aoff);
    bf16x8 al = *(const bf16x8*)(pA_l + aoff);
#pragma unroll
    for (int j = 0; j < 8; ++j) {
      bf16x8 bh = *(const bf16x8*)(pB_h + boff + j * 16 * 32);
      bf16x8 bl = *(const bf16x8*)(pB_l + boff + j * 16 * 32);
      acc[j] = __builtin_amdgcn_mfma_f32_16x16x32_bf16(ah, bh, acc[j], 0, 0, 0);
      acc[j] = __builtin_amdgcn_mfma_f32_16x16x32_bf16(ah, bl, acc[j], 0, 0, 0);
      acc[j] = __builtin_amdgcn_mfma_f32_16x16x32_bf16(al, bh, acc[j], 0, 0, 0);
    }

    __syncthreads();   // ONE barrier: next buf staged + this buf reads done
  }
#undef STAGE

  int row0 = m0 + wv * 16 + quad * 4;
#pragma unroll
  for (int j = 0; j < 8; ++j) {
    int colb = n0 + j * 16 + l15;
#pragma unroll
    for (int r = 0; r < 4; ++r)
      Cm[(size_t)(row0 + r) * Nn + colb] = acc[j][r];
  }
}

// ---------------------------------------------------------------------------
// K5: activations + hi/lo split of stage-1 LoRA outputs (MFMA stage-2 prep).
// ---------------------------------------------------------------------------
__global__ __launch_bounds__(256) void k_act2(
    const float* __restrict__ h1w, const float* __restrict__ h1a,
    const float* __restrict__ h1v, const float* __restrict__ h1g,
    __hip_bfloat16* __restrict__ wh, __hip_bfloat16* __restrict__ wl,
    __hip_bfloat16* __restrict__ ah, __hip_bfloat16* __restrict__ al,
    __hip_bfloat16* __restrict__ vh, __hip_bfloat16* __restrict__ vl,
    __hip_bfloat16* __restrict__ gh, __hip_bfloat16* __restrict__ gl) {
  int i = blockIdx.x * 256 + threadIdx.x;   // grid covers BT*128 exactly
  if (i < BT * 64) {
    split_bf16(tanhf(h1w[i]), wh[i], wl[i]);
    split_bf16(h1a[i], ah[i], al[i]);
    split_bf16(h1v[i], vh[i], vl[i]);
  }
  split_bf16(sigf(h1g[i]), gh[i], gl[i]);
}

// ---------------------------------------------------------------------------
// K6: elementwise gates + kk-normalize + per-head bonus. wave == head.
// ---------------------------------------------------------------------------
__global__ __launch_bounds__(256) void k_gate(
    const float* __restrict__ h2w, const float* __restrict__ h2a,
    const float* __restrict__ h2v,
    const float* __restrict__ w0, const float* __restrict__ a0,
    const float* __restrict__ v0, const float* __restrict__ kkc,
    const float* __restrict__ kac, float* __restrict__ kbuf,
    float* __restrict__ vbuf, const float* __restrict__ vfirst,
    const float* __restrict__ rbuf, const float* __restrict__ rk,
    float* __restrict__ dec, float* __restrict__ aw,
    float* __restrict__ bw, float* __restrict__ bonb) {
  int idx = blockIdx.x * 256 + threadIdx.x;   // < BT*CC
  int c = idx & (CC - 1);
  float kv = kbuf[idx], vv = vbuf[idx], vf = vfirst[idx];
  float d_ = 0.60653065971f * sigf(w0[c] + h2w[idx]);   // sigmoid * e^-0.5
  float as = sigf(a0[c] + h2a[idx]);
  float vs = sigf(v0[c] + h2v[idx]);
  float vm = vv + (vf - vv) * vs;
  float kfv = kv * (1.0f + kac[c] * (as - 1.0f));
  float kku = kv * kkc[c];
  float s = kku * kku;     // per-head L2 over 64 lanes (wave == head)
  s += __shfl_xor(s, 1);  s += __shfl_xor(s, 2);  s += __shfl_xor(s, 4);
  s += __shfl_xor(s, 8);  s += __shfl_xor(s, 16); s += __shfl_xor(s, 32);
  float nrm = fmaxf(sqrtf(s), 1e-12f);
  float kkn = kku / nrm;
  float bon = rbuf[idx] * kfv * rk[c];
  bon += __shfl_xor(bon, 1);  bon += __shfl_xor(bon, 2);
  bon += __shfl_xor(bon, 4);  bon += __shfl_xor(bon, 8);
  bon += __shfl_xor(bon, 16); bon += __shfl_xor(bon, 32);
  if ((threadIdx.x & 63) == 0) bonb[(idx >> 11) * HH + (c >> 6)] = bon;
  dec[idx] = d_;
  aw[idx]  = -kkn; bw[idx] = kkn * as;
  kbuf[idx] = kfv; vbuf[idx] = vm;
}

// ---------------------------------------------------------------------------
// K7: WKV7 scan — ROUND-20: counted-lgkm pipelined LDS reads.
// r12 evidence: VALUBusy 28% (123/440 cy); 4 waves x ~5.2KB ds_read/step
// nearly saturates the LDS pipe, and the old schedule (DSRD(t+1) ->
// STEPR(t) -> lgkmcnt(0)) gave each token's 6 ds_reads only ~90cy of cover
// before a FULL drain on the critical path. New schedule: issue a slot's
// reads AFTER the step that frees its regs, wait with COUNTED lgkmcnt(6)
// (DS ops complete in order): the wait only needs reads issued a full
// iteration ago (long done); the 6 newest stream in flight ~1.5 steps.
// WVM dropped from steady loop (arithmetic no-op: <=34 outstanding < 40;
// 13+-token read-behind margin vs ~900cy HBM latency unchanged from r7-12).
// Math identical (red16 pure-DPP, same fma order).
// ---------------------------------------------------------------------------
__global__ __launch_bounds__(64, 1) void k_scan(
    const float* __restrict__ rbuf, const float* __restrict__ kf,
    const float* __restrict__ dec, const float* __restrict__ aw,
    const float* __restrict__ bw, const float* __restrict__ vbuf,
    const float* __restrict__ st0, float* __restrict__ ybuf) {
  __shared__ __align__(16) char ldsbuf[16 * 2048];
  int blk = blockIdx.x;                     // 0..1023
  int xcd = blk & 7;
  int q   = blk >> 3;                       // 0..127
  int bh  = xcd * 8 + (q & 7);              // 16 rg-waves of a head share blk%8
  int rg  = q >> 3;                         // 0..15
  int b = bh >> 5, h = bh & 31;
  int lane = threadIdx.x;
  int l15  = lane & 15;
  int row  = rg * 4 + (lane >> 4);
  size_t tokbase = (size_t)b * TT * CC + h * 64;

  f32x4 S = *(const f32x4*)(st0 + ((size_t)bh * 64 + row) * 64 + l15 * 4);
  bool writer = (l15 == 0);
  float* yout = ybuf + tokbase + row;

  // per-lane DMA source pointers (advance +CC per token, all lanes uniform)
  const float* g1 = (lane < 16 ? rbuf : lane < 32 ? kf : lane < 48 ? dec : aw)
                  + tokbase + l15 * 4;
  const float* g2 = (lane < 16) ? (bw + tokbase + l15 * 4)
                                : (vbuf + tokbase + rg * 4);  // lanes>=16: v rows (16 real, rest pad)

  // LDS byte offsets (relative to workgroup LDS base)
  unsigned lbase = (unsigned)(uintptr_t)(__attribute__((address_space(3))) char*)ldsbuf;
  unsigned larr = lbase + (unsigned)(l15 * 16);          // +slot: arrays at 0/256/512/768/1024
  unsigned lvad = lbase + 1280u + (unsigned)((lane >> 4) * 4);  // +slot: v word

#define DMAQ(T)                                                              \
  { char* sb_ = ldsbuf + (((T) & 15) << 11);                                 \
    __builtin_amdgcn_global_load_lds(                                        \
        (const __attribute__((address_space(1))) void*)g1,                   \
        (__attribute__((address_space(3))) void*)sb_, 16, 0, 0);             \
    __builtin_amdgcn_global_load_lds(                                        \
        (const __attribute__((address_space(1))) void*)g2,                   \
        (__attribute__((address_space(3))) void*)(sb_ + 1024), 16, 0, 0);    \
    g1 += CC; g2 += CC; }

#define DSRD(RR, RK, RD, RA, RB, RV, T)                                      \
  { unsigned a_ = larr + (unsigned)(((T) & 15) << 11);                       \
    unsigned v_ = lvad + (unsigned)(((T) & 15) << 11);                       \
    asm volatile("ds_read_b128 %0, %1"             : "=v"(RR) : "v"(a_));    \
    asm volatile("ds_read_b128 %0, %1 offset:256"  : "=v"(RK) : "v"(a_));    \
    asm volatile("ds_read_b128 %0, %1 offset:512"  : "=v"(RD) : "v"(a_));    \
    asm volatile("ds_read_b128 %0, %1 offset:768"  : "=v"(RA) : "v"(a_));    \
    asm volatile("ds_read_b128 %0, %1 offset:1024" : "=v"(RB) : "v"(a_));    \
    asm volatile("ds_read_b32 %0, %1"              : "=v"(RV) : "v"(v_)); }

#define WVM(N) { asm volatile("s_waitcnt vmcnt(" #N ")" ::: "memory");       \
                 __builtin_amdgcn_sched_barrier(0); }
#define WLG    { asm volatile("s_waitcnt lgkmcnt(0)" ::: "memory");          \
                 __builtin_amdgcn_sched_barrier(0); }
#define WLG6   { asm volatile("s_waitcnt lgkmcnt(6)" ::: "memory");          \
                 __builtin_amdgcn_sched_barrier(0); }

#define STEPR(RR, RK, RD, RA, RB, RV, T)                                     \
  { float sa = fmaf(S.w, RA.w, fmaf(S.z, RA.z,                               \
               fmaf(S.y, RA.y, S.x * RA.x)));                                \
    sa = red16(sa);                                                          \
    float vv = RV;                                                           \
    S.x = fmaf(S.x, RD.x, fmaf(sa, RB.x, vv * RK.x));                        \
    S.y = fmaf(S.y, RD.y, fmaf(sa, RB.y, vv * RK.y));                        \
    S.z = fmaf(S.z, RD.z, fmaf(sa, RB.z, vv * RK.z));                        \
    S.w = fmaf(S.w, RD.w, fmaf(sa, RB.w, vv * RK.w));                        \
    float y = fmaf(S.w, RR.w, fmaf(S.z, RR.z,                                \
              fmaf(S.y, RR.y, S.x * RR.x)));                                 \
    y = red16(y);                                                            \
    if (writer) yout[(size_t)(T) * CC] = y; }

  // prologue: DMA tokens 0..15 (32 vmem ops in flight)
  for (int tt = 0; tt < 16; ++tt) DMAQ(tt)

  f32x4 Ar, Ak, Ad, Aa, Ab; float Av;
  f32x4 Br, Bk, Bd, Ba, Bb; float Bv;

  WVM(24)                      // tokens 0..3 landed (24 newer outstanding)
  DSRD(Ar, Ak, Ad, Aa, Ab, Av, 0)
  WLG                          // A(0) ready
  DSRD(Br, Bk, Bd, Ba, Bb, Bv, 1)   // B(1) in flight (6 outstanding)

  // invariant at loop top: A holds token t (ready); B(t+1) reads issued.
  int t = 0;
  for (; t < TT - 16; t += 2) {
    DMAQ(t + 16)
    STEPR(Ar, Ak, Ad, Aa, Ab, Av, t)
    DSRD(Ar, Ak, Ad, Aa, Ab, Av, t + 2)
    WLG6                        // B(t+1) done; A(t+2)'s 6 newest in flight
    DMAQ(t + 17)
    STEPR(Br, Bk, Bd, Ba, Bb, Bv, t + 1)
    DSRD(Br, Bk, Bd, Ba, Bb, Bv, t + 3)
    WLG6                        // A(t+2) done; B(t+3) in flight
  }
  // no more DMA; same pipeline to t = TT-4 (DSRD targets <= TT-1)
  for (; t < TT - 2; t += 2) {
    STEPR(Ar, Ak, Ad, Aa, Ab, Av, t)
    DSRD(Ar, Ak, Ad, Aa, Ab, Av, t + 2)
    WLG6
    STEPR(Br, Bk, Bd, Ba, Bb, Bv, t + 1)
    if (t + 3 < TT) DSRD(Br, Bk, Bd, Ba, Bb, Bv, t + 3)
    WLG6
  }
  // t == TT-2: A holds TT-2 (ready); B(TT-1) reads issued
  STEPR(Ar, Ak, Ad, Aa, Ab, Av, TT - 2)
  WLG
  STEPR(Br, Bk, Bd, Ba, Bb, Bv, TT - 1)
#undef DMAQ
#undef DSRD
#undef WVM
#undef WLG
#undef WLG6
#undef STEPR
}

// ---------------------------------------------------------------------------
// K8: post-scan epilogue: GroupNorm + bonus + g-gate, fully parallel.
// ---------------------------------------------------------------------------
__global__ __launch_bounds__(256) void k_post(
    const float* __restrict__ ybuf, const float* __restrict__ vb,
    const float* __restrict__ gvb, const float* __restrict__ bonb,
    const float* __restrict__ gnw, const float* __restrict__ gnb,
    __hip_bfloat16* __restrict__ xoh, __hip_bfloat16* __restrict__ xol) {
  int tid = threadIdx.x, wv = tid >> 6, lane = tid & 63;
  int id = blockIdx.x * 4 + wv;        // 0..BT*HH-1
  int bt = id >> 5, h = id & 31;
  size_t base = (size_t)bt * CC + h * 64 + lane;
  float y = ybuf[base];
  float s1 = y, s2 = y * y;
#pragma unroll
  for (int off = 1; off < 64; off <<= 1) {
    s1 += __shfl_xor(s1, off);
    s2 += __shfl_xor(s2, off);
  }
  float mean = s1 * (1.0f / 64.0f);
  float var  = s2 * (1.0f / 64.0f) - mean * mean;
  float inv  = rsqrtf(var + GN_EPS);
  float x = fmaf((y - mean) * inv, gnw[h * 64 + lane], gnb[h * 64 + lane])
          + bonb[bt * HH + h] * vb[base];
  split_bf16(x * gvb[base], xoh[base], xol[base]);
}

// ---------------------------------------------------------------------------
extern "C" void kernel_launch(void* const* d_in, const int* in_sizes, int n_in,
                              void* d_out, int out_size, void* d_ws, size_t ws_size,
                              hipStream_t stream) {
  (void)in_sizes; (void)n_in; (void)out_size; (void)ws_size;
  const float* hid    = (const float*)d_in[0];
  const float* shift  = (const float*)d_in[1];
  const float* st0    = (const float*)d_in[2];
  const float* vfirst = (const float*)d_in[3];
  const float* xrc = (const float*)d_in[4];
  const float* xwc = (const float*)d_in[5];
  const float* xkc = (const float*)d_in[6];
  const float* xvc = (const float*)d_in[7];
  const float* xac = (const float*)d_in[8];
  const float* xgc = (const float*)d_in[9];
  const float* w0  = (const float*)d_in[10];
  const float* w1  = (const float*)d_in[11];
  const float* w2  = (const float*)d_in[12];
  const float* a0  = (const float*)d_in[13];
  const float* a1  = (const float*)d_in[14];
  const float* a2  = (const float*)d_in[15];
  const float* v0  = (const float*)d_in[16];
  const float* v1  = (const float*)d_in[17];
  const float* v2  = (const float*)d_in[18];
  const float* g1  = (const float*)d_in[19];
  const float* g2  = (const float*)d_in[20];
  const float* kkc = (const float*)d_in[21];
  const float* kac = (const float*)d_in[22];
  const float* rk  = (const float*)d_in[23];
  const float* Wr  = (const float*)d_in[24];
  const float* Wk  = (const float*)d_in[25];
  const float* Wv  = (const float*)d_in[26];
  const float* Wo  = (const float*)d_in[27];
  const float* gnw = (const float*)d_in[28];
  const float* gnb = (const float*)d_in[29];
  float* out = (float*)d_out;

  char* p = (char*)d_ws;
  auto alloc = [&](size_t n) { char* q = p; p += (n + 255) & ~(size_t)255; return q; };
  const size_t EL = (size_t)BT * CC;

  // --- alias pool: xrh..xvl + Wrh,Wrl dead by k_gate time; db/awb/bwb +
  //     h2g (the old gvb slot) overlay them.
  char* pool = p;
  __hip_bfloat16* xrh = (__hip_bfloat16*)alloc(EL * 2);
  __hip_bfloat16* xrl = (__hip_bfloat16*)alloc(EL * 2);
  __hip_bfloat16* xkh = (__hip_bfloat16*)alloc(EL * 2);
  __hip_bfloat16* xkl = (__hip_bfloat16*)alloc(EL * 2);
  __hip_bfloat16* xvh = (__hip_bfloat16*)alloc(EL * 2);
  __hip_bfloat16* xvl = (__hip_bfloat16*)alloc(EL * 2);
  __hip_bfloat16* Wrh = (__hip_bfloat16*)alloc((size_t)CC * CC * 2);
  __hip_bfloat16* Wrl = (__hip_bfloat16*)alloc((size_t)CC * CC * 2);
  float* db  = (float*)pool;           // overlays xrh+xrl
  float* awb = db + EL;                // overlays xkh+xkl
  float* bwb = db + 2 * EL;            // overlays xvh+xvl
  float* h2g = db + 3 * EL;            // overlays Wrh+Wrl (old gvb slot)

  __hip_bfloat16* Wkh = (__hip_bfloat16*)alloc((size_t)CC * CC * 2);
  __hip_bfloat16* Wkl = (__hip_bfloat16*)alloc((size_t)CC * CC * 2);
  float* ybuf = (float*)Wkh;           // overlays Wkh+Wkl (dead after k-GEMM)
  float* h2v  = (float*)Wkh;           // same region, read by k_gate BEFORE scan writes ybuf

  __hip_bfloat16* Wvh = (__hip_bfloat16*)alloc((size_t)CC * CC * 2);
  __hip_bfloat16* Wvl = (__hip_bfloat16*)alloc((size_t)CC * CC * 2);
  __hip_bfloat16* Woh = (__hip_bfloat16*)alloc((size_t)CC * CC * 2);
  __hip_bfloat16* Wol = (__hip_bfloat16*)alloc((size_t)CC * CC * 2);
  __hip_bfloat16* xw  = (__hip_bfloat16*)alloc(EL * 2);
  __hip_bfloat16* xa  = (__hip_bfloat16*)alloc(EL * 2);
  __hip_bfloat16* xg  = (__hip_bfloat16*)alloc(EL * 2);
  float* h2w = (float*)xw;             // overlays xw+xa (dead after stage-1 GEMMs)
  __hip_bfloat16* w1t = (__hip_bfloat16*)alloc((size_t)64  * CC * 2);
  __hip_bfloat16* a1t = (__hip_bfloat16*)alloc((size_t)64  * CC * 2);
  __hip_bfloat16* v1t = (__hip_bfloat16*)alloc((size_t)64  * CC * 2);
  __hip_bfloat16* g1t = (__hip_bfloat16*)alloc((size_t)128 * CC * 2);
  float* rb  = (float*)alloc(EL * 4);
  float* kb  = (float*)alloc(EL * 4);  // raw k, then k_final in place
  float* vb  = (float*)alloc(EL * 4);  // raw v, then v_mix in place
  float* h1w = (float*)alloc((size_t)BT * 64  * 4);
  float* h1a = (float*)alloc((size_t)BT * 64  * 4);
  float* h1v = (float*)alloc((size_t)BT * 64  * 4);
  float* h1g = (float*)alloc((size_t)BT * 128 * 4);
  __hip_bfloat16* xoh = (__hip_bfloat16*)alloc(EL * 2);
  __hip_bfloat16* xol = (__hip_bfloat16*)alloc(EL * 2);
  float* h2a = (float*)xoh;            // overlays xoh+xol (k_post writes them AFTER k_gate)
  float* bonb = (float*)alloc((size_t)BT * HH * 4);   // per-(token,head) bonus
  // stage-2 split operands (small, fresh):
  __hip_bfloat16* h1wh = (__hip_bfloat16*)alloc((size_t)BT * 64 * 2);
  __hip_bfloat16* h1wl = (__hip_bfloat16*)alloc((size_t)BT * 64 * 2);
  __hip_bfloat16* h1ah = (__hip_bfloat16*)alloc((size_t)BT * 64 * 2);
  __hip_bfloat16* h1al = (__hip_bfloat16*)alloc((size_t)BT * 64 * 2);
  __hip_bfloat16* h1vh = (__hip_bfloat16*)alloc((size_t)BT * 64 * 2);
  __hip_bfloat16* h1vl = (__hip_bfloat16*)alloc((size_t)BT * 64 * 2);
  __hip_bfloat16* h1gh = (__hip_bfloat16*)alloc((size_t)BT * 128 * 2);
  __hip_bfloat16* h1gl = (__hip_bfloat16*)alloc((size_t)BT * 128 * 2);
  __hip_bfloat16* w2th = (__hip_bfloat16*)alloc((size_t)CC * 64 * 2);
  __hip_bfloat16* w2tl = (__hip_bfloat16*)alloc((size_t)CC * 64 * 2);
  __hip_bfloat16* a2th = (__hip_bfloat16*)alloc((size_t)CC * 64 * 2);
  __hip_bfloat16* a2tl = (__hip_bfloat16*)alloc((size_t)CC * 64 * 2);
  __hip_bfloat16* v2th = (__hip_bfloat16*)alloc((size_t)CC * 64 * 2);
  __hip_bfloat16* v2tl = (__hip_bfloat16*)alloc((size_t)CC * 64 * 2);
  __hip_bfloat16* g2th = (__hip_bfloat16*)alloc((size_t)CC * 128 * 2);
  __hip_bfloat16* g2tl = (__hip_bfloat16*)alloc((size_t)CC * 128 * 2);
  // total ~210 MiB (known-OK envelope: 220 OK, 268 crashed)

  k_prepx<<<16384, 256, 0, stream>>>(hid, shift, xrc, xwc, xkc, xvc, xac, xgc,
                                     xrh, xrl, xw, xkh, xkl, xvh, xvl, xa, xg);
  k_cvt2x4<<<dim3(16384, 4), 256, 0, stream>>>(Wr, Wk, Wv, Wo,
                                               Wrh, Wrl, Wkh, Wkl,
                                               Wvh, Wvl, Woh, Wol);
  k_tr<<<512, 256, 0, stream>>>(w1, w1t, 64);
  k_tr<<<512, 256, 0, stream>>>(a1, a1t, 64);
  k_tr<<<512, 256, 0, stream>>>(v1, v1t, 32);
  k_tr<<<1024, 256, 0, stream>>>(g1, g1t, 128);
  k_trs<<<512, 256, 0, stream>>>(w2, w2th, w2tl, 64, 6);
  k_trs<<<512, 256, 0, stream>>>(a2, a2th, a2tl, 64, 6);
  k_trs<<<512, 256, 0, stream>>>(v2, v2th, v2tl, 32, 6);   // padded K=64
  k_trs<<<1024, 256, 0, stream>>>(g2, g2th, g2tl, 128, 7);

  k_gemm_bt3<<<dim3(32, 16), 256, 0, stream>>>(xrh, xrl, Wrh, Wrl, rb, BT, CC, CC);
  k_gemm_bt3<<<dim3(32, 16), 256, 0, stream>>>(xkh, xkl, Wkh, Wkl, kb, BT, CC, CC);
  k_gemm_bt3<<<dim3(32, 16), 256, 0, stream>>>(xvh, xvl, Wvh, Wvl, vb, BT, CC, CC);
  k_lora1<<<dim3(32, 5), 256, 0, stream>>>(xw, xa, xvh, xg, w1t, a1t, v1t, g1t,
                                           h1w, h1a, h1v, h1g);

  k_act2<<<1024, 256, 0, stream>>>(h1w, h1a, h1v, h1g,
                                   h1wh, h1wl, h1ah, h1al,
                                   h1vh, h1vl, h1gh, h1gl);
  // stage-2 LoRA dots on MFMA (split precision). Overlays now live:
  //   h2w->xw+xa, h2a->xoh+xol, h2v->Wkh+Wkl, h2g->Wrh+Wrl.
  k_gemm_bt3<<<dim3(32, 16), 256, 0, stream>>>(h1wh, h1wl, w2th, w2tl, h2w, BT, CC, 64);
  k_gemm_bt3<<<dim3(32, 16), 256, 0, stream>>>(h1ah, h1al, a2th, a2tl, h2a, BT, CC, 64);
  k_gemm_bt3<<<dim3(32, 16), 256, 0, stream>>>(h1vh, h1vl, v2th, v2tl, h2v, BT, CC, 64);
  k_gemm_bt3<<<dim3(32, 16), 256, 0, stream>>>(h1gh, h1gl, g2th, g2tl, h2g, BT, CC, 128);

  k_gate<<<16384, 256, 0, stream>>>(h2w, h2a, h2v, w0, a0, v0, kkc, kac,
                                    kb, vb, vfirst, rb, rk, db, awb, bwb, bonb);
  k_scan<<<1024, 64, 0, stream>>>(rb, kb, db, awb, bwb, vb, st0, ybuf);
  k_post<<<16384, 256, 0, stream>>>(ybuf, vb, h2g, bonb, gnw, gnb, xoh, xol);
  k_gemm_bt3<<<dim3(32, 16), 256, 0, stream>>>(xoh, xol, Woh, Wol, out, BT, CC, CC);
}

// Round 14
// 770.945 us; speedup vs baseline: 1.4134x; 1.0281x over previous
//
#include <hip/hip_runtime.h>
#include <hip/hip_bf16.h>

// Problem constants (RWKV-7 Tmix: B=2, T=1024, C=2048, H=32, N=64)
#define BB 2
#define TT 1024
#define CC 2048
#define HH 32
#define BT 2048          // BB*TT tokens
#define GN_EPS 6.4e-4f   // 1e-5 * 8^2

typedef __attribute__((ext_vector_type(8))) __bf16 bf16x8;
typedef __attribute__((ext_vector_type(4))) float f32x4;

__device__ __forceinline__ float sigf(float x) { return 1.0f / (1.0f + expf(-x)); }

__device__ __forceinline__ void split_bf16(float x, __hip_bfloat16& hi, __hip_bfloat16& lo) {
  __hip_bfloat16 h = __float2bfloat16(x);
  hi = h;
  lo = __float2bfloat16(x - __bfloat162float(h));
}

__device__ __forceinline__ unsigned short bfb(float x) {
  union { __hip_bfloat16 h; unsigned short u; } cv;
  cv.h = __float2bfloat16(x);
  return cv.u;
}
__device__ __forceinline__ void splitu(float x, unsigned short& hi, unsigned short& lo) {
  union { __hip_bfloat16 h; unsigned short u; } cv;
  cv.h = __float2bfloat16(x);
  hi = cv.u;
  lo = bfb(x - __bfloat162float(cv.h));
}

// Sum over each aligned 16-lane group, pure DPP (no LDS pipe on the chain).
__device__ __forceinline__ float red16(float x) {
  x += __int_as_float(__builtin_amdgcn_update_dpp(
      0, __float_as_int(x), 0xB1 /*quad_perm [1,0,3,2]*/, 0xF, 0xF, true));
  x += __int_as_float(__builtin_amdgcn_update_dpp(
      0, __float_as_int(x), 0x4E /*quad_perm [2,3,0,1]*/, 0xF, 0xF, true));
  x += __int_as_float(__builtin_amdgcn_update_dpp(
      0, __float_as_int(x), 0x141 /*row_half_mirror*/, 0xF, 0xF, true));
  x += __int_as_float(__builtin_amdgcn_update_dpp(
      0, __float_as_int(x), 0x140 /*row_mirror*/, 0xF, 0xF, true));
  return x;
}

// ---------------------------------------------------------------------------
// K1: token shift + six lerped projections — ROUND-21: 4-wide vectorized
// (float4 loads, ushort4 bf16 stores; was scalar = G13's 2-2.5x penalty).
// ---------------------------------------------------------------------------
__global__ __launch_bounds__(256) void k_prepx(
    const float* __restrict__ hid, const float* __restrict__ shift,
    const float* __restrict__ xrc, const float* __restrict__ xwc,
    const float* __restrict__ xkc, const float* __restrict__ xvc,
    const float* __restrict__ xac, const float* __restrict__ xgc,
    __hip_bfloat16* __restrict__ xrh, __hip_bfloat16* __restrict__ xrl,
    __hip_bfloat16* __restrict__ xw,
    __hip_bfloat16* __restrict__ xkh, __hip_bfloat16* __restrict__ xkl,
    __hip_bfloat16* __restrict__ xvh, __hip_bfloat16* __restrict__ xvl,
    __hip_bfloat16* __restrict__ xa, __hip_bfloat16* __restrict__ xg) {
  int i4 = (blockIdx.x * 256 + threadIdx.x) * 4;   // < BT*CC
  int c  = i4 & (CC - 1);
  int bt = i4 >> 11;
  int t  = bt & (TT - 1);
  int b  = bt >> 10;
  float4 hc = *(const float4*)&hid[i4];
  float4 hp = (t == 0) ? *(const float4*)&shift[b * CC + c]
                       : *(const float4*)&hid[i4 - CC];
  float xxv[4] = {hp.x - hc.x, hp.y - hc.y, hp.z - hc.z, hp.w - hc.w};
  float hcv[4] = {hc.x, hc.y, hc.z, hc.w};
  float4 crv = *(const float4*)&xrc[c];
  float4 cwv = *(const float4*)&xwc[c];
  float4 ckv = *(const float4*)&xkc[c];
  float4 cvv = *(const float4*)&xvc[c];
  float4 cav = *(const float4*)&xac[c];
  float4 cgv = *(const float4*)&xgc[c];
  float cr[4] = {crv.x, crv.y, crv.z, crv.w};
  float cw[4] = {cwv.x, cwv.y, cwv.z, cwv.w};
  float ck[4] = {ckv.x, ckv.y, ckv.z, ckv.w};
  float cv[4] = {cvv.x, cvv.y, cvv.z, cvv.w};
  float ca[4] = {cav.x, cav.y, cav.z, cav.w};
  float cg[4] = {cgv.x, cgv.y, cgv.z, cgv.w};
  ushort4 rh, rl, kh, kl, vh, vl, wv, av, gv;
  unsigned short* prh = (unsigned short*)&rh;
  unsigned short* prl = (unsigned short*)&rl;
  unsigned short* pkh = (unsigned short*)&kh;
  unsigned short* pkl = (unsigned short*)&kl;
  unsigned short* pvh = (unsigned short*)&vh;
  unsigned short* pvl = (unsigned short*)&vl;
  unsigned short* pw  = (unsigned short*)&wv;
  unsigned short* pa  = (unsigned short*)&av;
  unsigned short* pg  = (unsigned short*)&gv;
#pragma unroll
  for (int j = 0; j < 4; ++j) {
    splitu(fmaf(xxv[j], cr[j], hcv[j]), prh[j], prl[j]);
    splitu(fmaf(xxv[j], ck[j], hcv[j]), pkh[j], pkl[j]);
    splitu(fmaf(xxv[j], cv[j], hcv[j]), pvh[j], pvl[j]);
    pw[j] = bfb(fmaf(xxv[j], cw[j], hcv[j]));
    pa[j] = bfb(fmaf(xxv[j], ca[j], hcv[j]));
    pg[j] = bfb(fmaf(xxv[j], cg[j], hcv[j]));
  }
  *(ushort4*)&xrh[i4] = rh; *(ushort4*)&xrl[i4] = rl;
  *(ushort4*)&xkh[i4] = kh; *(ushort4*)&xkl[i4] = kl;
  *(ushort4*)&xvh[i4] = vh; *(ushort4*)&xvl[i4] = vl;
  *(ushort4*)&xw[i4]  = wv; *(ushort4*)&xa[i4]  = av;
  *(ushort4*)&xg[i4]  = gv;
}

// ---------------------------------------------------------------------------
// K2: f32 -> hi+lo bf16 split for all four big weights, 4-wide vectorized.
// ---------------------------------------------------------------------------
__global__ __launch_bounds__(256) void k_cvt2x4(
    const float* __restrict__ i0, const float* __restrict__ i1,
    const float* __restrict__ i2, const float* __restrict__ i3,
    __hip_bfloat16* __restrict__ h0, __hip_bfloat16* __restrict__ l0,
    __hip_bfloat16* __restrict__ h1, __hip_bfloat16* __restrict__ l1,
    __hip_bfloat16* __restrict__ h2, __hip_bfloat16* __restrict__ l2,
    __hip_bfloat16* __restrict__ h3, __hip_bfloat16* __restrict__ l3) {
  int i4 = (blockIdx.x * 256 + threadIdx.x) * 4;
  int w = blockIdx.y;
  const float* in = (w == 0) ? i0 : (w == 1) ? i1 : (w == 2) ? i2 : i3;
  __hip_bfloat16* oh = (w == 0) ? h0 : (w == 1) ? h1 : (w == 2) ? h2 : h3;
  __hip_bfloat16* ol = (w == 0) ? l0 : (w == 1) ? l1 : (w == 2) ? l2 : l3;
  float4 v = *(const float4*)&in[i4];
  float vv[4] = {v.x, v.y, v.z, v.w};
  ushort4 hv, lv;
  unsigned short* ph = (unsigned short*)&hv;
  unsigned short* pl = (unsigned short*)&lv;
#pragma unroll
  for (int j = 0; j < 4; ++j) splitu(vv[j], ph[j], pl[j]);
  *(ushort4*)&oh[i4] = hv;
  *(ushort4*)&ol[i4] = lv;
}

// ---------------------------------------------------------------------------
// K3: fused transpose-convert of the 4 stage-1 "up" weights (one dispatch).
// slice y: in [2048][N0] f32 -> out [NP][2048] bf16, rows >= N0 zero.
// ---------------------------------------------------------------------------
__global__ __launch_bounds__(256) void k_tr4(
    const float* __restrict__ w1, const float* __restrict__ a1,
    const float* __restrict__ v1, const float* __restrict__ g1,
    __hip_bfloat16* __restrict__ w1t, __hip_bfloat16* __restrict__ a1t,
    __hip_bfloat16* __restrict__ v1t, __hip_bfloat16* __restrict__ g1t) {
  int i = blockIdx.x * 256 + threadIdx.x;   // < 128*2048 max
  int y = blockIdx.y;
  const float* in; __hip_bfloat16* out; int N0, NP;
  if (y == 0)      { in = w1; out = w1t; N0 = 64;  NP = 64;  }
  else if (y == 1) { in = a1; out = a1t; N0 = 64;  NP = 64;  }
  else if (y == 2) { in = v1; out = v1t; N0 = 32;  NP = 64;  }
  else             { in = g1; out = g1t; N0 = 128; NP = 128; }
  if (i >= NP * 2048) return;
  int n = i >> 11;
  int k = i & 2047;
  float v = (n < N0) ? in[k * N0 + n] : 0.0f;
  out[i] = __float2bfloat16(v);
}

// ---------------------------------------------------------------------------
// K3b: fused transpose+split of the 4 stage-2 "down" weights (one dispatch).
// slice y: in [N0][CC] f32 -> out [CC][K0] bf16 hi+lo, cols >= N0 zero.
// ---------------------------------------------------------------------------
__global__ __launch_bounds__(256) void k_trs4(
    const float* __restrict__ w2, const float* __restrict__ a2,
    const float* __restrict__ v2, const float* __restrict__ g2,
    __hip_bfloat16* __restrict__ w2th, __hip_bfloat16* __restrict__ w2tl,
    __hip_bfloat16* __restrict__ a2th, __hip_bfloat16* __restrict__ a2tl,
    __hip_bfloat16* __restrict__ v2th, __hip_bfloat16* __restrict__ v2tl,
    __hip_bfloat16* __restrict__ g2th, __hip_bfloat16* __restrict__ g2tl) {
  int i = blockIdx.x * 256 + threadIdx.x;   // < CC*128 max
  int y = blockIdx.y;
  const float* in; __hip_bfloat16 *oh, *ol; int N0, lgK;
  if (y == 0)      { in = w2; oh = w2th; ol = w2tl; N0 = 64;  lgK = 6; }
  else if (y == 1) { in = a2; oh = a2th; ol = a2tl; N0 = 64;  lgK = 6; }
  else if (y == 2) { in = v2; oh = v2th; ol = v2tl; N0 = 32;  lgK = 6; }
  else             { in = g2; oh = g2th; ol = g2tl; N0 = 128; lgK = 7; }
  if (i >= (CC << lgK)) return;
  int n = i >> lgK;
  int k = i & ((1 << lgK) - 1);
  float v = (k < N0) ? in[k * CC + n] : 0.0f;
  split_bf16(v, oh[i], ol[i]);
}

// ---------------------------------------------------------------------------
// K4: fused stage-1 LoRA GEMM, LDS-staged (r11 winner, unchanged).
// ---------------------------------------------------------------------------
__global__ __launch_bounds__(256, 4) void k_lora1(
    const __hip_bfloat16* __restrict__ xw, const __hip_bfloat16* __restrict__ xa,
    const __hip_bfloat16* __restrict__ xv, const __hip_bfloat16* __restrict__ xg,
    const __hip_bfloat16* __restrict__ w1t, const __hip_bfloat16* __restrict__ a1t,
    const __hip_bfloat16* __restrict__ v1t, const __hip_bfloat16* __restrict__ g1t,
    float* __restrict__ h1w, float* __restrict__ h1a,
    float* __restrict__ h1v, float* __restrict__ h1g) {
  __shared__ __align__(16) __hip_bfloat16 sA[2][64 * 32], sB[2][64 * 32];
  int tid  = threadIdx.x;
  int lane = tid & 63;
  int wv   = tid >> 6;
  int l15  = lane & 15;
  int quad = lane >> 4;
  int m0 = blockIdx.x * 64;
  int bly = blockIdx.y;

  const __hip_bfloat16* Ab;
  const __hip_bfloat16* Bb;
  float* Ob;
  int os, cb;
  if (bly == 0)      { Ab = xw; Bb = w1t;            Ob = h1w; os = 64;  cb = 0;  }
  else if (bly == 1) { Ab = xa; Bb = a1t;            Ob = h1a; os = 64;  cb = 0;  }
  else if (bly == 2) { Ab = xv; Bb = v1t;            Ob = h1v; os = 64;  cb = 0;  }
  else if (bly == 3) { Ab = xg; Bb = g1t;            Ob = h1g; os = 128; cb = 0;  }
  else               { Ab = xg; Bb = g1t + 64 * CC;  Ob = h1g; os = 128; cb = 64; }

  int srow = wv * 16 + (lane >> 2);
  int scol = (lane & 3) * 8;
  const __hip_bfloat16* gA = Ab + (size_t)(m0 + srow) * CC + scol;
  const __hip_bfloat16* gB = Bb + (size_t)srow * CC + scol;

  f32x4 z = {0.f, 0.f, 0.f, 0.f};
  f32x4 acc0 = z, acc1 = z, acc2 = z, acc3 = z;

  int aoff = (wv * 16 + l15) * 32 + quad * 8;
  int boff = l15 * 32 + quad * 8;

#define STAGE1(BUF, KO)                                                      \
  { unsigned db_ = (unsigned)(BUF) * 4096u + (unsigned)wv * 1024u;           \
    __builtin_amdgcn_global_load_lds(                                        \
        (const __attribute__((address_space(1))) void*)(gA + (KO)),          \
        (__attribute__((address_space(3))) void*)((char*)sA + db_), 16, 0, 0);\
    __builtin_amdgcn_global_load_lds(                                        \
        (const __attribute__((address_space(1))) void*)(gB + (KO)),          \
        (__attribute__((address_space(3))) void*)((char*)sB + db_), 16, 0, 0);}

  STAGE1(0, 0)
  __syncthreads();

  for (int k0 = 0; k0 < CC; k0 += 32) {
    int cur = (k0 >> 5) & 1;
    if (k0 + 32 < CC) STAGE1(cur ^ 1, k0 + 32)

    const __hip_bfloat16* pA_ = &sA[cur][0];
    const __hip_bfloat16* pB_ = &sB[cur][0];
    bf16x8 av = *(const bf16x8*)(pA_ + aoff);
    bf16x8 b0 = *(const bf16x8*)(pB_ + boff);
    bf16x8 b1 = *(const bf16x8*)(pB_ + boff + 16 * 32);
    bf16x8 b2 = *(const bf16x8*)(pB_ + boff + 32 * 32);
    bf16x8 b3 = *(const bf16x8*)(pB_ + boff + 48 * 32);

    acc0 = __builtin_amdgcn_mfma_f32_16x16x32_bf16(av, b0, acc0, 0, 0, 0);
    acc1 = __builtin_amdgcn_mfma_f32_16x16x32_bf16(av, b1, acc1, 0, 0, 0);
    acc2 = __builtin_amdgcn_mfma_f32_16x16x32_bf16(av, b2, acc2, 0, 0, 0);
    acc3 = __builtin_amdgcn_mfma_f32_16x16x32_bf16(av, b3, acc3, 0, 0, 0);

    __syncthreads();
  }
#undef STAGE1

  int row0 = m0 + wv * 16 + quad * 4;
  int colb = cb + l15;
#pragma unroll
  for (int r = 0; r < 4; ++r) {
    Ob[(size_t)(row0 + r) * os + colb +  0] = acc0[r];
    Ob[(size_t)(row0 + r) * os + colb + 16] = acc1[r];
    Ob[(size_t)(row0 + r) * os + colb + 32] = acc2[r];
    Ob[(size_t)(row0 + r) * os + colb + 48] = acc3[r];
  }
}

// ---------------------------------------------------------------------------
// K4b: split-precision GEMM — 64x128 tile, 2-phase LDS staging (r12 winner).
// ---------------------------------------------------------------------------
__global__ __launch_bounds__(256, 3) void k_gemm_bt3(
    const __hip_bfloat16* __restrict__ Ah, const __hip_bfloat16* __restrict__ Al,
    const __hip_bfloat16* __restrict__ Bh, const __hip_bfloat16* __restrict__ Bl,
    float* __restrict__ Cm, int M, int Nn, int K) {
  __shared__ __align__(16) __hip_bfloat16 sAh[2][64 * 32],  sAl[2][64 * 32];
  __shared__ __align__(16) __hip_bfloat16 sBh[2][128 * 32], sBl[2][128 * 32];
  int tid  = threadIdx.x;
  int lane = tid & 63;
  int wv   = tid >> 6;
  int l15  = lane & 15;
  int quad = lane >> 4;
  int m0 = blockIdx.x * 64;
  int n0 = blockIdx.y * 128;

  int srowA = wv * 16 + (lane >> 2);
  int srowB = wv * 32 + (lane >> 2);
  int scol  = (lane & 3) * 8;
  const __hip_bfloat16* gAh  = Ah + (size_t)(m0 + srowA) * K + scol;
  const __hip_bfloat16* gAl  = Al + (size_t)(m0 + srowA) * K + scol;
  const __hip_bfloat16* gBh0 = Bh + (size_t)(n0 + srowB) * K + scol;
  const __hip_bfloat16* gBh1 = Bh + (size_t)(n0 + srowB + 16) * K + scol;
  const __hip_bfloat16* gBl0 = Bl + (size_t)(n0 + srowB) * K + scol;
  const __hip_bfloat16* gBl1 = Bl + (size_t)(n0 + srowB + 16) * K + scol;

  f32x4 z = {0.f, 0.f, 0.f, 0.f};
  f32x4 acc[8];
#pragma unroll
  for (int j = 0; j < 8; ++j) acc[j] = z;

  int aoff = (wv * 16 + l15) * 32 + quad * 8;
  int boff = l15 * 32 + quad * 8;

#define STAGE(BUF, KO)                                                       \
  { unsigned dA_ = (unsigned)(BUF) * 4096u + (unsigned)wv * 1024u;           \
    unsigned dB_ = (unsigned)(BUF) * 8192u + (unsigned)wv * 2048u;           \
    __builtin_amdgcn_global_load_lds(                                        \
        (const __attribute__((address_space(1))) void*)(gAh + (KO)),         \
        (__attribute__((address_space(3))) void*)((char*)sAh + dA_), 16, 0, 0);\
    __builtin_amdgcn_global_load_lds(                                        \
        (const __attribute__((address_space(1))) void*)(gAl + (KO)),         \
        (__attribute__((address_space(3))) void*)((char*)sAl + dA_), 16, 0, 0);\
    __builtin_amdgcn_global_load_lds(                                        \
        (const __attribute__((address_space(1))) void*)(gBh0 + (KO)),        \
        (__attribute__((address_space(3))) void*)((char*)sBh + dB_), 16, 0, 0);\
    __builtin_amdgcn_global_load_lds(                                        \
        (const __attribute__((address_space(1))) void*)(gBh1 + (KO)),        \
        (__attribute__((address_space(3))) void*)((char*)sBh + dB_ + 1024u), 16, 0, 0);\
    __builtin_amdgcn_global_load_lds(                                        \
        (const __attribute__((address_space(1))) void*)(gBl0 + (KO)),        \
        (__attribute__((address_space(3))) void*)((char*)sBl + dB_), 16, 0, 0);\
    __builtin_amdgcn_global_load_lds(                                        \
        (const __attribute__((address_space(1))) void*)(gBl1 + (KO)),        \
        (__attribute__((address_space(3))) void*)((char*)sBl + dB_ + 1024u), 16, 0, 0);}

  STAGE(0, 0)
  __syncthreads();   // buf0 staged (implicit vmcnt(0) drain before barrier)

  for (int k0 = 0; k0 < K; k0 += 32) {
    int cur = (k0 >> 5) & 1;
    if (k0 + 32 < K) STAGE(cur ^ 1, k0 + 32)   // next tile in flight NOW

    const __hip_bfloat16* pA_h = &sAh[cur][0];
    const __hip_bfloat16* pA_l = &sAl[cur][0];
    const __hip_bfloat16* pB_h = &sBh[cur][0];
    const __hip_bfloat16* pB_l = &sBl[cur][0];
    bf16x8 ah = *(const bf16x8*)(pA_h + aoff);
    bf16x8 al = *(const bf16x8*)(pA_l + aoff);
#pragma unroll
    for (int j = 0; j < 8; ++j) {
      bf16x8 bh = *(const bf16x8*)(pB_h + boff + j * 16 * 32);
      bf16x8 bl = *(const bf16x8*)(pB_l + boff + j * 16 * 32);
      acc[j] = __builtin_amdgcn_mfma_f32_16x16x32_bf16(ah, bh, acc[j], 0, 0, 0);
      acc[j] = __builtin_amdgcn_mfma_f32_16x16x32_bf16(ah, bl, acc[j], 0, 0, 0);
      acc[j] = __builtin_amdgcn_mfma_f32_16x16x32_bf16(al, bh, acc[j], 0, 0, 0);
    }

    __syncthreads();   // ONE barrier: next buf staged + this buf reads done
  }
#undef STAGE

  int row0 = m0 + wv * 16 + quad * 4;
#pragma unroll
  for (int j = 0; j < 8; ++j) {
    int colb = n0 + j * 16 + l15;
#pragma unroll
    for (int r = 0; r < 4; ++r)
      Cm[(size_t)(row0 + r) * Nn + colb] = acc[j][r];
  }
}

// ---------------------------------------------------------------------------
// K5: activations + hi/lo split of stage-1 LoRA outputs — 4-wide vectorized.
// ---------------------------------------------------------------------------
__global__ __launch_bounds__(256) void k_act2(
    const float* __restrict__ h1w, const float* __restrict__ h1a,
    const float* __restrict__ h1v, const float* __restrict__ h1g,
    __hip_bfloat16* __restrict__ wh, __hip_bfloat16* __restrict__ wl,
    __hip_bfloat16* __restrict__ ah, __hip_bfloat16* __restrict__ al,
    __hip_bfloat16* __restrict__ vh, __hip_bfloat16* __restrict__ vl,
    __hip_bfloat16* __restrict__ gh, __hip_bfloat16* __restrict__ gl) {
  int i4 = (blockIdx.x * 256 + threadIdx.x) * 4;   // over BT*128
  if (i4 < BT * 64) {
    float4 w = *(const float4*)&h1w[i4];
    float4 a = *(const float4*)&h1a[i4];
    float4 v = *(const float4*)&h1v[i4];
    float wvv[4] = {w.x, w.y, w.z, w.w};
    float avv[4] = {a.x, a.y, a.z, a.w};
    float vvv[4] = {v.x, v.y, v.z, v.w};
    ushort4 whv, wlv, ahv, alv, vhv, vlv;
    unsigned short* p0 = (unsigned short*)&whv;
    unsigned short* p1 = (unsigned short*)&wlv;
    unsigned short* p2 = (unsigned short*)&ahv;
    unsigned short* p3 = (unsigned short*)&alv;
    unsigned short* p4 = (unsigned short*)&vhv;
    unsigned short* p5 = (unsigned short*)&vlv;
#pragma unroll
    for (int j = 0; j < 4; ++j) {
      splitu(tanhf(wvv[j]), p0[j], p1[j]);
      splitu(avv[j], p2[j], p3[j]);
      splitu(vvv[j], p4[j], p5[j]);
    }
    *(ushort4*)&wh[i4] = whv; *(ushort4*)&wl[i4] = wlv;
    *(ushort4*)&ah[i4] = ahv; *(ushort4*)&al[i4] = alv;
    *(ushort4*)&vh[i4] = vhv; *(ushort4*)&vl[i4] = vlv;
  }
  float4 g = *(const float4*)&h1g[i4];
  float gvv[4] = {g.x, g.y, g.z, g.w};
  ushort4 ghv, glv;
  unsigned short* p6 = (unsigned short*)&ghv;
  unsigned short* p7 = (unsigned short*)&glv;
#pragma unroll
  for (int j = 0; j < 4; ++j) splitu(sigf(gvv[j]), p6[j], p7[j]);
  *(ushort4*)&gh[i4] = ghv; *(ushort4*)&gl[i4] = glv;
}

// ---------------------------------------------------------------------------
// K6: gates + kk-normalize + per-head bonus — 4-wide: 16 lanes x 4 cols per
// head; reductions via pure-DPP red16 (drops the 6x ds_swizzle chain).
// ---------------------------------------------------------------------------
__global__ __launch_bounds__(256) void k_gate(
    const float* __restrict__ h2w, const float* __restrict__ h2a,
    const float* __restrict__ h2v,
    const float* __restrict__ w0, const float* __restrict__ a0,
    const float* __restrict__ v0, const float* __restrict__ kkc,
    const float* __restrict__ kac, float* __restrict__ kbuf,
    float* __restrict__ vbuf, const float* __restrict__ vfirst,
    const float* __restrict__ rbuf, const float* __restrict__ rk,
    float* __restrict__ dec, float* __restrict__ aw,
    float* __restrict__ bw, float* __restrict__ bonb) {
  int i4 = (blockIdx.x * 256 + threadIdx.x) * 4;   // < BT*CC
  int c = i4 & (CC - 1);
  float4 kv4 = *(const float4*)&kbuf[i4];
  float4 vv4 = *(const float4*)&vbuf[i4];
  float4 vf4 = *(const float4*)&vfirst[i4];
  float4 hw4 = *(const float4*)&h2w[i4];
  float4 ha4 = *(const float4*)&h2a[i4];
  float4 hv4 = *(const float4*)&h2v[i4];
  float4 w04 = *(const float4*)&w0[c];
  float4 a04 = *(const float4*)&a0[c];
  float4 v04 = *(const float4*)&v0[c];
  float4 kk4 = *(const float4*)&kkc[c];
  float4 ka4 = *(const float4*)&kac[c];
  float4 rk4 = *(const float4*)&rk[c];
  float4 rb4 = *(const float4*)&rbuf[i4];
  float kv[4] = {kv4.x, kv4.y, kv4.z, kv4.w};
  float vv[4] = {vv4.x, vv4.y, vv4.z, vv4.w};
  float vf[4] = {vf4.x, vf4.y, vf4.z, vf4.w};
  float hw[4] = {hw4.x, hw4.y, hw4.z, hw4.w};
  float ha[4] = {ha4.x, ha4.y, ha4.z, ha4.w};
  float hv[4] = {hv4.x, hv4.y, hv4.z, hv4.w};
  float w0v[4] = {w04.x, w04.y, w04.z, w04.w};
  float a0v[4] = {a04.x, a04.y, a04.z, a04.w};
  float v0v[4] = {v04.x, v04.y, v04.z, v04.w};
  float kkv[4] = {kk4.x, kk4.y, kk4.z, kk4.w};
  float kav[4] = {ka4.x, ka4.y, ka4.z, ka4.w};
  float rkv[4] = {rk4.x, rk4.y, rk4.z, rk4.w};
  float rbv[4] = {rb4.x, rb4.y, rb4.z, rb4.w};
  float d_[4], as[4], vm[4], kfv[4], kku[4];
  float sl = 0.f, bl = 0.f;
#pragma unroll
  for (int j = 0; j < 4; ++j) {
    d_[j] = 0.60653065971f * sigf(w0v[j] + hw[j]);   // sigmoid * e^-0.5
    as[j] = sigf(a0v[j] + ha[j]);
    float vs = sigf(v0v[j] + hv[j]);
    vm[j] = vv[j] + (vf[j] - vv[j]) * vs;
    kfv[j] = kv[j] * (1.0f + kav[j] * (as[j] - 1.0f));
    kku[j] = kv[j] * kkv[j];
    sl = fmaf(kku[j], kku[j], sl);
    bl = fmaf(rbv[j] * kfv[j], rkv[j], bl);
  }
  float s = red16(sl);                 // per-head L2 (16 lanes x 4 cols)
  float nrm = fmaxf(sqrtf(s), 1e-12f);
  float bon = red16(bl);
  if ((threadIdx.x & 15) == 0) bonb[(i4 >> 11) * HH + (c >> 6)] = bon;
  float4 o0, o1, o2, o3, o4;
  float* q0 = (float*)&o0; float* q1 = (float*)&o1; float* q2 = (float*)&o2;
  float* q3 = (float*)&o3; float* q4 = (float*)&o4;
#pragma unroll
  for (int j = 0; j < 4; ++j) {
    float kkn = kku[j] / nrm;
    q0[j] = d_[j];
    q1[j] = -kkn;
    q2[j] = kkn * as[j];
    q3[j] = kfv[j];
    q4[j] = vm[j];
  }
  *(float4*)&dec[i4] = o0;
  *(float4*)&aw[i4]  = o1;
  *(float4*)&bw[i4]  = o2;
  *(float4*)&kbuf[i4] = o3;
  *(float4*)&vbuf[i4] = o4;
}

// ---------------------------------------------------------------------------
// K7: WKV7 scan — r13 counted-lgkm LDS-DMA-ring version (~180 µs), unchanged.
// ---------------------------------------------------------------------------
__global__ __launch_bounds__(64, 1) void k_scan(
    const float* __restrict__ rbuf, const float* __restrict__ kf,
    const float* __restrict__ dec, const float* __restrict__ aw,
    const float* __restrict__ bw, const float* __restrict__ vbuf,
    const float* __restrict__ st0, float* __restrict__ ybuf) {
  __shared__ __align__(16) char ldsbuf[16 * 2048];
  int blk = blockIdx.x;                     // 0..1023
  int xcd = blk & 7;
  int q   = blk >> 3;                       // 0..127
  int bh  = xcd * 8 + (q & 7);              // 16 rg-waves of a head share blk%8
  int rg  = q >> 3;                         // 0..15
  int b = bh >> 5, h = bh & 31;
  int lane = threadIdx.x;
  int l15  = lane & 15;
  int row  = rg * 4 + (lane >> 4);
  size_t tokbase = (size_t)b * TT * CC + h * 64;

  f32x4 S = *(const f32x4*)(st0 + ((size_t)bh * 64 + row) * 64 + l15 * 4);
  bool writer = (l15 == 0);
  float* yout = ybuf + tokbase + row;

  const float* g1 = (lane < 16 ? rbuf : lane < 32 ? kf : lane < 48 ? dec : aw)
                  + tokbase + l15 * 4;
  const float* g2 = (lane < 16) ? (bw + tokbase + l15 * 4)
                                : (vbuf + tokbase + rg * 4);

  unsigned lbase = (unsigned)(uintptr_t)(__attribute__((address_space(3))) char*)ldsbuf;
  unsigned larr = lbase + (unsigned)(l15 * 16);
  unsigned lvad = lbase + 1280u + (unsigned)((lane >> 4) * 4);

#define DMAQ(T)                                                              \
  { char* sb_ = ldsbuf + (((T) & 15) << 11);                                 \
    __builtin_amdgcn_global_load_lds(                                        \
        (const __attribute__((address_space(1))) void*)g1,                   \
        (__attribute__((address_space(3))) void*)sb_, 16, 0, 0);             \
    __builtin_amdgcn_global_load_lds(                                        \
        (const __attribute__((address_space(1))) void*)g2,                   \
        (__attribute__((address_space(3))) void*)(sb_ + 1024), 16, 0, 0);    \
    g1 += CC; g2 += CC; }

#define DSRD(RR, RK, RD, RA, RB, RV, T)                                      \
  { unsigned a_ = larr + (unsigned)(((T) & 15) << 11);                       \
    unsigned v_ = lvad + (unsigned)(((T) & 15) << 11);                       \
    asm volatile("ds_read_b128 %0, %1"             : "=v"(RR) : "v"(a_));    \
    asm volatile("ds_read_b128 %0, %1 offset:256"  : "=v"(RK) : "v"(a_));    \
    asm volatile("ds_read_b128 %0, %1 offset:512"  : "=v"(RD) : "v"(a_));    \
    asm volatile("ds_read_b128 %0, %1 offset:768"  : "=v"(RA) : "v"(a_));    \
    asm volatile("ds_read_b128 %0, %1 offset:1024" : "=v"(RB) : "v"(a_));    \
    asm volatile("ds_read_b32 %0, %1"              : "=v"(RV) : "v"(v_)); }

#define WVM(N) { asm volatile("s_waitcnt vmcnt(" #N ")" ::: "memory");       \
                 __builtin_amdgcn_sched_barrier(0); }
#define WLG    { asm volatile("s_waitcnt lgkmcnt(0)" ::: "memory");          \
                 __builtin_amdgcn_sched_barrier(0); }
#define WLG6   { asm volatile("s_waitcnt lgkmcnt(6)" ::: "memory");          \
                 __builtin_amdgcn_sched_barrier(0); }

#define STEPR(RR, RK, RD, RA, RB, RV, T)                                     \
  { float sa = fmaf(S.w, RA.w, fmaf(S.z, RA.z,                               \
               fmaf(S.y, RA.y, S.x * RA.x)));                                \
    sa = red16(sa);                                                          \
    float vv = RV;                                                           \
    S.x = fmaf(S.x, RD.x, fmaf(sa, RB.x, vv * RK.x));                        \
    S.y = fmaf(S.y, RD.y, fmaf(sa, RB.y, vv * RK.y));                        \
    S.z = fmaf(S.z, RD.z, fmaf(sa, RB.z, vv * RK.z));                        \
    S.w = fmaf(S.w, RD.w, fmaf(sa, RB.w, vv * RK.w));                        \
    float y = fmaf(S.w, RR.w, fmaf(S.z, RR.z,                                \
              fmaf(S.y, RR.y, S.x * RR.x)));                                 \
    y = red16(y);                                                            \
    if (writer) yout[(size_t)(T) * CC] = y; }

  for (int tt = 0; tt < 16; ++tt) DMAQ(tt)

  f32x4 Ar, Ak, Ad, Aa, Ab; float Av;
  f32x4 Br, Bk, Bd, Ba, Bb; float Bv;

  WVM(24)
  DSRD(Ar, Ak, Ad, Aa, Ab, Av, 0)
  WLG
  DSRD(Br, Bk, Bd, Ba, Bb, Bv, 1)

  int t = 0;
  for (; t < TT - 16; t += 2) {
    DMAQ(t + 16)
    STEPR(Ar, Ak, Ad, Aa, Ab, Av, t)
    DSRD(Ar, Ak, Ad, Aa, Ab, Av, t + 2)
    WLG6
    DMAQ(t + 17)
    STEPR(Br, Bk, Bd, Ba, Bb, Bv, t + 1)
    DSRD(Br, Bk, Bd, Ba, Bb, Bv, t + 3)
    WLG6
  }
  for (; t < TT - 2; t += 2) {
    STEPR(Ar, Ak, Ad, Aa, Ab, Av, t)
    DSRD(Ar, Ak, Ad, Aa, Ab, Av, t + 2)
    WLG6
    STEPR(Br, Bk, Bd, Ba, Bb, Bv, t + 1)
    if (t + 3 < TT) DSRD(Br, Bk, Bd, Ba, Bb, Bv, t + 3)
    WLG6
  }
  STEPR(Ar, Ak, Ad, Aa, Ab, Av, TT - 2)
  WLG
  STEPR(Br, Bk, Bd, Ba, Bb, Bv, TT - 1)
#undef DMAQ
#undef DSRD
#undef WVM
#undef WLG
#undef WLG6
#undef STEPR
}

// ---------------------------------------------------------------------------
// K8: post-scan epilogue — 4-wide: 16-lane group per (token,head), red16
// statistics, float4 loads, ushort4 stores.
// ---------------------------------------------------------------------------
__global__ __launch_bounds__(256) void k_post(
    const float* __restrict__ ybuf, const float* __restrict__ vb,
    const float* __restrict__ gvb, const float* __restrict__ bonb,
    const float* __restrict__ gnw, const float* __restrict__ gnb,
    __hip_bfloat16* __restrict__ xoh, __hip_bfloat16* __restrict__ xol) {
  int gid = blockIdx.x * 16 + (threadIdx.x >> 4);   // 0..BT*HH-1
  int l15 = threadIdx.x & 15;
  int bt = gid >> 5, h = gid & 31;
  size_t base = (size_t)bt * CC + h * 64 + l15 * 4;
  float4 y4 = *(const float4*)&ybuf[base];
  float yv[4] = {y4.x, y4.y, y4.z, y4.w};
  float s1 = yv[0] + yv[1] + yv[2] + yv[3];
  float s2 = fmaf(yv[0], yv[0], fmaf(yv[1], yv[1],
             fmaf(yv[2], yv[2], yv[3] * yv[3])));
  s1 = red16(s1);
  s2 = red16(s2);
  float mean = s1 * (1.0f / 64.0f);
  float var  = s2 * (1.0f / 64.0f) - mean * mean;
  float inv  = rsqrtf(var + GN_EPS);
  float4 gw4 = *(const float4*)&gnw[h * 64 + l15 * 4];
  float4 gb4 = *(const float4*)&gnb[h * 64 + l15 * 4];
  float4 vb4 = *(const float4*)&vb[base];
  float4 gv4 = *(const float4*)&gvb[base];
  float gw[4] = {gw4.x, gw4.y, gw4.z, gw4.w};
  float gb[4] = {gb4.x, gb4.y, gb4.z, gb4.w};
  float vbv[4] = {vb4.x, vb4.y, vb4.z, vb4.w};
  float gvv[4] = {gv4.x, gv4.y, gv4.z, gv4.w};
  float bo = bonb[bt * HH + h];
  ushort4 hv, lv;
  unsigned short* ph = (unsigned short*)&hv;
  unsigned short* pl = (unsigned short*)&lv;
#pragma unroll
  for (int j = 0; j < 4; ++j) {
    float x = fmaf((yv[j] - mean) * inv, gw[j], gb[j]) + bo * vbv[j];
    splitu(x * gvv[j], ph[j], pl[j]);
  }
  *(ushort4*)&xoh[base] = hv;
  *(ushort4*)&xol[base] = lv;
}

// ---------------------------------------------------------------------------
extern "C" void kernel_launch(void* const* d_in, const int* in_sizes, int n_in,
                              void* d_out, int out_size, void* d_ws, size_t ws_size,
                              hipStream_t stream) {
  (void)in_sizes; (void)n_in; (void)out_size; (void)ws_size;
  const float* hid    = (const float*)d_in[0];
  const float* shift  = (const float*)d_in[1];
  const float* st0    = (const float*)d_in[2];
  const float* vfirst = (const float*)d_in[3];
  const float* xrc = (const float*)d_in[4];
  const float* xwc = (const float*)d_in[5];
  const float* xkc = (const float*)d_in[6];
  const float* xvc = (const float*)d_in[7];
  const float* xac = (const float*)d_in[8];
  const float* xgc = (const float*)d_in[9];
  const float* w0  = (const float*)d_in[10];
  const float* w1  = (const float*)d_in[11];
  const float* w2  = (const float*)d_in[12];
  const float* a0  = (const float*)d_in[13];
  const float* a1  = (const float*)d_in[14];
  const float* a2  = (const float*)d_in[15];
  const float* v0  = (const float*)d_in[16];
  const float* v1  = (const float*)d_in[17];
  const float* v2  = (const float*)d_in[18];
  const float* g1  = (const float*)d_in[19];
  const float* g2  = (const float*)d_in[20];
  const float* kkc = (const float*)d_in[21];
  const float* kac = (const float*)d_in[22];
  const float* rk  = (const float*)d_in[23];
  const float* Wr  = (const float*)d_in[24];
  const float* Wk  = (const float*)d_in[25];
  const float* Wv  = (const float*)d_in[26];
  const float* Wo  = (const float*)d_in[27];
  const float* gnw = (const float*)d_in[28];
  const float* gnb = (const float*)d_in[29];
  float* out = (float*)d_out;

  char* p = (char*)d_ws;
  auto alloc = [&](size_t n) { char* q = p; p += (n + 255) & ~(size_t)255; return q; };
  const size_t EL = (size_t)BT * CC;

  // --- alias pool: xrh..xvl + Wrh,Wrl dead by k_gate time; db/awb/bwb +
  //     h2g (the old gvb slot) overlay them.
  char* pool = p;
  __hip_bfloat16* xrh = (__hip_bfloat16*)alloc(EL * 2);
  __hip_bfloat16* xrl = (__hip_bfloat16*)alloc(EL * 2);
  __hip_bfloat16* xkh = (__hip_bfloat16*)alloc(EL * 2);
  __hip_bfloat16* xkl = (__hip_bfloat16*)alloc(EL * 2);
  __hip_bfloat16* xvh = (__hip_bfloat16*)alloc(EL * 2);
  __hip_bfloat16* xvl = (__hip_bfloat16*)alloc(EL * 2);
  __hip_bfloat16* Wrh = (__hip_bfloat16*)alloc((size_t)CC * CC * 2);
  __hip_bfloat16* Wrl = (__hip_bfloat16*)alloc((size_t)CC * CC * 2);
  float* db  = (float*)pool;           // overlays xrh+xrl
  float* awb = db + EL;                // overlays xkh+xkl
  float* bwb = db + 2 * EL;            // overlays xvh+xvl
  float* h2g = db + 3 * EL;            // overlays Wrh+Wrl (old gvb slot)

  __hip_bfloat16* Wkh = (__hip_bfloat16*)alloc((size_t)CC * CC * 2);
  __hip_bfloat16* Wkl = (__hip_bfloat16*)alloc((size_t)CC * CC * 2);
  float* ybuf = (float*)Wkh;           // overlays Wkh+Wkl (dead after k-GEMM)
  float* h2v  = (float*)Wkh;           // same region, read by k_gate BEFORE scan writes ybuf

  __hip_bfloat16* Wvh = (__hip_bfloat16*)alloc((size_t)CC * CC * 2);
  __hip_bfloat16* Wvl = (__hip_bfloat16*)alloc((size_t)CC * CC * 2);
  __hip_bfloat16* Woh = (__hip_bfloat16*)alloc((size_t)CC * CC * 2);
  __hip_bfloat16* Wol = (__hip_bfloat16*)alloc((size_t)CC * CC * 2);
  __hip_bfloat16* xw  = (__hip_bfloat16*)alloc(EL * 2);
  __hip_bfloat16* xa  = (__hip_bfloat16*)alloc(EL * 2);
  __hip_bfloat16* xg  = (__hip_bfloat16*)alloc(EL * 2);
  float* h2w = (float*)xw;             // overlays xw+xa (dead after stage-1 GEMMs)
  __hip_bfloat16* w1t = (__hip_bfloat16*)alloc((size_t)64  * CC * 2);
  __hip_bfloat16* a1t = (__hip_bfloat16*)alloc((size_t)64  * CC * 2);
  __hip_bfloat16* v1t = (__hip_bfloat16*)alloc((size_t)64  * CC * 2);
  __hip_bfloat16* g1t = (__hip_bfloat16*)alloc((size_t)128 * CC * 2);
  float* rb  = (float*)alloc(EL * 4);
  float* kb  = (float*)alloc(EL * 4);  // raw k, then k_final in place
  float* vb  = (float*)alloc(EL * 4);  // raw v, then v_mix in place
  float* h1w = (float*)alloc((size_t)BT * 64  * 4);
  float* h1a = (float*)alloc((size_t)BT * 64  * 4);
  float* h1v = (float*)alloc((size_t)BT * 64  * 4);
  float* h1g = (float*)alloc((size_t)BT * 128 * 4);
  __hip_bfloat16* xoh = (__hip_bfloat16*)alloc(EL * 2);
  __hip_bfloat16* xol = (__hip_bfloat16*)alloc(EL * 2);
  float* h2a = (float*)xoh;            // overlays xoh+xol (k_post writes them AFTER k_gate)
  float* bonb = (float*)alloc((size_t)BT * HH * 4);   // per-(token,head) bonus
  // stage-2 split operands (small, fresh):
  __hip_bfloat16* h1wh = (__hip_bfloat16*)alloc((size_t)BT * 64 * 2);
  __hip_bfloat16* h1wl = (__hip_bfloat16*)alloc((size_t)BT * 64 * 2);
  __hip_bfloat16* h1ah = (__hip_bfloat16*)alloc((size_t)BT * 64 * 2);
  __hip_bfloat16* h1al = (__hip_bfloat16*)alloc((size_t)BT * 64 * 2);
  __hip_bfloat16* h1vh = (__hip_bfloat16*)alloc((size_t)BT * 64 * 2);
  __hip_bfloat16* h1vl = (__hip_bfloat16*)alloc((size_t)BT * 64 * 2);
  __hip_bfloat16* h1gh = (__hip_bfloat16*)alloc((size_t)BT * 128 * 2);
  __hip_bfloat16* h1gl = (__hip_bfloat16*)alloc((size_t)BT * 128 * 2);
  __hip_bfloat16* w2th = (__hip_bfloat16*)alloc((size_t)CC * 64 * 2);
  __hip_bfloat16* w2tl = (__hip_bfloat16*)alloc((size_t)CC * 64 * 2);
  __hip_bfloat16* a2th = (__hip_bfloat16*)alloc((size_t)CC * 64 * 2);
  __hip_bfloat16* a2tl = (__hip_bfloat16*)alloc((size_t)CC * 64 * 2);
  __hip_bfloat16* v2th = (__hip_bfloat16*)alloc((size_t)CC * 64 * 2);
  __hip_bfloat16* v2tl = (__hip_bfloat16*)alloc((size_t)CC * 64 * 2);
  __hip_bfloat16* g2th = (__hip_bfloat16*)alloc((size_t)CC * 128 * 2);
  __hip_bfloat16* g2tl = (__hip_bfloat16*)alloc((size_t)CC * 128 * 2);
  // total ~210 MiB (known-OK envelope: 220 OK, 268 crashed)

  k_prepx<<<4096, 256, 0, stream>>>(hid, shift, xrc, xwc, xkc, xvc, xac, xgc,
                                    xrh, xrl, xw, xkh, xkl, xvh, xvl, xa, xg);
  k_cvt2x4<<<dim3(4096, 4), 256, 0, stream>>>(Wr, Wk, Wv, Wo,
                                              Wrh, Wrl, Wkh, Wkl,
                                              Wvh, Wvl, Woh, Wol);
  k_tr4<<<dim3(1024, 4), 256, 0, stream>>>(w1, a1, v1, g1, w1t, a1t, v1t, g1t);
  k_trs4<<<dim3(1024, 4), 256, 0, stream>>>(w2, a2, v2, g2,
                                            w2th, w2tl, a2th, a2tl,
                                            v2th, v2tl, g2th, g2tl);

  k_gemm_bt3<<<dim3(32, 16), 256, 0, stream>>>(xrh, xrl, Wrh, Wrl, rb, BT, CC, CC);
  k_gemm_bt3<<<dim3(32, 16), 256, 0, stream>>>(xkh, xkl, Wkh, Wkl, kb, BT, CC, CC);
  k_gemm_bt3<<<dim3(32, 16), 256, 0, stream>>>(xvh, xvl, Wvh, Wvl, vb, BT, CC, CC);
  k_lora1<<<dim3(32, 5), 256, 0, stream>>>(xw, xa, xvh, xg, w1t, a1t, v1t, g1t,
                                           h1w, h1a, h1v, h1g);

  k_act2<<<256, 256, 0, stream>>>(h1w, h1a, h1v, h1g,
                                  h1wh, h1wl, h1ah, h1al,
                                  h1vh, h1vl, h1gh, h1gl);
  // stage-2 LoRA dots on MFMA (split precision). Overlays now live:
  //   h2w->xw+xa, h2a->xoh+xol, h2v->Wkh+Wkl, h2g->Wrh+Wrl.
  k_gemm_bt3<<<dim3(32, 16), 256, 0, stream>>>(h1wh, h1wl, w2th, w2tl, h2w, BT, CC, 64);
  k_gemm_bt3<<<dim3(32, 16), 256, 0, stream>>>(h1ah, h1al, a2th, a2tl, h2a, BT, CC, 64);
  k_gemm_bt3<<<dim3(32, 16), 256, 0, stream>>>(h1vh, h1vl, v2th, v2tl, h2v, BT, CC, 64);
  k_gemm_bt3<<<dim3(32, 16), 256, 0, stream>>>(h1gh, h1gl, g2th, g2tl, h2g, BT, CC, 128);

  k_gate<<<4096, 256, 0, stream>>>(h2w, h2a, h2v, w0, a0, v0, kkc, kac,
                                   kb, vb, vfirst, rb, rk, db, awb, bwb, bonb);
  k_scan<<<1024, 64, 0, stream>>>(rb, kb, db, awb, bwb, vb, st0, ybuf);
  k_post<<<4096, 256, 0, stream>>>(ybuf, vb, h2g, bonb, gnw, gnb, xoh, xol);
  k_gemm_bt3<<<dim3(32, 16), 256, 0, stream>>>(xoh, xol, Woh, Wol, out, BT, CC, CC);
}

// Round 15
// 748.233 us; speedup vs baseline: 1.4563x; 1.0304x over previous
//
#include <hip/hip_runtime.h>
#include <hip/hip_bf16.h>

// Problem constants (RWKV-7 Tmix: B=2, T=1024, C=2048, H=32, N=64)
#define BB 2
#define TT 1024
#define CC 2048
#define HH 32
#define BT 2048          // BB*TT tokens
#define GN_EPS 6.4e-4f   // 1e-5 * 8^2

typedef __attribute__((ext_vector_type(8))) __bf16 bf16x8;
typedef __attribute__((ext_vector_type(4))) float f32x4;

__device__ __forceinline__ float sigf(float x) { return 1.0f / (1.0f + expf(-x)); }

__device__ __forceinline__ void split_bf16(float x, __hip_bfloat16& hi, __hip_bfloat16& lo) {
  __hip_bfloat16 h = __float2bfloat16(x);
  hi = h;
  lo = __float2bfloat16(x - __bfloat162float(h));
}

__device__ __forceinline__ unsigned short bfb(float x) {
  union { __hip_bfloat16 h; unsigned short u; } cv;
  cv.h = __float2bfloat16(x);
  return cv.u;
}
__device__ __forceinline__ void splitu(float x, unsigned short& hi, unsigned short& lo) {
  union { __hip_bfloat16 h; unsigned short u; } cv;
  cv.h = __float2bfloat16(x);
  hi = cv.u;
  lo = bfb(x - __bfloat162float(cv.h));
}

// Sum over each aligned 16-lane group, pure DPP (no LDS pipe on the chain).
__device__ __forceinline__ float red16(float x) {
  x += __int_as_float(__builtin_amdgcn_update_dpp(
      0, __float_as_int(x), 0xB1 /*quad_perm [1,0,3,2]*/, 0xF, 0xF, true));
  x += __int_as_float(__builtin_amdgcn_update_dpp(
      0, __float_as_int(x), 0x4E /*quad_perm [2,3,0,1]*/, 0xF, 0xF, true));
  x += __int_as_float(__builtin_amdgcn_update_dpp(
      0, __float_as_int(x), 0x141 /*row_half_mirror*/, 0xF, 0xF, true));
  x += __int_as_float(__builtin_amdgcn_update_dpp(
      0, __float_as_int(x), 0x140 /*row_mirror*/, 0xF, 0xF, true));
  return x;
}

// ---------------------------------------------------------------------------
// K1: token shift + six lerped projections — 4-wide vectorized (r14 winner).
// ---------------------------------------------------------------------------
__global__ __launch_bounds__(256) void k_prepx(
    const float* __restrict__ hid, const float* __restrict__ shift,
    const float* __restrict__ xrc, const float* __restrict__ xwc,
    const float* __restrict__ xkc, const float* __restrict__ xvc,
    const float* __restrict__ xac, const float* __restrict__ xgc,
    __hip_bfloat16* __restrict__ xrh, __hip_bfloat16* __restrict__ xrl,
    __hip_bfloat16* __restrict__ xw,
    __hip_bfloat16* __restrict__ xkh, __hip_bfloat16* __restrict__ xkl,
    __hip_bfloat16* __restrict__ xvh, __hip_bfloat16* __restrict__ xvl,
    __hip_bfloat16* __restrict__ xa, __hip_bfloat16* __restrict__ xg) {
  int i4 = (blockIdx.x * 256 + threadIdx.x) * 4;   // < BT*CC
  int c  = i4 & (CC - 1);
  int bt = i4 >> 11;
  int t  = bt & (TT - 1);
  int b  = bt >> 10;
  float4 hc = *(const float4*)&hid[i4];
  float4 hp = (t == 0) ? *(const float4*)&shift[b * CC + c]
                       : *(const float4*)&hid[i4 - CC];
  float xxv[4] = {hp.x - hc.x, hp.y - hc.y, hp.z - hc.z, hp.w - hc.w};
  float hcv[4] = {hc.x, hc.y, hc.z, hc.w};
  float4 crv = *(const float4*)&xrc[c];
  float4 cwv = *(const float4*)&xwc[c];
  float4 ckv = *(const float4*)&xkc[c];
  float4 cvv = *(const float4*)&xvc[c];
  float4 cav = *(const float4*)&xac[c];
  float4 cgv = *(const float4*)&xgc[c];
  float cr[4] = {crv.x, crv.y, crv.z, crv.w};
  float cw[4] = {cwv.x, cwv.y, cwv.z, cwv.w};
  float ck[4] = {ckv.x, ckv.y, ckv.z, ckv.w};
  float cv[4] = {cvv.x, cvv.y, cvv.z, cvv.w};
  float ca[4] = {cav.x, cav.y, cav.z, cav.w};
  float cg[4] = {cgv.x, cgv.y, cgv.z, cgv.w};
  ushort4 rh, rl, kh, kl, vh, vl, wv, av, gv;
  unsigned short* prh = (unsigned short*)&rh;
  unsigned short* prl = (unsigned short*)&rl;
  unsigned short* pkh = (unsigned short*)&kh;
  unsigned short* pkl = (unsigned short*)&kl;
  unsigned short* pvh = (unsigned short*)&vh;
  unsigned short* pvl = (unsigned short*)&vl;
  unsigned short* pw  = (unsigned short*)&wv;
  unsigned short* pa  = (unsigned short*)&av;
  unsigned short* pg  = (unsigned short*)&gv;
#pragma unroll
  for (int j = 0; j < 4; ++j) {
    splitu(fmaf(xxv[j], cr[j], hcv[j]), prh[j], prl[j]);
    splitu(fmaf(xxv[j], ck[j], hcv[j]), pkh[j], pkl[j]);
    splitu(fmaf(xxv[j], cv[j], hcv[j]), pvh[j], pvl[j]);
    pw[j] = bfb(fmaf(xxv[j], cw[j], hcv[j]));
    pa[j] = bfb(fmaf(xxv[j], ca[j], hcv[j]));
    pg[j] = bfb(fmaf(xxv[j], cg[j], hcv[j]));
  }
  *(ushort4*)&xrh[i4] = rh; *(ushort4*)&xrl[i4] = rl;
  *(ushort4*)&xkh[i4] = kh; *(ushort4*)&xkl[i4] = kl;
  *(ushort4*)&xvh[i4] = vh; *(ushort4*)&xvl[i4] = vl;
  *(ushort4*)&xw[i4]  = wv; *(ushort4*)&xa[i4]  = av;
  *(ushort4*)&xg[i4]  = gv;
}

// ---------------------------------------------------------------------------
// K2: f32 -> hi+lo bf16 split for all four big weights, 4-wide vectorized.
// ---------------------------------------------------------------------------
__global__ __launch_bounds__(256) void k_cvt2x4(
    const float* __restrict__ i0, const float* __restrict__ i1,
    const float* __restrict__ i2, const float* __restrict__ i3,
    __hip_bfloat16* __restrict__ h0, __hip_bfloat16* __restrict__ l0,
    __hip_bfloat16* __restrict__ h1, __hip_bfloat16* __restrict__ l1,
    __hip_bfloat16* __restrict__ h2, __hip_bfloat16* __restrict__ l2,
    __hip_bfloat16* __restrict__ h3, __hip_bfloat16* __restrict__ l3) {
  int i4 = (blockIdx.x * 256 + threadIdx.x) * 4;
  int w = blockIdx.y;
  const float* in = (w == 0) ? i0 : (w == 1) ? i1 : (w == 2) ? i2 : i3;
  __hip_bfloat16* oh = (w == 0) ? h0 : (w == 1) ? h1 : (w == 2) ? h2 : h3;
  __hip_bfloat16* ol = (w == 0) ? l0 : (w == 1) ? l1 : (w == 2) ? l2 : l3;
  float4 v = *(const float4*)&in[i4];
  float vv[4] = {v.x, v.y, v.z, v.w};
  ushort4 hv, lv;
  unsigned short* ph = (unsigned short*)&hv;
  unsigned short* pl = (unsigned short*)&lv;
#pragma unroll
  for (int j = 0; j < 4; ++j) splitu(vv[j], ph[j], pl[j]);
  *(ushort4*)&oh[i4] = hv;
  *(ushort4*)&ol[i4] = lv;
}

// ---------------------------------------------------------------------------
// K3: fused transpose-convert of the 4 stage-1 "up" weights (one dispatch).
// ---------------------------------------------------------------------------
__global__ __launch_bounds__(256) void k_tr4(
    const float* __restrict__ w1, const float* __restrict__ a1,
    const float* __restrict__ v1, const float* __restrict__ g1,
    __hip_bfloat16* __restrict__ w1t, __hip_bfloat16* __restrict__ a1t,
    __hip_bfloat16* __restrict__ v1t, __hip_bfloat16* __restrict__ g1t) {
  int i = blockIdx.x * 256 + threadIdx.x;   // < 128*2048 max
  int y = blockIdx.y;
  const float* in; __hip_bfloat16* out; int N0, NP;
  if (y == 0)      { in = w1; out = w1t; N0 = 64;  NP = 64;  }
  else if (y == 1) { in = a1; out = a1t; N0 = 64;  NP = 64;  }
  else if (y == 2) { in = v1; out = v1t; N0 = 32;  NP = 64;  }
  else             { in = g1; out = g1t; N0 = 128; NP = 128; }
  if (i >= NP * 2048) return;
  int n = i >> 11;
  int k = i & 2047;
  float v = (n < N0) ? in[k * N0 + n] : 0.0f;
  out[i] = __float2bfloat16(v);
}

// ---------------------------------------------------------------------------
// K3b: fused transpose+split of the 4 stage-2 "down" weights (one dispatch).
// ---------------------------------------------------------------------------
__global__ __launch_bounds__(256) void k_trs4(
    const float* __restrict__ w2, const float* __restrict__ a2,
    const float* __restrict__ v2, const float* __restrict__ g2,
    __hip_bfloat16* __restrict__ w2th, __hip_bfloat16* __restrict__ w2tl,
    __hip_bfloat16* __restrict__ a2th, __hip_bfloat16* __restrict__ a2tl,
    __hip_bfloat16* __restrict__ v2th, __hip_bfloat16* __restrict__ v2tl,
    __hip_bfloat16* __restrict__ g2th, __hip_bfloat16* __restrict__ g2tl) {
  int i = blockIdx.x * 256 + threadIdx.x;   // < CC*128 max
  int y = blockIdx.y;
  const float* in; __hip_bfloat16 *oh, *ol; int N0, lgK;
  if (y == 0)      { in = w2; oh = w2th; ol = w2tl; N0 = 64;  lgK = 6; }
  else if (y == 1) { in = a2; oh = a2th; ol = a2tl; N0 = 64;  lgK = 6; }
  else if (y == 2) { in = v2; oh = v2th; ol = v2tl; N0 = 32;  lgK = 6; }
  else             { in = g2; oh = g2th; ol = g2tl; N0 = 128; lgK = 7; }
  if (i >= (CC << lgK)) return;
  int n = i >> lgK;
  int k = i & ((1 << lgK) - 1);
  float v = (k < N0) ? in[k * CC + n] : 0.0f;
  split_bf16(v, oh[i], ol[i]);
}

// ---------------------------------------------------------------------------
// K4: fused stage-1 LoRA GEMM, LDS-staged (r11 winner, unchanged).
// ---------------------------------------------------------------------------
__global__ __launch_bounds__(256, 4) void k_lora1(
    const __hip_bfloat16* __restrict__ xw, const __hip_bfloat16* __restrict__ xa,
    const __hip_bfloat16* __restrict__ xv, const __hip_bfloat16* __restrict__ xg,
    const __hip_bfloat16* __restrict__ w1t, const __hip_bfloat16* __restrict__ a1t,
    const __hip_bfloat16* __restrict__ v1t, const __hip_bfloat16* __restrict__ g1t,
    float* __restrict__ h1w, float* __restrict__ h1a,
    float* __restrict__ h1v, float* __restrict__ h1g) {
  __shared__ __align__(16) __hip_bfloat16 sA[2][64 * 32], sB[2][64 * 32];
  int tid  = threadIdx.x;
  int lane = tid & 63;
  int wv   = tid >> 6;
  int l15  = lane & 15;
  int quad = lane >> 4;
  int m0 = blockIdx.x * 64;
  int bly = blockIdx.y;

  const __hip_bfloat16* Ab;
  const __hip_bfloat16* Bb;
  float* Ob;
  int os, cb;
  if (bly == 0)      { Ab = xw; Bb = w1t;            Ob = h1w; os = 64;  cb = 0;  }
  else if (bly == 1) { Ab = xa; Bb = a1t;            Ob = h1a; os = 64;  cb = 0;  }
  else if (bly == 2) { Ab = xv; Bb = v1t;            Ob = h1v; os = 64;  cb = 0;  }
  else if (bly == 3) { Ab = xg; Bb = g1t;            Ob = h1g; os = 128; cb = 0;  }
  else               { Ab = xg; Bb = g1t + 64 * CC;  Ob = h1g; os = 128; cb = 64; }

  int srow = wv * 16 + (lane >> 2);
  int scol = (lane & 3) * 8;
  const __hip_bfloat16* gA = Ab + (size_t)(m0 + srow) * CC + scol;
  const __hip_bfloat16* gB = Bb + (size_t)srow * CC + scol;

  f32x4 z = {0.f, 0.f, 0.f, 0.f};
  f32x4 acc0 = z, acc1 = z, acc2 = z, acc3 = z;

  int aoff = (wv * 16 + l15) * 32 + quad * 8;
  int boff = l15 * 32 + quad * 8;

#define STAGE1(BUF, KO)                                                      \
  { unsigned db_ = (unsigned)(BUF) * 4096u + (unsigned)wv * 1024u;           \
    __builtin_amdgcn_global_load_lds(                                        \
        (const __attribute__((address_space(1))) void*)(gA + (KO)),          \
        (__attribute__((address_space(3))) void*)((char*)sA + db_), 16, 0, 0);\
    __builtin_amdgcn_global_load_lds(                                        \
        (const __attribute__((address_space(1))) void*)(gB + (KO)),          \
        (__attribute__((address_space(3))) void*)((char*)sB + db_), 16, 0, 0);}

  STAGE1(0, 0)
  __syncthreads();

  for (int k0 = 0; k0 < CC; k0 += 32) {
    int cur = (k0 >> 5) & 1;
    if (k0 + 32 < CC) STAGE1(cur ^ 1, k0 + 32)

    const __hip_bfloat16* pA_ = &sA[cur][0];
    const __hip_bfloat16* pB_ = &sB[cur][0];
    bf16x8 av = *(const bf16x8*)(pA_ + aoff);
    bf16x8 b0 = *(const bf16x8*)(pB_ + boff);
    bf16x8 b1 = *(const bf16x8*)(pB_ + boff + 16 * 32);
    bf16x8 b2 = *(const bf16x8*)(pB_ + boff + 32 * 32);
    bf16x8 b3 = *(const bf16x8*)(pB_ + boff + 48 * 32);

    acc0 = __builtin_amdgcn_mfma_f32_16x16x32_bf16(av, b0, acc0, 0, 0, 0);
    acc1 = __builtin_amdgcn_mfma_f32_16x16x32_bf16(av, b1, acc1, 0, 0, 0);
    acc2 = __builtin_amdgcn_mfma_f32_16x16x32_bf16(av, b2, acc2, 0, 0, 0);
    acc3 = __builtin_amdgcn_mfma_f32_16x16x32_bf16(av, b3, acc3, 0, 0, 0);

    __syncthreads();
  }
#undef STAGE1

  int row0 = m0 + wv * 16 + quad * 4;
  int colb = cb + l15;
#pragma unroll
  for (int r = 0; r < 4; ++r) {
    Ob[(size_t)(row0 + r) * os + colb +  0] = acc0[r];
    Ob[(size_t)(row0 + r) * os + colb + 16] = acc1[r];
    Ob[(size_t)(row0 + r) * os + colb + 32] = acc2[r];
    Ob[(size_t)(row0 + r) * os + colb + 48] = acc3[r];
  }
}

// ---------------------------------------------------------------------------
// K4b body: split-precision GEMM, 64x128 tile, 2-phase LDS staging (r12
// winner) — shared by the standalone, big3-fused, and stage2-fused kernels.
// ---------------------------------------------------------------------------
__device__ __forceinline__ void gemm_bt3_body(
    const __hip_bfloat16* __restrict__ Ah, const __hip_bfloat16* __restrict__ Al,
    const __hip_bfloat16* __restrict__ Bh, const __hip_bfloat16* __restrict__ Bl,
    float* __restrict__ Cm, int Nn, int K) {
  __shared__ __align__(16) __hip_bfloat16 sAh[2][64 * 32],  sAl[2][64 * 32];
  __shared__ __align__(16) __hip_bfloat16 sBh[2][128 * 32], sBl[2][128 * 32];
  int tid  = threadIdx.x;
  int lane = tid & 63;
  int wv   = tid >> 6;
  int l15  = lane & 15;
  int quad = lane >> 4;
  int m0 = blockIdx.x * 64;
  int n0 = blockIdx.y * 128;

  int srowA = wv * 16 + (lane >> 2);
  int srowB = wv * 32 + (lane >> 2);
  int scol  = (lane & 3) * 8;
  const __hip_bfloat16* gAh  = Ah + (size_t)(m0 + srowA) * K + scol;
  const __hip_bfloat16* gAl  = Al + (size_t)(m0 + srowA) * K + scol;
  const __hip_bfloat16* gBh0 = Bh + (size_t)(n0 + srowB) * K + scol;
  const __hip_bfloat16* gBh1 = Bh + (size_t)(n0 + srowB + 16) * K + scol;
  const __hip_bfloat16* gBl0 = Bl + (size_t)(n0 + srowB) * K + scol;
  const __hip_bfloat16* gBl1 = Bl + (size_t)(n0 + srowB + 16) * K + scol;

  f32x4 z = {0.f, 0.f, 0.f, 0.f};
  f32x4 acc[8];
#pragma unroll
  for (int j = 0; j < 8; ++j) acc[j] = z;

  int aoff = (wv * 16 + l15) * 32 + quad * 8;
  int boff = l15 * 32 + quad * 8;

#define STAGE(BUF, KO)                                                       \
  { unsigned dA_ = (unsigned)(BUF) * 4096u + (unsigned)wv * 1024u;           \
    unsigned dB_ = (unsigned)(BUF) * 8192u + (unsigned)wv * 2048u;           \
    __builtin_amdgcn_global_load_lds(                                        \
        (const __attribute__((address_space(1))) void*)(gAh + (KO)),         \
        (__attribute__((address_space(3))) void*)((char*)sAh + dA_), 16, 0, 0);\
    __builtin_amdgcn_global_load_lds(                                        \
        (const __attribute__((address_space(1))) void*)(gAl + (KO)),         \
        (__attribute__((address_space(3))) void*)((char*)sAl + dA_), 16, 0, 0);\
    __builtin_amdgcn_global_load_lds(                                        \
        (const __attribute__((address_space(1))) void*)(gBh0 + (KO)),        \
        (__attribute__((address_space(3))) void*)((char*)sBh + dB_), 16, 0, 0);\
    __builtin_amdgcn_global_load_lds(                                        \
        (const __attribute__((address_space(1))) void*)(gBh1 + (KO)),        \
        (__attribute__((address_space(3))) void*)((char*)sBh + dB_ + 1024u), 16, 0, 0);\
    __builtin_amdgcn_global_load_lds(                                        \
        (const __attribute__((address_space(1))) void*)(gBl0 + (KO)),        \
        (__attribute__((address_space(3))) void*)((char*)sBl + dB_), 16, 0, 0);\
    __builtin_amdgcn_global_load_lds(                                        \
        (const __attribute__((address_space(1))) void*)(gBl1 + (KO)),        \
        (__attribute__((address_space(3))) void*)((char*)sBl + dB_ + 1024u), 16, 0, 0);}

  STAGE(0, 0)
  __syncthreads();   // buf0 staged (implicit vmcnt(0) drain before barrier)

  for (int k0 = 0; k0 < K; k0 += 32) {
    int cur = (k0 >> 5) & 1;
    if (k0 + 32 < K) STAGE(cur ^ 1, k0 + 32)   // next tile in flight NOW

    const __hip_bfloat16* pA_h = &sAh[cur][0];
    const __hip_bfloat16* pA_l = &sAl[cur][0];
    const __hip_bfloat16* pB_h = &sBh[cur][0];
    const __hip_bfloat16* pB_l = &sBl[cur][0];
    bf16x8 ah = *(const bf16x8*)(pA_h + aoff);
    bf16x8 al = *(const bf16x8*)(pA_l + aoff);
#pragma unroll
    for (int j = 0; j < 8; ++j) {
      bf16x8 bh = *(const bf16x8*)(pB_h + boff + j * 16 * 32);
      bf16x8 bl = *(const bf16x8*)(pB_l + boff + j * 16 * 32);
      acc[j] = __builtin_amdgcn_mfma_f32_16x16x32_bf16(ah, bh, acc[j], 0, 0, 0);
      acc[j] = __builtin_amdgcn_mfma_f32_16x16x32_bf16(ah, bl, acc[j], 0, 0, 0);
      acc[j] = __builtin_amdgcn_mfma_f32_16x16x32_bf16(al, bh, acc[j], 0, 0, 0);
    }

    __syncthreads();   // ONE barrier: next buf staged + this buf reads done
  }
#undef STAGE

  int row0 = m0 + wv * 16 + quad * 4;
#pragma unroll
  for (int j = 0; j < 8; ++j) {
    int colb = n0 + j * 16 + l15;
#pragma unroll
    for (int r = 0; r < 4; ++r)
      Cm[(size_t)(row0 + r) * Nn + colb] = acc[j][r];
  }
}

// standalone (Wo output GEMM)
__global__ __launch_bounds__(256, 3) void k_gemm_bt3(
    const __hip_bfloat16* __restrict__ Ah, const __hip_bfloat16* __restrict__ Al,
    const __hip_bfloat16* __restrict__ Bh, const __hip_bfloat16* __restrict__ Bl,
    float* __restrict__ Cm, int M, int Nn, int K) {
  gemm_bt3_body(Ah, Al, Bh, Bl, Cm, Nn, K);
}

// ROUND-22: 3 big input GEMMs (r/k/v) fused into one dispatch, grid z = slice.
__global__ __launch_bounds__(256, 3) void k_gemm_big3(
    const __hip_bfloat16* __restrict__ Ah0, const __hip_bfloat16* __restrict__ Al0,
    const __hip_bfloat16* __restrict__ Bh0, const __hip_bfloat16* __restrict__ Bl0,
    float* __restrict__ C0,
    const __hip_bfloat16* __restrict__ Ah1, const __hip_bfloat16* __restrict__ Al1,
    const __hip_bfloat16* __restrict__ Bh1, const __hip_bfloat16* __restrict__ Bl1,
    float* __restrict__ C1,
    const __hip_bfloat16* __restrict__ Ah2, const __hip_bfloat16* __restrict__ Al2,
    const __hip_bfloat16* __restrict__ Bh2, const __hip_bfloat16* __restrict__ Bl2,
    float* __restrict__ C2) {
  int zz = blockIdx.z;
  const __hip_bfloat16* Ah = (zz == 0) ? Ah0 : (zz == 1) ? Ah1 : Ah2;
  const __hip_bfloat16* Al = (zz == 0) ? Al0 : (zz == 1) ? Al1 : Al2;
  const __hip_bfloat16* Bh = (zz == 0) ? Bh0 : (zz == 1) ? Bh1 : Bh2;
  const __hip_bfloat16* Bl = (zz == 0) ? Bl0 : (zz == 1) ? Bl1 : Bl2;
  float* Cm = (zz == 0) ? C0 : (zz == 1) ? C1 : C2;
  gemm_bt3_body(Ah, Al, Bh, Bl, Cm, CC, CC);
}

// ROUND-22: 4 stage-2 GEMMs fused into one dispatch, grid z = slice (K table).
__global__ __launch_bounds__(256, 3) void k_gemm_s2x4(
    const __hip_bfloat16* __restrict__ h1wh, const __hip_bfloat16* __restrict__ h1wl,
    const __hip_bfloat16* __restrict__ h1ah, const __hip_bfloat16* __restrict__ h1al,
    const __hip_bfloat16* __restrict__ h1vh, const __hip_bfloat16* __restrict__ h1vl,
    const __hip_bfloat16* __restrict__ h1gh, const __hip_bfloat16* __restrict__ h1gl,
    const __hip_bfloat16* __restrict__ w2th, const __hip_bfloat16* __restrict__ w2tl,
    const __hip_bfloat16* __restrict__ a2th, const __hip_bfloat16* __restrict__ a2tl,
    const __hip_bfloat16* __restrict__ v2th, const __hip_bfloat16* __restrict__ v2tl,
    const __hip_bfloat16* __restrict__ g2th, const __hip_bfloat16* __restrict__ g2tl,
    float* __restrict__ h2w, float* __restrict__ h2a,
    float* __restrict__ h2v, float* __restrict__ h2g) {
  int zz = blockIdx.z;
  const __hip_bfloat16* Ah = (zz == 0) ? h1wh : (zz == 1) ? h1ah : (zz == 2) ? h1vh : h1gh;
  const __hip_bfloat16* Al = (zz == 0) ? h1wl : (zz == 1) ? h1al : (zz == 2) ? h1vl : h1gl;
  const __hip_bfloat16* Bh = (zz == 0) ? w2th : (zz == 1) ? a2th : (zz == 2) ? v2th : g2th;
  const __hip_bfloat16* Bl = (zz == 0) ? w2tl : (zz == 1) ? a2tl : (zz == 2) ? v2tl : g2tl;
  float* Cm = (zz == 0) ? h2w : (zz == 1) ? h2a : (zz == 2) ? h2v : h2g;
  int K = (zz == 3) ? 128 : 64;
  gemm_bt3_body(Ah, Al, Bh, Bl, Cm, CC, K);
}

// ---------------------------------------------------------------------------
// K5: activations + hi/lo split of stage-1 LoRA outputs — 4-wide vectorized.
// ---------------------------------------------------------------------------
__global__ __launch_bounds__(256) void k_act2(
    const float* __restrict__ h1w, const float* __restrict__ h1a,
    const float* __restrict__ h1v, const float* __restrict__ h1g,
    __hip_bfloat16* __restrict__ wh, __hip_bfloat16* __restrict__ wl,
    __hip_bfloat16* __restrict__ ah, __hip_bfloat16* __restrict__ al,
    __hip_bfloat16* __restrict__ vh, __hip_bfloat16* __restrict__ vl,
    __hip_bfloat16* __restrict__ gh, __hip_bfloat16* __restrict__ gl) {
  int i4 = (blockIdx.x * 256 + threadIdx.x) * 4;   // over BT*128
  if (i4 < BT * 64) {
    float4 w = *(const float4*)&h1w[i4];
    float4 a = *(const float4*)&h1a[i4];
    float4 v = *(const float4*)&h1v[i4];
    float wvv[4] = {w.x, w.y, w.z, w.w};
    float avv[4] = {a.x, a.y, a.z, a.w};
    float vvv[4] = {v.x, v.y, v.z, v.w};
    ushort4 whv, wlv, ahv, alv, vhv, vlv;
    unsigned short* p0 = (unsigned short*)&whv;
    unsigned short* p1 = (unsigned short*)&wlv;
    unsigned short* p2 = (unsigned short*)&ahv;
    unsigned short* p3 = (unsigned short*)&alv;
    unsigned short* p4 = (unsigned short*)&vhv;
    unsigned short* p5 = (unsigned short*)&vlv;
#pragma unroll
    for (int j = 0; j < 4; ++j) {
      splitu(tanhf(wvv[j]), p0[j], p1[j]);
      splitu(avv[j], p2[j], p3[j]);
      splitu(vvv[j], p4[j], p5[j]);
    }
    *(ushort4*)&wh[i4] = whv; *(ushort4*)&wl[i4] = wlv;
    *(ushort4*)&ah[i4] = ahv; *(ushort4*)&al[i4] = alv;
    *(ushort4*)&vh[i4] = vhv; *(ushort4*)&vl[i4] = vlv;
  }
  float4 g = *(const float4*)&h1g[i4];
  float gvv[4] = {g.x, g.y, g.z, g.w};
  ushort4 ghv, glv;
  unsigned short* p6 = (unsigned short*)&ghv;
  unsigned short* p7 = (unsigned short*)&glv;
#pragma unroll
  for (int j = 0; j < 4; ++j) splitu(sigf(gvv[j]), p6[j], p7[j]);
  *(ushort4*)&gh[i4] = ghv; *(ushort4*)&gl[i4] = glv;
}

// ---------------------------------------------------------------------------
// K6: gates + kk-normalize + per-head bonus — 4-wide, red16 reductions.
// ---------------------------------------------------------------------------
__global__ __launch_bounds__(256) void k_gate(
    const float* __restrict__ h2w, const float* __restrict__ h2a,
    const float* __restrict__ h2v,
    const float* __restrict__ w0, const float* __restrict__ a0,
    const float* __restrict__ v0, const float* __restrict__ kkc,
    const float* __restrict__ kac, float* __restrict__ kbuf,
    float* __restrict__ vbuf, const float* __restrict__ vfirst,
    const float* __restrict__ rbuf, const float* __restrict__ rk,
    float* __restrict__ dec, float* __restrict__ aw,
    float* __restrict__ bw, float* __restrict__ bonb) {
  int i4 = (blockIdx.x * 256 + threadIdx.x) * 4;   // < BT*CC
  int c = i4 & (CC - 1);
  float4 kv4 = *(const float4*)&kbuf[i4];
  float4 vv4 = *(const float4*)&vbuf[i4];
  float4 vf4 = *(const float4*)&vfirst[i4];
  float4 hw4 = *(const float4*)&h2w[i4];
  float4 ha4 = *(const float4*)&h2a[i4];
  float4 hv4 = *(const float4*)&h2v[i4];
  float4 w04 = *(const float4*)&w0[c];
  float4 a04 = *(const float4*)&a0[c];
  float4 v04 = *(const float4*)&v0[c];
  float4 kk4 = *(const float4*)&kkc[c];
  float4 ka4 = *(const float4*)&kac[c];
  float4 rk4 = *(const float4*)&rk[c];
  float4 rb4 = *(const float4*)&rbuf[i4];
  float kv[4] = {kv4.x, kv4.y, kv4.z, kv4.w};
  float vv[4] = {vv4.x, vv4.y, vv4.z, vv4.w};
  float vf[4] = {vf4.x, vf4.y, vf4.z, vf4.w};
  float hw[4] = {hw4.x, hw4.y, hw4.z, hw4.w};
  float ha[4] = {ha4.x, ha4.y, ha4.z, ha4.w};
  float hv[4] = {hv4.x, hv4.y, hv4.z, hv4.w};
  float w0v[4] = {w04.x, w04.y, w04.z, w04.w};
  float a0v[4] = {a04.x, a04.y, a04.z, a04.w};
  float v0v[4] = {v04.x, v04.y, v04.z, v04.w};
  float kkv[4] = {kk4.x, kk4.y, kk4.z, kk4.w};
  float kav[4] = {ka4.x, ka4.y, ka4.z, ka4.w};
  float rkv[4] = {rk4.x, rk4.y, rk4.z, rk4.w};
  float rbv[4] = {rb4.x, rb4.y, rb4.z, rb4.w};
  float d_[4], as[4], vm[4], kfv[4], kku[4];
  float sl = 0.f, bl = 0.f;
#pragma unroll
  for (int j = 0; j < 4; ++j) {
    d_[j] = 0.60653065971f * sigf(w0v[j] + hw[j]);   // sigmoid * e^-0.5
    as[j] = sigf(a0v[j] + ha[j]);
    float vs = sigf(v0v[j] + hv[j]);
    vm[j] = vv[j] + (vf[j] - vv[j]) * vs;
    kfv[j] = kv[j] * (1.0f + kav[j] * (as[j] - 1.0f));
    kku[j] = kv[j] * kkv[j];
    sl = fmaf(kku[j], kku[j], sl);
    bl = fmaf(rbv[j] * kfv[j], rkv[j], bl);
  }
  float s = red16(sl);                 // per-head L2 (16 lanes x 4 cols)
  float nrm = fmaxf(sqrtf(s), 1e-12f);
  float bon = red16(bl);
  if ((threadIdx.x & 15) == 0) bonb[(i4 >> 11) * HH + (c >> 6)] = bon;
  float4 o0, o1, o2, o3, o4;
  float* q0 = (float*)&o0; float* q1 = (float*)&o1; float* q2 = (float*)&o2;
  float* q3 = (float*)&o3; float* q4 = (float*)&o4;
#pragma unroll
  for (int j = 0; j < 4; ++j) {
    float kkn = kku[j] / nrm;
    q0[j] = d_[j];
    q1[j] = -kkn;
    q2[j] = kkn * as[j];
    q3[j] = kfv[j];
    q4[j] = vm[j];
  }
  *(float4*)&dec[i4] = o0;
  *(float4*)&aw[i4]  = o1;
  *(float4*)&bw[i4]  = o2;
  *(float4*)&kbuf[i4] = o3;
  *(float4*)&vbuf[i4] = o4;
}

// ---------------------------------------------------------------------------
// K7: WKV7 scan — r13 counted-lgkm LDS-DMA-ring version (~180 µs), unchanged.
// ---------------------------------------------------------------------------
__global__ __launch_bounds__(64, 1) void k_scan(
    const float* __restrict__ rbuf, const float* __restrict__ kf,
    const float* __restrict__ dec, const float* __restrict__ aw,
    const float* __restrict__ bw, const float* __restrict__ vbuf,
    const float* __restrict__ st0, float* __restrict__ ybuf) {
  __shared__ __align__(16) char ldsbuf[16 * 2048];
  int blk = blockIdx.x;                     // 0..1023
  int xcd = blk & 7;
  int q   = blk >> 3;                       // 0..127
  int bh  = xcd * 8 + (q & 7);              // 16 rg-waves of a head share blk%8
  int rg  = q >> 3;                         // 0..15
  int b = bh >> 5, h = bh & 31;
  int lane = threadIdx.x;
  int l15  = lane & 15;
  int row  = rg * 4 + (lane >> 4);
  size_t tokbase = (size_t)b * TT * CC + h * 64;

  f32x4 S = *(const f32x4*)(st0 + ((size_t)bh * 64 + row) * 64 + l15 * 4);
  bool writer = (l15 == 0);
  float* yout = ybuf + tokbase + row;

  const float* g1 = (lane < 16 ? rbuf : lane < 32 ? kf : lane < 48 ? dec : aw)
                  + tokbase + l15 * 4;
  const float* g2 = (lane < 16) ? (bw + tokbase + l15 * 4)
                                : (vbuf + tokbase + rg * 4);

  unsigned lbase = (unsigned)(uintptr_t)(__attribute__((address_space(3))) char*)ldsbuf;
  unsigned larr = lbase + (unsigned)(l15 * 16);
  unsigned lvad = lbase + 1280u + (unsigned)((lane >> 4) * 4);

#define DMAQ(T)                                                              \
  { char* sb_ = ldsbuf + (((T) & 15) << 11);                                 \
    __builtin_amdgcn_global_load_lds(                                        \
        (const __attribute__((address_space(1))) void*)g1,                   \
        (__attribute__((address_space(3))) void*)sb_, 16, 0, 0);             \
    __builtin_amdgcn_global_load_lds(                                        \
        (const __attribute__((address_space(1))) void*)g2,                   \
        (__attribute__((address_space(3))) void*)(sb_ + 1024), 16, 0, 0);    \
    g1 += CC; g2 += CC; }

#define DSRD(RR, RK, RD, RA, RB, RV, T)                                      \
  { unsigned a_ = larr + (unsigned)(((T) & 15) << 11);                       \
    unsigned v_ = lvad + (unsigned)(((T) & 15) << 11);                       \
    asm volatile("ds_read_b128 %0, %1"             : "=v"(RR) : "v"(a_));    \
    asm volatile("ds_read_b128 %0, %1 offset:256"  : "=v"(RK) : "v"(a_));    \
    asm volatile("ds_read_b128 %0, %1 offset:512"  : "=v"(RD) : "v"(a_));    \
    asm volatile("ds_read_b128 %0, %1 offset:768"  : "=v"(RA) : "v"(a_));    \
    asm volatile("ds_read_b128 %0, %1 offset:1024" : "=v"(RB) : "v"(a_));    \
    asm volatile("ds_read_b32 %0, %1"              : "=v"(RV) : "v"(v_)); }

#define WVM(N) { asm volatile("s_waitcnt vmcnt(" #N ")" ::: "memory");       \
                 __builtin_amdgcn_sched_barrier(0); }
#define WLG    { asm volatile("s_waitcnt lgkmcnt(0)" ::: "memory");          \
                 __builtin_amdgcn_sched_barrier(0); }
#define WLG6   { asm volatile("s_waitcnt lgkmcnt(6)" ::: "memory");          \
                 __builtin_amdgcn_sched_barrier(0); }

#define STEPR(RR, RK, RD, RA, RB, RV, T)                                     \
  { float sa = fmaf(S.w, RA.w, fmaf(S.z, RA.z,                               \
               fmaf(S.y, RA.y, S.x * RA.x)));                                \
    sa = red16(sa);                                                          \
    float vv = RV;                                                           \
    S.x = fmaf(S.x, RD.x, fmaf(sa, RB.x, vv * RK.x));                        \
    S.y = fmaf(S.y, RD.y, fmaf(sa, RB.y, vv * RK.y));                        \
    S.z = fmaf(S.z, RD.z, fmaf(sa, RB.z, vv * RK.z));                        \
    S.w = fmaf(S.w, RD.w, fmaf(sa, RB.w, vv * RK.w));                        \
    float y = fmaf(S.w, RR.w, fmaf(S.z, RR.z,                                \
              fmaf(S.y, RR.y, S.x * RR.x)));                                 \
    y = red16(y);                                                            \
    if (writer) yout[(size_t)(T) * CC] = y; }

  for (int tt = 0; tt < 16; ++tt) DMAQ(tt)

  f32x4 Ar, Ak, Ad, Aa, Ab; float Av;
  f32x4 Br, Bk, Bd, Ba, Bb; float Bv;

  WVM(24)
  DSRD(Ar, Ak, Ad, Aa, Ab, Av, 0)
  WLG
  DSRD(Br, Bk, Bd, Ba, Bb, Bv, 1)

  int t = 0;
  for (; t < TT - 16; t += 2) {
    DMAQ(t + 16)
    STEPR(Ar, Ak, Ad, Aa, Ab, Av, t)
    DSRD(Ar, Ak, Ad, Aa, Ab, Av, t + 2)
    WLG6
    DMAQ(t + 17)
    STEPR(Br, Bk, Bd, Ba, Bb, Bv, t + 1)
    DSRD(Br, Bk, Bd, Ba, Bb, Bv, t + 3)
    WLG6
  }
  for (; t < TT - 2; t += 2) {
    STEPR(Ar, Ak, Ad, Aa, Ab, Av, t)
    DSRD(Ar, Ak, Ad, Aa, Ab, Av, t + 2)
    WLG6
    STEPR(Br, Bk, Bd, Ba, Bb, Bv, t + 1)
    if (t + 3 < TT) DSRD(Br, Bk, Bd, Ba, Bb, Bv, t + 3)
    WLG6
  }
  STEPR(Ar, Ak, Ad, Aa, Ab, Av, TT - 2)
  WLG
  STEPR(Br, Bk, Bd, Ba, Bb, Bv, TT - 1)
#undef DMAQ
#undef DSRD
#undef WVM
#undef WLG
#undef WLG6
#undef STEPR
}

// ---------------------------------------------------------------------------
// K8: post-scan epilogue — 4-wide, red16 statistics.
// ---------------------------------------------------------------------------
__global__ __launch_bounds__(256) void k_post(
    const float* __restrict__ ybuf, const float* __restrict__ vb,
    const float* __restrict__ gvb, const float* __restrict__ bonb,
    const float* __restrict__ gnw, const float* __restrict__ gnb,
    __hip_bfloat16* __restrict__ xoh, __hip_bfloat16* __restrict__ xol) {
  int gid = blockIdx.x * 16 + (threadIdx.x >> 4);   // 0..BT*HH-1
  int l15 = threadIdx.x & 15;
  int bt = gid >> 5, h = gid & 31;
  size_t base = (size_t)bt * CC + h * 64 + l15 * 4;
  float4 y4 = *(const float4*)&ybuf[base];
  float yv[4] = {y4.x, y4.y, y4.z, y4.w};
  float s1 = yv[0] + yv[1] + yv[2] + yv[3];
  float s2 = fmaf(yv[0], yv[0], fmaf(yv[1], yv[1],
             fmaf(yv[2], yv[2], yv[3] * yv[3])));
  s1 = red16(s1);
  s2 = red16(s2);
  float mean = s1 * (1.0f / 64.0f);
  float var  = s2 * (1.0f / 64.0f) - mean * mean;
  float inv  = rsqrtf(var + GN_EPS);
  float4 gw4 = *(const float4*)&gnw[h * 64 + l15 * 4];
  float4 gb4 = *(const float4*)&gnb[h * 64 + l15 * 4];
  float4 vb4 = *(const float4*)&vb[base];
  float4 gv4 = *(const float4*)&gvb[base];
  float gw[4] = {gw4.x, gw4.y, gw4.z, gw4.w};
  float gb[4] = {gb4.x, gb4.y, gb4.z, gb4.w};
  float vbv[4] = {vb4.x, vb4.y, vb4.z, vb4.w};
  float gvv[4] = {gv4.x, gv4.y, gv4.z, gv4.w};
  float bo = bonb[bt * HH + h];
  ushort4 hv, lv;
  unsigned short* ph = (unsigned short*)&hv;
  unsigned short* pl = (unsigned short*)&lv;
#pragma unroll
  for (int j = 0; j < 4; ++j) {
    float x = fmaf((yv[j] - mean) * inv, gw[j], gb[j]) + bo * vbv[j];
    splitu(x * gvv[j], ph[j], pl[j]);
  }
  *(ushort4*)&xoh[base] = hv;
  *(ushort4*)&xol[base] = lv;
}

// ---------------------------------------------------------------------------
extern "C" void kernel_launch(void* const* d_in, const int* in_sizes, int n_in,
                              void* d_out, int out_size, void* d_ws, size_t ws_size,
                              hipStream_t stream) {
  (void)in_sizes; (void)n_in; (void)out_size; (void)ws_size;
  const float* hid    = (const float*)d_in[0];
  const float* shift  = (const float*)d_in[1];
  const float* st0    = (const float*)d_in[2];
  const float* vfirst = (const float*)d_in[3];
  const float* xrc = (const float*)d_in[4];
  const float* xwc = (const float*)d_in[5];
  const float* xkc = (const float*)d_in[6];
  const float* xvc = (const float*)d_in[7];
  const float* xac = (const float*)d_in[8];
  const float* xgc = (const float*)d_in[9];
  const float* w0  = (const float*)d_in[10];
  const float* w1  = (const float*)d_in[11];
  const float* w2  = (const float*)d_in[12];
  const float* a0  = (const float*)d_in[13];
  const float* a1  = (const float*)d_in[14];
  const float* a2  = (const float*)d_in[15];
  const float* v0  = (const float*)d_in[16];
  const float* v1  = (const float*)d_in[17];
  const float* v2  = (const float*)d_in[18];
  const float* g1  = (const float*)d_in[19];
  const float* g2  = (const float*)d_in[20];
  const float* kkc = (const float*)d_in[21];
  const float* kac = (const float*)d_in[22];
  const float* rk  = (const float*)d_in[23];
  const float* Wr  = (const float*)d_in[24];
  const float* Wk  = (const float*)d_in[25];
  const float* Wv  = (const float*)d_in[26];
  const float* Wo  = (const float*)d_in[27];
  const float* gnw = (const float*)d_in[28];
  const float* gnb = (const float*)d_in[29];
  float* out = (float*)d_out;

  char* p = (char*)d_ws;
  auto alloc = [&](size_t n) { char* q = p; p += (n + 255) & ~(size_t)255; return q; };
  const size_t EL = (size_t)BT * CC;

  // --- alias pool: xrh..xvl + Wrh,Wrl dead by k_gate time; db/awb/bwb +
  //     h2g (the old gvb slot) overlay them.
  char* pool = p;
  __hip_bfloat16* xrh = (__hip_bfloat16*)alloc(EL * 2);
  __hip_bfloat16* xrl = (__hip_bfloat16*)alloc(EL * 2);
  __hip_bfloat16* xkh = (__hip_bfloat16*)alloc(EL * 2);
  __hip_bfloat16* xkl = (__hip_bfloat16*)alloc(EL * 2);
  __hip_bfloat16* xvh = (__hip_bfloat16*)alloc(EL * 2);
  __hip_bfloat16* xvl = (__hip_bfloat16*)alloc(EL * 2);
  __hip_bfloat16* Wrh = (__hip_bfloat16*)alloc((size_t)CC * CC * 2);
  __hip_bfloat16* Wrl = (__hip_bfloat16*)alloc((size_t)CC * CC * 2);
  float* db  = (float*)pool;           // overlays xrh+xrl
  float* awb = db + EL;                // overlays xkh+xkl
  float* bwb = db + 2 * EL;            // overlays xvh+xvl
  float* h2g = db + 3 * EL;            // overlays Wrh+Wrl (old gvb slot)

  __hip_bfloat16* Wkh = (__hip_bfloat16*)alloc((size_t)CC * CC * 2);
  __hip_bfloat16* Wkl = (__hip_bfloat16*)alloc((size_t)CC * CC * 2);
  float* ybuf = (float*)Wkh;           // overlays Wkh+Wkl (dead after k-GEMM)
  float* h2v  = (float*)Wkh;           // same region, read by k_gate BEFORE scan writes ybuf

  __hip_bfloat16* Wvh = (__hip_bfloat16*)alloc((size_t)CC * CC * 2);
  __hip_bfloat16* Wvl = (__hip_bfloat16*)alloc((size_t)CC * CC * 2);
  __hip_bfloat16* Woh = (__hip_bfloat16*)alloc((size_t)CC * CC * 2);
  __hip_bfloat16* Wol = (__hip_bfloat16*)alloc((size_t)CC * CC * 2);
  __hip_bfloat16* xw  = (__hip_bfloat16*)alloc(EL * 2);
  __hip_bfloat16* xa  = (__hip_bfloat16*)alloc(EL * 2);
  __hip_bfloat16* xg  = (__hip_bfloat16*)alloc(EL * 2);
  float* h2w = (float*)xw;             // overlays xw+xa (dead after stage-1 GEMMs)
  __hip_bfloat16* w1t = (__hip_bfloat16*)alloc((size_t)64  * CC * 2);
  __hip_bfloat16* a1t = (__hip_bfloat16*)alloc((size_t)64  * CC * 2);
  __hip_bfloat16* v1t = (__hip_bfloat16*)alloc((size_t)64  * CC * 2);
  __hip_bfloat16* g1t = (__hip_bfloat16*)alloc((size_t)128 * CC * 2);
  float* rb  = (float*)alloc(EL * 4);
  float* kb  = (float*)alloc(EL * 4);  // raw k, then k_final in place
  float* vb  = (float*)alloc(EL * 4);  // raw v, then v_mix in place
  float* h1w = (float*)alloc((size_t)BT * 64  * 4);
  float* h1a = (float*)alloc((size_t)BT * 64  * 4);
  float* h1v = (float*)alloc((size_t)BT * 64  * 4);
  float* h1g = (float*)alloc((size_t)BT * 128 * 4);
  __hip_bfloat16* xoh = (__hip_bfloat16*)alloc(EL * 2);
  __hip_bfloat16* xol = (__hip_bfloat16*)alloc(EL * 2);
  float* h2a = (float*)xoh;            // overlays xoh+xol (k_post writes them AFTER k_gate)
  float* bonb = (float*)alloc((size_t)BT * HH * 4);   // per-(token,head) bonus
  // stage-2 split operands (small, fresh):
  __hip_bfloat16* h1wh = (__hip_bfloat16*)alloc((size_t)BT * 64 * 2);
  __hip_bfloat16* h1wl = (__hip_bfloat16*)alloc((size_t)BT * 64 * 2);
  __hip_bfloat16* h1ah = (__hip_bfloat16*)alloc((size_t)BT * 64 * 2);
  __hip_bfloat16* h1al = (__hip_bfloat16*)alloc((size_t)BT * 64 * 2);
  __hip_bfloat16* h1vh = (__hip_bfloat16*)alloc((size_t)BT * 64 * 2);
  __hip_bfloat16* h1vl = (__hip_bfloat16*)alloc((size_t)BT * 64 * 2);
  __hip_bfloat16* h1gh = (__hip_bfloat16*)alloc((size_t)BT * 128 * 2);
  __hip_bfloat16* h1gl = (__hip_bfloat16*)alloc((size_t)BT * 128 * 2);
  __hip_bfloat16* w2th = (__hip_bfloat16*)alloc((size_t)CC * 64 * 2);
  __hip_bfloat16* w2tl = (__hip_bfloat16*)alloc((size_t)CC * 64 * 2);
  __hip_bfloat16* a2th = (__hip_bfloat16*)alloc((size_t)CC * 64 * 2);
  __hip_bfloat16* a2tl = (__hip_bfloat16*)alloc((size_t)CC * 64 * 2);
  __hip_bfloat16* v2th = (__hip_bfloat16*)alloc((size_t)CC * 64 * 2);
  __hip_bfloat16* v2tl = (__hip_bfloat16*)alloc((size_t)CC * 64 * 2);
  __hip_bfloat16* g2th = (__hip_bfloat16*)alloc((size_t)CC * 128 * 2);
  __hip_bfloat16* g2tl = (__hip_bfloat16*)alloc((size_t)CC * 128 * 2);
  // total ~210 MiB (known-OK envelope: 220 OK, 268 crashed)

  k_prepx<<<4096, 256, 0, stream>>>(hid, shift, xrc, xwc, xkc, xvc, xac, xgc,
                                    xrh, xrl, xw, xkh, xkl, xvh, xvl, xa, xg);
  k_cvt2x4<<<dim3(4096, 4), 256, 0, stream>>>(Wr, Wk, Wv, Wo,
                                              Wrh, Wrl, Wkh, Wkl,
                                              Wvh, Wvl, Woh, Wol);
  k_tr4<<<dim3(1024, 4), 256, 0, stream>>>(w1, a1, v1, g1, w1t, a1t, v1t, g1t);
  k_trs4<<<dim3(1024, 4), 256, 0, stream>>>(w2, a2, v2, g2,
                                            w2th, w2tl, a2th, a2tl,
                                            v2th, v2tl, g2th, g2tl);

  k_gemm_big3<<<dim3(32, 16, 3), 256, 0, stream>>>(
      xrh, xrl, Wrh, Wrl, rb,
      xkh, xkl, Wkh, Wkl, kb,
      xvh, xvl, Wvh, Wvl, vb);
  k_lora1<<<dim3(32, 5), 256, 0, stream>>>(xw, xa, xvh, xg, w1t, a1t, v1t, g1t,
                                           h1w, h1a, h1v, h1g);

  k_act2<<<256, 256, 0, stream>>>(h1w, h1a, h1v, h1g,
                                  h1wh, h1wl, h1ah, h1al,
                                  h1vh, h1vl, h1gh, h1gl);
  // stage-2 LoRA dots on MFMA (split precision), fused 4-in-1. Overlays:
  //   h2w->xw+xa, h2a->xoh+xol, h2v->Wkh+Wkl, h2g->Wrh+Wrl.
  k_gemm_s2x4<<<dim3(32, 16, 4), 256, 0, stream>>>(
      h1wh, h1wl, h1ah, h1al, h1vh, h1vl, h1gh, h1gl,
      w2th, w2tl, a2th, a2tl, v2th, v2tl, g2th, g2tl,
      h2w, h2a, h2v, h2g);

  k_gate<<<4096, 256, 0, stream>>>(h2w, h2a, h2v, w0, a0, v0, kkc, kac,
                                   kb, vb, vfirst, rb, rk, db, awb, bwb, bonb);
  k_scan<<<1024, 64, 0, stream>>>(rb, kb, db, awb, bwb, vb, st0, ybuf);
  k_post<<<4096, 256, 0, stream>>>(ybuf, vb, h2g, bonb, gnw, gnb, xoh, xol);
  k_gemm_bt3<<<dim3(32, 16), 256, 0, stream>>>(xoh, xol, Woh, Wol, out, BT, CC, CC);
}

// Round 16
// 739.868 us; speedup vs baseline: 1.4727x; 1.0113x over previous
//
#include <hip/hip_runtime.h>
#include <hip/hip_bf16.h>

// Problem constants (RWKV-7 Tmix: B=2, T=1024, C=2048, H=32, N=64)
#define BB 2
#define TT 1024
#define CC 2048
#define HH 32
#define BT 2048          // BB*TT tokens
#define GN_EPS 6.4e-4f   // 1e-5 * 8^2

typedef __attribute__((ext_vector_type(8))) __bf16 bf16x8;
typedef __attribute__((ext_vector_type(4))) float f32x4;

__device__ __forceinline__ float sigf(float x) { return 1.0f / (1.0f + expf(-x)); }

__device__ __forceinline__ void split_bf16(float x, __hip_bfloat16& hi, __hip_bfloat16& lo) {
  __hip_bfloat16 h = __float2bfloat16(x);
  hi = h;
  lo = __float2bfloat16(x - __bfloat162float(h));
}

__device__ __forceinline__ unsigned short bfb(float x) {
  union { __hip_bfloat16 h; unsigned short u; } cv;
  cv.h = __float2bfloat16(x);
  return cv.u;
}
__device__ __forceinline__ void splitu(float x, unsigned short& hi, unsigned short& lo) {
  union { __hip_bfloat16 h; unsigned short u; } cv;
  cv.h = __float2bfloat16(x);
  hi = cv.u;
  lo = bfb(x - __bfloat162float(cv.h));
}

// Sum over each aligned 16-lane group, pure DPP (no LDS pipe on the chain).
__device__ __forceinline__ float red16(float x) {
  x += __int_as_float(__builtin_amdgcn_update_dpp(
      0, __float_as_int(x), 0xB1 /*quad_perm [1,0,3,2]*/, 0xF, 0xF, true));
  x += __int_as_float(__builtin_amdgcn_update_dpp(
      0, __float_as_int(x), 0x4E /*quad_perm [2,3,0,1]*/, 0xF, 0xF, true));
  x += __int_as_float(__builtin_amdgcn_update_dpp(
      0, __float_as_int(x), 0x141 /*row_half_mirror*/, 0xF, 0xF, true));
  x += __int_as_float(__builtin_amdgcn_update_dpp(
      0, __float_as_int(x), 0x140 /*row_mirror*/, 0xF, 0xF, true));
  return x;
}

// ---------------------------------------------------------------------------
// K1: token shift + six lerped projections — 4-wide vectorized (r14 winner).
// ---------------------------------------------------------------------------
__global__ __launch_bounds__(256) void k_prepx(
    const float* __restrict__ hid, const float* __restrict__ shift,
    const float* __restrict__ xrc, const float* __restrict__ xwc,
    const float* __restrict__ xkc, const float* __restrict__ xvc,
    const float* __restrict__ xac, const float* __restrict__ xgc,
    __hip_bfloat16* __restrict__ xrh, __hip_bfloat16* __restrict__ xrl,
    __hip_bfloat16* __restrict__ xw,
    __hip_bfloat16* __restrict__ xkh, __hip_bfloat16* __restrict__ xkl,
    __hip_bfloat16* __restrict__ xvh, __hip_bfloat16* __restrict__ xvl,
    __hip_bfloat16* __restrict__ xa, __hip_bfloat16* __restrict__ xg) {
  int i4 = (blockIdx.x * 256 + threadIdx.x) * 4;   // < BT*CC
  int c  = i4 & (CC - 1);
  int bt = i4 >> 11;
  int t  = bt & (TT - 1);
  int b  = bt >> 10;
  float4 hc = *(const float4*)&hid[i4];
  float4 hp = (t == 0) ? *(const float4*)&shift[b * CC + c]
                       : *(const float4*)&hid[i4 - CC];
  float xxv[4] = {hp.x - hc.x, hp.y - hc.y, hp.z - hc.z, hp.w - hc.w};
  float hcv[4] = {hc.x, hc.y, hc.z, hc.w};
  float4 crv = *(const float4*)&xrc[c];
  float4 cwv = *(const float4*)&xwc[c];
  float4 ckv = *(const float4*)&xkc[c];
  float4 cvv = *(const float4*)&xvc[c];
  float4 cav = *(const float4*)&xac[c];
  float4 cgv = *(const float4*)&xgc[c];
  float cr[4] = {crv.x, crv.y, crv.z, crv.w};
  float cw[4] = {cwv.x, cwv.y, cwv.z, cwv.w};
  float ck[4] = {ckv.x, ckv.y, ckv.z, ckv.w};
  float cv[4] = {cvv.x, cvv.y, cvv.z, cvv.w};
  float ca[4] = {cav.x, cav.y, cav.z, cav.w};
  float cg[4] = {cgv.x, cgv.y, cgv.z, cgv.w};
  ushort4 rh, rl, kh, kl, vh, vl, wv, av, gv;
  unsigned short* prh = (unsigned short*)&rh;
  unsigned short* prl = (unsigned short*)&rl;
  unsigned short* pkh = (unsigned short*)&kh;
  unsigned short* pkl = (unsigned short*)&kl;
  unsigned short* pvh = (unsigned short*)&vh;
  unsigned short* pvl = (unsigned short*)&vl;
  unsigned short* pw  = (unsigned short*)&wv;
  unsigned short* pa  = (unsigned short*)&av;
  unsigned short* pg  = (unsigned short*)&gv;
#pragma unroll
  for (int j = 0; j < 4; ++j) {
    splitu(fmaf(xxv[j], cr[j], hcv[j]), prh[j], prl[j]);
    splitu(fmaf(xxv[j], ck[j], hcv[j]), pkh[j], pkl[j]);
    splitu(fmaf(xxv[j], cv[j], hcv[j]), pvh[j], pvl[j]);
    pw[j] = bfb(fmaf(xxv[j], cw[j], hcv[j]));
    pa[j] = bfb(fmaf(xxv[j], ca[j], hcv[j]));
    pg[j] = bfb(fmaf(xxv[j], cg[j], hcv[j]));
  }
  *(ushort4*)&xrh[i4] = rh; *(ushort4*)&xrl[i4] = rl;
  *(ushort4*)&xkh[i4] = kh; *(ushort4*)&xkl[i4] = kl;
  *(ushort4*)&xvh[i4] = vh; *(ushort4*)&xvl[i4] = vl;
  *(ushort4*)&xw[i4]  = wv; *(ushort4*)&xa[i4]  = av;
  *(ushort4*)&xg[i4]  = gv;
}

// ---------------------------------------------------------------------------
// K2: f32 -> hi+lo bf16 split for all four big weights, 4-wide vectorized.
// ---------------------------------------------------------------------------
__global__ __launch_bounds__(256) void k_cvt2x4(
    const float* __restrict__ i0, const float* __restrict__ i1,
    const float* __restrict__ i2, const float* __restrict__ i3,
    __hip_bfloat16* __restrict__ h0, __hip_bfloat16* __restrict__ l0,
    __hip_bfloat16* __restrict__ h1, __hip_bfloat16* __restrict__ l1,
    __hip_bfloat16* __restrict__ h2, __hip_bfloat16* __restrict__ l2,
    __hip_bfloat16* __restrict__ h3, __hip_bfloat16* __restrict__ l3) {
  int i4 = (blockIdx.x * 256 + threadIdx.x) * 4;
  int w = blockIdx.y;
  const float* in = (w == 0) ? i0 : (w == 1) ? i1 : (w == 2) ? i2 : i3;
  __hip_bfloat16* oh = (w == 0) ? h0 : (w == 1) ? h1 : (w == 2) ? h2 : h3;
  __hip_bfloat16* ol = (w == 0) ? l0 : (w == 1) ? l1 : (w == 2) ? l2 : l3;
  float4 v = *(const float4*)&in[i4];
  float vv[4] = {v.x, v.y, v.z, v.w};
  ushort4 hv, lv;
  unsigned short* ph = (unsigned short*)&hv;
  unsigned short* pl = (unsigned short*)&lv;
#pragma unroll
  for (int j = 0; j < 4; ++j) splitu(vv[j], ph[j], pl[j]);
  *(ushort4*)&oh[i4] = hv;
  *(ushort4*)&ol[i4] = lv;
}

// ---------------------------------------------------------------------------
// K3: fused transpose-convert of the 4 stage-1 "up" weights (one dispatch).
// ---------------------------------------------------------------------------
__global__ __launch_bounds__(256) void k_tr4(
    const float* __restrict__ w1, const float* __restrict__ a1,
    const float* __restrict__ v1, const float* __restrict__ g1,
    __hip_bfloat16* __restrict__ w1t, __hip_bfloat16* __restrict__ a1t,
    __hip_bfloat16* __restrict__ v1t, __hip_bfloat16* __restrict__ g1t) {
  int i = blockIdx.x * 256 + threadIdx.x;   // < 128*2048 max
  int y = blockIdx.y;
  const float* in; __hip_bfloat16* out; int N0, NP;
  if (y == 0)      { in = w1; out = w1t; N0 = 64;  NP = 64;  }
  else if (y == 1) { in = a1; out = a1t; N0 = 64;  NP = 64;  }
  else if (y == 2) { in = v1; out = v1t; N0 = 32;  NP = 64;  }
  else             { in = g1; out = g1t; N0 = 128; NP = 128; }
  if (i >= NP * 2048) return;
  int n = i >> 11;
  int k = i & 2047;
  float v = (n < N0) ? in[k * N0 + n] : 0.0f;
  out[i] = __float2bfloat16(v);
}

// ---------------------------------------------------------------------------
// K3b: fused transpose+split of the 4 stage-2 "down" weights (one dispatch).
// ---------------------------------------------------------------------------
__global__ __launch_bounds__(256) void k_trs4(
    const float* __restrict__ w2, const float* __restrict__ a2,
    const float* __restrict__ v2, const float* __restrict__ g2,
    __hip_bfloat16* __restrict__ w2th, __hip_bfloat16* __restrict__ w2tl,
    __hip_bfloat16* __restrict__ a2th, __hip_bfloat16* __restrict__ a2tl,
    __hip_bfloat16* __restrict__ v2th, __hip_bfloat16* __restrict__ v2tl,
    __hip_bfloat16* __restrict__ g2th, __hip_bfloat16* __restrict__ g2tl) {
  int i = blockIdx.x * 256 + threadIdx.x;   // < CC*128 max
  int y = blockIdx.y;
  const float* in; __hip_bfloat16 *oh, *ol; int N0, lgK;
  if (y == 0)      { in = w2; oh = w2th; ol = w2tl; N0 = 64;  lgK = 6; }
  else if (y == 1) { in = a2; oh = a2th; ol = a2tl; N0 = 64;  lgK = 6; }
  else if (y == 2) { in = v2; oh = v2th; ol = v2tl; N0 = 32;  lgK = 6; }
  else             { in = g2; oh = g2th; ol = g2tl; N0 = 128; lgK = 7; }
  if (i >= (CC << lgK)) return;
  int n = i >> lgK;
  int k = i & ((1 << lgK) - 1);
  float v = (k < N0) ? in[k * CC + n] : 0.0f;
  split_bf16(v, oh[i], ol[i]);
}

// ---------------------------------------------------------------------------
// K4: fused stage-1 LoRA GEMM, LDS-staged — ROUND-23: +T2 bank-conflict
// swizzle (quad' = quad ^ (row&3) on reads; inverse permutation on the DMA
// global SOURCE, dest stays linear per rule-21). Data bit-identical.
// ---------------------------------------------------------------------------
__global__ __launch_bounds__(256, 4) void k_lora1(
    const __hip_bfloat16* __restrict__ xw, const __hip_bfloat16* __restrict__ xa,
    const __hip_bfloat16* __restrict__ xv, const __hip_bfloat16* __restrict__ xg,
    const __hip_bfloat16* __restrict__ w1t, const __hip_bfloat16* __restrict__ a1t,
    const __hip_bfloat16* __restrict__ v1t, const __hip_bfloat16* __restrict__ g1t,
    float* __restrict__ h1w, float* __restrict__ h1a,
    float* __restrict__ h1v, float* __restrict__ h1g) {
  __shared__ __align__(16) __hip_bfloat16 sA[2][64 * 32], sB[2][64 * 32];
  int tid  = threadIdx.x;
  int lane = tid & 63;
  int wv   = tid >> 6;
  int l15  = lane & 15;
  int quad = lane >> 4;
  int m0 = blockIdx.x * 64;
  int bly = blockIdx.y;

  const __hip_bfloat16* Ab;
  const __hip_bfloat16* Bb;
  float* Ob;
  int os, cb;
  if (bly == 0)      { Ab = xw; Bb = w1t;            Ob = h1w; os = 64;  cb = 0;  }
  else if (bly == 1) { Ab = xa; Bb = a1t;            Ob = h1a; os = 64;  cb = 0;  }
  else if (bly == 2) { Ab = xv; Bb = v1t;            Ob = h1v; os = 64;  cb = 0;  }
  else if (bly == 3) { Ab = xg; Bb = g1t;            Ob = h1g; os = 128; cb = 0;  }
  else               { Ab = xg; Bb = g1t + 64 * CC;  Ob = h1g; os = 128; cb = 64; }

  int srow = wv * 16 + (lane >> 2);
  int scol = (((lane & 3) ^ ((lane >> 2) & 3)) * 8);   // inverse-swizzled src
  const __hip_bfloat16* gA = Ab + (size_t)(m0 + srow) * CC + scol;
  const __hip_bfloat16* gB = Bb + (size_t)srow * CC + scol;

  f32x4 z = {0.f, 0.f, 0.f, 0.f};
  f32x4 acc0 = z, acc1 = z, acc2 = z, acc3 = z;

  int sw = (quad ^ (l15 & 3)) * 8;                     // swizzled read col
  int aoff = (wv * 16 + l15) * 32 + sw;
  int boff = l15 * 32 + sw;

#define STAGE1(BUF, KO)                                                      \
  { unsigned db_ = (unsigned)(BUF) * 4096u + (unsigned)wv * 1024u;           \
    __builtin_amdgcn_global_load_lds(                                        \
        (const __attribute__((address_space(1))) void*)(gA + (KO)),          \
        (__attribute__((address_space(3))) void*)((char*)sA + db_), 16, 0, 0);\
    __builtin_amdgcn_global_load_lds(                                        \
        (const __attribute__((address_space(1))) void*)(gB + (KO)),          \
        (__attribute__((address_space(3))) void*)((char*)sB + db_), 16, 0, 0);}

  STAGE1(0, 0)
  __syncthreads();

  for (int k0 = 0; k0 < CC; k0 += 32) {
    int cur = (k0 >> 5) & 1;
    if (k0 + 32 < CC) STAGE1(cur ^ 1, k0 + 32)

    const __hip_bfloat16* pA_ = &sA[cur][0];
    const __hip_bfloat16* pB_ = &sB[cur][0];
    bf16x8 av = *(const bf16x8*)(pA_ + aoff);
    bf16x8 b0 = *(const bf16x8*)(pB_ + boff);
    bf16x8 b1 = *(const bf16x8*)(pB_ + boff + 16 * 32);
    bf16x8 b2 = *(const bf16x8*)(pB_ + boff + 32 * 32);
    bf16x8 b3 = *(const bf16x8*)(pB_ + boff + 48 * 32);

    acc0 = __builtin_amdgcn_mfma_f32_16x16x32_bf16(av, b0, acc0, 0, 0, 0);
    acc1 = __builtin_amdgcn_mfma_f32_16x16x32_bf16(av, b1, acc1, 0, 0, 0);
    acc2 = __builtin_amdgcn_mfma_f32_16x16x32_bf16(av, b2, acc2, 0, 0, 0);
    acc3 = __builtin_amdgcn_mfma_f32_16x16x32_bf16(av, b3, acc3, 0, 0, 0);

    __syncthreads();
  }
#undef STAGE1

  int row0 = m0 + wv * 16 + quad * 4;
  int colb = cb + l15;
#pragma unroll
  for (int r = 0; r < 4; ++r) {
    Ob[(size_t)(row0 + r) * os + colb +  0] = acc0[r];
    Ob[(size_t)(row0 + r) * os + colb + 16] = acc1[r];
    Ob[(size_t)(row0 + r) * os + colb + 32] = acc2[r];
    Ob[(size_t)(row0 + r) * os + colb + 48] = acc3[r];
  }
}

// ---------------------------------------------------------------------------
// K4b body: split-precision GEMM, 64x128 tile, 2-phase LDS staging —
// ROUND-23: +T2 swizzle. r15 PMC: SQ_LDS_BANK_CONFLICT=28.3M (~21% of
// cycles): row-major [rows][32]bf16 (64B rows) puts service batches of 8
// lanes on only 2 bank-groups (4-way). Fix (rule-21 both-sides): read
// quad' = quad ^ (row&3) (involution; 2-way residual = free per m136),
// DMA dest linear, global SOURCE col-group = (l&3)^((l>>2)&3). All stripe
// bases = 0 mod 4 rows and B's j*16-row offsets preserve row&3, so the
// mapping is exact. Data bit-identical -> absmax unchanged.
// ---------------------------------------------------------------------------
__device__ __forceinline__ void gemm_bt3_body(
    const __hip_bfloat16* __restrict__ Ah, const __hip_bfloat16* __restrict__ Al,
    const __hip_bfloat16* __restrict__ Bh, const __hip_bfloat16* __restrict__ Bl,
    float* __restrict__ Cm, int Nn, int K) {
  __shared__ __align__(16) __hip_bfloat16 sAh[2][64 * 32],  sAl[2][64 * 32];
  __shared__ __align__(16) __hip_bfloat16 sBh[2][128 * 32], sBl[2][128 * 32];
  int tid  = threadIdx.x;
  int lane = tid & 63;
  int wv   = tid >> 6;
  int l15  = lane & 15;
  int quad = lane >> 4;
  int m0 = blockIdx.x * 64;
  int n0 = blockIdx.y * 128;

  int srowA = wv * 16 + (lane >> 2);
  int srowB = wv * 32 + (lane >> 2);
  int scol  = (((lane & 3) ^ ((lane >> 2) & 3)) * 8);  // inverse-swizzled src
  const __hip_bfloat16* gAh  = Ah + (size_t)(m0 + srowA) * K + scol;
  const __hip_bfloat16* gAl  = Al + (size_t)(m0 + srowA) * K + scol;
  const __hip_bfloat16* gBh0 = Bh + (size_t)(n0 + srowB) * K + scol;
  const __hip_bfloat16* gBh1 = Bh + (size_t)(n0 + srowB + 16) * K + scol;
  const __hip_bfloat16* gBl0 = Bl + (size_t)(n0 + srowB) * K + scol;
  const __hip_bfloat16* gBl1 = Bl + (size_t)(n0 + srowB + 16) * K + scol;

  f32x4 z = {0.f, 0.f, 0.f, 0.f};
  f32x4 acc[8];
#pragma unroll
  for (int j = 0; j < 8; ++j) acc[j] = z;

  int sw = (quad ^ (l15 & 3)) * 8;                     // swizzled read col
  int aoff = (wv * 16 + l15) * 32 + sw;
  int boff = l15 * 32 + sw;

#define STAGE(BUF, KO)                                                       \
  { unsigned dA_ = (unsigned)(BUF) * 4096u + (unsigned)wv * 1024u;           \
    unsigned dB_ = (unsigned)(BUF) * 8192u + (unsigned)wv * 2048u;           \
    __builtin_amdgcn_global_load_lds(                                        \
        (const __attribute__((address_space(1))) void*)(gAh + (KO)),         \
        (__attribute__((address_space(3))) void*)((char*)sAh + dA_), 16, 0, 0);\
    __builtin_amdgcn_global_load_lds(                                        \
        (const __attribute__((address_space(1))) void*)(gAl + (KO)),         \
        (__attribute__((address_space(3))) void*)((char*)sAl + dA_), 16, 0, 0);\
    __builtin_amdgcn_global_load_lds(                                        \
        (const __attribute__((address_space(1))) void*)(gBh0 + (KO)),        \
        (__attribute__((address_space(3))) void*)((char*)sBh + dB_), 16, 0, 0);\
    __builtin_amdgcn_global_load_lds(                                        \
        (const __attribute__((address_space(1))) void*)(gBh1 + (KO)),        \
        (__attribute__((address_space(3))) void*)((char*)sBh + dB_ + 1024u), 16, 0, 0);\
    __builtin_amdgcn_global_load_lds(                                        \
        (const __attribute__((address_space(1))) void*)(gBl0 + (KO)),        \
        (__attribute__((address_space(3))) void*)((char*)sBl + dB_), 16, 0, 0);\
    __builtin_amdgcn_global_load_lds(                                        \
        (const __attribute__((address_space(1))) void*)(gBl1 + (KO)),        \
        (__attribute__((address_space(3))) void*)((char*)sBl + dB_ + 1024u), 16, 0, 0);}

  STAGE(0, 0)
  __syncthreads();   // buf0 staged (implicit vmcnt(0) drain before barrier)

  for (int k0 = 0; k0 < K; k0 += 32) {
    int cur = (k0 >> 5) & 1;
    if (k0 + 32 < K) STAGE(cur ^ 1, k0 + 32)   // next tile in flight NOW

    const __hip_bfloat16* pA_h = &sAh[cur][0];
    const __hip_bfloat16* pA_l = &sAl[cur][0];
    const __hip_bfloat16* pB_h = &sBh[cur][0];
    const __hip_bfloat16* pB_l = &sBl[cur][0];
    bf16x8 ah = *(const bf16x8*)(pA_h + aoff);
    bf16x8 al = *(const bf16x8*)(pA_l + aoff);
#pragma unroll
    for (int j = 0; j < 8; ++j) {
      bf16x8 bh = *(const bf16x8*)(pB_h + boff + j * 16 * 32);
      bf16x8 bl = *(const bf16x8*)(pB_l + boff + j * 16 * 32);
      acc[j] = __builtin_amdgcn_mfma_f32_16x16x32_bf16(ah, bh, acc[j], 0, 0, 0);
      acc[j] = __builtin_amdgcn_mfma_f32_16x16x32_bf16(ah, bl, acc[j], 0, 0, 0);
      acc[j] = __builtin_amdgcn_mfma_f32_16x16x32_bf16(al, bh, acc[j], 0, 0, 0);
    }

    __syncthreads();   // ONE barrier: next buf staged + this buf reads done
  }
#undef STAGE

  int row0 = m0 + wv * 16 + quad * 4;
#pragma unroll
  for (int j = 0; j < 8; ++j) {
    int colb = n0 + j * 16 + l15;
#pragma unroll
    for (int r = 0; r < 4; ++r)
      Cm[(size_t)(row0 + r) * Nn + colb] = acc[j][r];
  }
}

// standalone (Wo output GEMM)
__global__ __launch_bounds__(256, 3) void k_gemm_bt3(
    const __hip_bfloat16* __restrict__ Ah, const __hip_bfloat16* __restrict__ Al,
    const __hip_bfloat16* __restrict__ Bh, const __hip_bfloat16* __restrict__ Bl,
    float* __restrict__ Cm, int M, int Nn, int K) {
  gemm_bt3_body(Ah, Al, Bh, Bl, Cm, Nn, K);
}

// 3 big input GEMMs (r/k/v) fused into one dispatch, grid z = slice.
__global__ __launch_bounds__(256, 3) void k_gemm_big3(
    const __hip_bfloat16* __restrict__ Ah0, const __hip_bfloat16* __restrict__ Al0,
    const __hip_bfloat16* __restrict__ Bh0, const __hip_bfloat16* __restrict__ Bl0,
    float* __restrict__ C0,
    const __hip_bfloat16* __restrict__ Ah1, const __hip_bfloat16* __restrict__ Al1,
    const __hip_bfloat16* __restrict__ Bh1, const __hip_bfloat16* __restrict__ Bl1,
    float* __restrict__ C1,
    const __hip_bfloat16* __restrict__ Ah2, const __hip_bfloat16* __restrict__ Al2,
    const __hip_bfloat16* __restrict__ Bh2, const __hip_bfloat16* __restrict__ Bl2,
    float* __restrict__ C2) {
  int zz = blockIdx.z;
  const __hip_bfloat16* Ah = (zz == 0) ? Ah0 : (zz == 1) ? Ah1 : Ah2;
  const __hip_bfloat16* Al = (zz == 0) ? Al0 : (zz == 1) ? Al1 : Al2;
  const __hip_bfloat16* Bh = (zz == 0) ? Bh0 : (zz == 1) ? Bh1 : Bh2;
  const __hip_bfloat16* Bl = (zz == 0) ? Bl0 : (zz == 1) ? Bl1 : Bl2;
  float* Cm = (zz == 0) ? C0 : (zz == 1) ? C1 : C2;
  gemm_bt3_body(Ah, Al, Bh, Bl, Cm, CC, CC);
}

// 4 stage-2 GEMMs fused into one dispatch, grid z = slice (K table).
__global__ __launch_bounds__(256, 3) void k_gemm_s2x4(
    const __hip_bfloat16* __restrict__ h1wh, const __hip_bfloat16* __restrict__ h1wl,
    const __hip_bfloat16* __restrict__ h1ah, const __hip_bfloat16* __restrict__ h1al,
    const __hip_bfloat16* __restrict__ h1vh, const __hip_bfloat16* __restrict__ h1vl,
    const __hip_bfloat16* __restrict__ h1gh, const __hip_bfloat16* __restrict__ h1gl,
    const __hip_bfloat16* __restrict__ w2th, const __hip_bfloat16* __restrict__ w2tl,
    const __hip_bfloat16* __restrict__ a2th, const __hip_bfloat16* __restrict__ a2tl,
    const __hip_bfloat16* __restrict__ v2th, const __hip_bfloat16* __restrict__ v2tl,
    const __hip_bfloat16* __restrict__ g2th, const __hip_bfloat16* __restrict__ g2tl,
    float* __restrict__ h2w, float* __restrict__ h2a,
    float* __restrict__ h2v, float* __restrict__ h2g) {
  int zz = blockIdx.z;
  const __hip_bfloat16* Ah = (zz == 0) ? h1wh : (zz == 1) ? h1ah : (zz == 2) ? h1vh : h1gh;
  const __hip_bfloat16* Al = (zz == 0) ? h1wl : (zz == 1) ? h1al : (zz == 2) ? h1vl : h1gl;
  const __hip_bfloat16* Bh = (zz == 0) ? w2th : (zz == 1) ? a2th : (zz == 2) ? v2th : g2th;
  const __hip_bfloat16* Bl = (zz == 0) ? w2tl : (zz == 1) ? a2tl : (zz == 2) ? v2tl : g2tl;
  float* Cm = (zz == 0) ? h2w : (zz == 1) ? h2a : (zz == 2) ? h2v : h2g;
  int K = (zz == 3) ? 128 : 64;
  gemm_bt3_body(Ah, Al, Bh, Bl, Cm, CC, K);
}

// ---------------------------------------------------------------------------
// K5: activations + hi/lo split of stage-1 LoRA outputs — 4-wide vectorized.
// ---------------------------------------------------------------------------
__global__ __launch_bounds__(256) void k_act2(
    const float* __restrict__ h1w, const float* __restrict__ h1a,
    const float* __restrict__ h1v, const float* __restrict__ h1g,
    __hip_bfloat16* __restrict__ wh, __hip_bfloat16* __restrict__ wl,
    __hip_bfloat16* __restrict__ ah, __hip_bfloat16* __restrict__ al,
    __hip_bfloat16* __restrict__ vh, __hip_bfloat16* __restrict__ vl,
    __hip_bfloat16* __restrict__ gh, __hip_bfloat16* __restrict__ gl) {
  int i4 = (blockIdx.x * 256 + threadIdx.x) * 4;   // over BT*128
  if (i4 < BT * 64) {
    float4 w = *(const float4*)&h1w[i4];
    float4 a = *(const float4*)&h1a[i4];
    float4 v = *(const float4*)&h1v[i4];
    float wvv[4] = {w.x, w.y, w.z, w.w};
    float avv[4] = {a.x, a.y, a.z, a.w};
    float vvv[4] = {v.x, v.y, v.z, v.w};
    ushort4 whv, wlv, ahv, alv, vhv, vlv;
    unsigned short* p0 = (unsigned short*)&whv;
    unsigned short* p1 = (unsigned short*)&wlv;
    unsigned short* p2 = (unsigned short*)&ahv;
    unsigned short* p3 = (unsigned short*)&alv;
    unsigned short* p4 = (unsigned short*)&vhv;
    unsigned short* p5 = (unsigned short*)&vlv;
#pragma unroll
    for (int j = 0; j < 4; ++j) {
      splitu(tanhf(wvv[j]), p0[j], p1[j]);
      splitu(avv[j], p2[j], p3[j]);
      splitu(vvv[j], p4[j], p5[j]);
    }
    *(ushort4*)&wh[i4] = whv; *(ushort4*)&wl[i4] = wlv;
    *(ushort4*)&ah[i4] = ahv; *(ushort4*)&al[i4] = alv;
    *(ushort4*)&vh[i4] = vhv; *(ushort4*)&vl[i4] = vlv;
  }
  float4 g = *(const float4*)&h1g[i4];
  float gvv[4] = {g.x, g.y, g.z, g.w};
  ushort4 ghv, glv;
  unsigned short* p6 = (unsigned short*)&ghv;
  unsigned short* p7 = (unsigned short*)&glv;
#pragma unroll
  for (int j = 0; j < 4; ++j) splitu(sigf(gvv[j]), p6[j], p7[j]);
  *(ushort4*)&gh[i4] = ghv; *(ushort4*)&gl[i4] = glv;
}

// ---------------------------------------------------------------------------
// K6: gates + kk-normalize + per-head bonus — 4-wide, red16 reductions.
// ---------------------------------------------------------------------------
__global__ __launch_bounds__(256) void k_gate(
    const float* __restrict__ h2w, const float* __restrict__ h2a,
    const float* __restrict__ h2v,
    const float* __restrict__ w0, const float* __restrict__ a0,
    const float* __restrict__ v0, const float* __restrict__ kkc,
    const float* __restrict__ kac, float* __restrict__ kbuf,
    float* __restrict__ vbuf, const float* __restrict__ vfirst,
    const float* __restrict__ rbuf, const float* __restrict__ rk,
    float* __restrict__ dec, float* __restrict__ aw,
    float* __restrict__ bw, float* __restrict__ bonb) {
  int i4 = (blockIdx.x * 256 + threadIdx.x) * 4;   // < BT*CC
  int c = i4 & (CC - 1);
  float4 kv4 = *(const float4*)&kbuf[i4];
  float4 vv4 = *(const float4*)&vbuf[i4];
  float4 vf4 = *(const float4*)&vfirst[i4];
  float4 hw4 = *(const float4*)&h2w[i4];
  float4 ha4 = *(const float4*)&h2a[i4];
  float4 hv4 = *(const float4*)&h2v[i4];
  float4 w04 = *(const float4*)&w0[c];
  float4 a04 = *(const float4*)&a0[c];
  float4 v04 = *(const float4*)&v0[c];
  float4 kk4 = *(const float4*)&kkc[c];
  float4 ka4 = *(const float4*)&kac[c];
  float4 rk4 = *(const float4*)&rk[c];
  float4 rb4 = *(const float4*)&rbuf[i4];
  float kv[4] = {kv4.x, kv4.y, kv4.z, kv4.w};
  float vv[4] = {vv4.x, vv4.y, vv4.z, vv4.w};
  float vf[4] = {vf4.x, vf4.y, vf4.z, vf4.w};
  float hw[4] = {hw4.x, hw4.y, hw4.z, hw4.w};
  float ha[4] = {ha4.x, ha4.y, ha4.z, ha4.w};
  float hv[4] = {hv4.x, hv4.y, hv4.z, hv4.w};
  float w0v[4] = {w04.x, w04.y, w04.z, w04.w};
  float a0v[4] = {a04.x, a04.y, a04.z, a04.w};
  float v0v[4] = {v04.x, v04.y, v04.z, v04.w};
  float kkv[4] = {kk4.x, kk4.y, kk4.z, kk4.w};
  float kav[4] = {ka4.x, ka4.y, ka4.z, ka4.w};
  float rkv[4] = {rk4.x, rk4.y, rk4.z, rk4.w};
  float rbv[4] = {rb4.x, rb4.y, rb4.z, rb4.w};
  float d_[4], as[4], vm[4], kfv[4], kku[4];
  float sl = 0.f, bl = 0.f;
#pragma unroll
  for (int j = 0; j < 4; ++j) {
    d_[j] = 0.60653065971f * sigf(w0v[j] + hw[j]);   // sigmoid * e^-0.5
    as[j] = sigf(a0v[j] + ha[j]);
    float vs = sigf(v0v[j] + hv[j]);
    vm[j] = vv[j] + (vf[j] - vv[j]) * vs;
    kfv[j] = kv[j] * (1.0f + kav[j] * (as[j] - 1.0f));
    kku[j] = kv[j] * kkv[j];
    sl = fmaf(kku[j], kku[j], sl);
    bl = fmaf(rbv[j] * kfv[j], rkv[j], bl);
  }
  float s = red16(sl);                 // per-head L2 (16 lanes x 4 cols)
  float nrm = fmaxf(sqrtf(s), 1e-12f);
  float bon = red16(bl);
  if ((threadIdx.x & 15) == 0) bonb[(i4 >> 11) * HH + (c >> 6)] = bon;
  float4 o0, o1, o2, o3, o4;
  float* q0 = (float*)&o0; float* q1 = (float*)&o1; float* q2 = (float*)&o2;
  float* q3 = (float*)&o3; float* q4 = (float*)&o4;
#pragma unroll
  for (int j = 0; j < 4; ++j) {
    float kkn = kku[j] / nrm;
    q0[j] = d_[j];
    q1[j] = -kkn;
    q2[j] = kkn * as[j];
    q3[j] = kfv[j];
    q4[j] = vm[j];
  }
  *(float4*)&dec[i4] = o0;
  *(float4*)&aw[i4]  = o1;
  *(float4*)&bw[i4]  = o2;
  *(float4*)&kbuf[i4] = o3;
  *(float4*)&vbuf[i4] = o4;
}

// ---------------------------------------------------------------------------
// K7: WKV7 scan — r13 counted-lgkm LDS-DMA-ring version (~180 µs), unchanged.
// ---------------------------------------------------------------------------
__global__ __launch_bounds__(64, 1) void k_scan(
    const float* __restrict__ rbuf, const float* __restrict__ kf,
    const float* __restrict__ dec, const float* __restrict__ aw,
    const float* __restrict__ bw, const float* __restrict__ vbuf,
    const float* __restrict__ st0, float* __restrict__ ybuf) {
  __shared__ __align__(16) char ldsbuf[16 * 2048];
  int blk = blockIdx.x;                     // 0..1023
  int xcd = blk & 7;
  int q   = blk >> 3;                       // 0..127
  int bh  = xcd * 8 + (q & 7);              // 16 rg-waves of a head share blk%8
  int rg  = q >> 3;                         // 0..15
  int b = bh >> 5, h = bh & 31;
  int lane = threadIdx.x;
  int l15  = lane & 15;
  int row  = rg * 4 + (lane >> 4);
  size_t tokbase = (size_t)b * TT * CC + h * 64;

  f32x4 S = *(const f32x4*)(st0 + ((size_t)bh * 64 + row) * 64 + l15 * 4);
  bool writer = (l15 == 0);
  float* yout = ybuf + tokbase + row;

  const float* g1 = (lane < 16 ? rbuf : lane < 32 ? kf : lane < 48 ? dec : aw)
                  + tokbase + l15 * 4;
  const float* g2 = (lane < 16) ? (bw + tokbase + l15 * 4)
                                : (vbuf + tokbase + rg * 4);

  unsigned lbase = (unsigned)(uintptr_t)(__attribute__((address_space(3))) char*)ldsbuf;
  unsigned larr = lbase + (unsigned)(l15 * 16);
  unsigned lvad = lbase + 1280u + (unsigned)((lane >> 4) * 4);

#define DMAQ(T)                                                              \
  { char* sb_ = ldsbuf + (((T) & 15) << 11);                                 \
    __builtin_amdgcn_global_load_lds(                                        \
        (const __attribute__((address_space(1))) void*)g1,                   \
        (__attribute__((address_space(3))) void*)sb_, 16, 0, 0);             \
    __builtin_amdgcn_global_load_lds(                                        \
        (const __attribute__((address_space(1))) void*)g2,                   \
        (__attribute__((address_space(3))) void*)(sb_ + 1024), 16, 0, 0);    \
    g1 += CC; g2 += CC; }

#define DSRD(RR, RK, RD, RA, RB, RV, T)                                      \
  { unsigned a_ = larr + (unsigned)(((T) & 15) << 11);                       \
    unsigned v_ = lvad + (unsigned)(((T) & 15) << 11);                       \
    asm volatile("ds_read_b128 %0, %1"             : "=v"(RR) : "v"(a_));    \
    asm volatile("ds_read_b128 %0, %1 offset:256"  : "=v"(RK) : "v"(a_));    \
    asm volatile("ds_read_b128 %0, %1 offset:512"  : "=v"(RD) : "v"(a_));    \
    asm volatile("ds_read_b128 %0, %1 offset:768"  : "=v"(RA) : "v"(a_));    \
    asm volatile("ds_read_b128 %0, %1 offset:1024" : "=v"(RB) : "v"(a_));    \
    asm volatile("ds_read_b32 %0, %1"              : "=v"(RV) : "v"(v_)); }

#define WVM(N) { asm volatile("s_waitcnt vmcnt(" #N ")" ::: "memory");       \
                 __builtin_amdgcn_sched_barrier(0); }
#define WLG    { asm volatile("s_waitcnt lgkmcnt(0)" ::: "memory");          \
                 __builtin_amdgcn_sched_barrier(0); }
#define WLG6   { asm volatile("s_waitcnt lgkmcnt(6)" ::: "memory");          \
                 __builtin_amdgcn_sched_barrier(0); }

#define STEPR(RR, RK, RD, RA, RB, RV, T)                                     \
  { float sa = fmaf(S.w, RA.w, fmaf(S.z, RA.z,                               \
               fmaf(S.y, RA.y, S.x * RA.x)));                                \
    sa = red16(sa);                                                          \
    float vv = RV;                                                           \
    S.x = fmaf(S.x, RD.x, fmaf(sa, RB.x, vv * RK.x));                        \
    S.y = fmaf(S.y, RD.y, fmaf(sa, RB.y, vv * RK.y));                        \
    S.z = fmaf(S.z, RD.z, fmaf(sa, RB.z, vv * RK.z));                        \
    S.w = fmaf(S.w, RD.w, fmaf(sa, RB.w, vv * RK.w));                        \
    float y = fmaf(S.w, RR.w, fmaf(S.z, RR.z,                                \
              fmaf(S.y, RR.y, S.x * RR.x)));                                 \
    y = red16(y);                                                            \
    if (writer) yout[(size_t)(T) * CC] = y; }

  for (int tt = 0; tt < 16; ++tt) DMAQ(tt)

  f32x4 Ar, Ak, Ad, Aa, Ab; float Av;
  f32x4 Br, Bk, Bd, Ba, Bb; float Bv;

  WVM(24)
  DSRD(Ar, Ak, Ad, Aa, Ab, Av, 0)
  WLG
  DSRD(Br, Bk, Bd, Ba, Bb, Bv, 1)

  int t = 0;
  for (; t < TT - 16; t += 2) {
    DMAQ(t + 16)
    STEPR(Ar, Ak, Ad, Aa, Ab, Av, t)
    DSRD(Ar, Ak, Ad, Aa, Ab, Av, t + 2)
    WLG6
    DMAQ(t + 17)
    STEPR(Br, Bk, Bd, Ba, Bb, Bv, t + 1)
    DSRD(Br, Bk, Bd, Ba, Bb, Bv, t + 3)
    WLG6
  }
  for (; t < TT - 2; t += 2) {
    STEPR(Ar, Ak, Ad, Aa, Ab, Av, t)
    DSRD(Ar, Ak, Ad, Aa, Ab, Av, t + 2)
    WLG6
    STEPR(Br, Bk, Bd, Ba, Bb, Bv, t + 1)
    if (t + 3 < TT) DSRD(Br, Bk, Bd, Ba, Bb, Bv, t + 3)
    WLG6
  }
  STEPR(Ar, Ak, Ad, Aa, Ab, Av, TT - 2)
  WLG
  STEPR(Br, Bk, Bd, Ba, Bb, Bv, TT - 1)
#undef DMAQ
#undef DSRD
#undef WVM
#undef WLG
#undef WLG6
#undef STEPR
}

// ---------------------------------------------------------------------------
// K8: post-scan epilogue — 4-wide, red16 statistics.
// ---------------------------------------------------------------------------
__global__ __launch_bounds__(256) void k_post(
    const float* __restrict__ ybuf, const float* __restrict__ vb,
    const float* __restrict__ gvb, const float* __restrict__ bonb,
    const float* __restrict__ gnw, const float* __restrict__ gnb,
    __hip_bfloat16* __restrict__ xoh, __hip_bfloat16* __restrict__ xol) {
  int gid = blockIdx.x * 16 + (threadIdx.x >> 4);   // 0..BT*HH-1
  int l15 = threadIdx.x & 15;
  int bt = gid >> 5, h = gid & 31;
  size_t base = (size_t)bt * CC + h * 64 + l15 * 4;
  float4 y4 = *(const float4*)&ybuf[base];
  float yv[4] = {y4.x, y4.y, y4.z, y4.w};
  float s1 = yv[0] + yv[1] + yv[2] + yv[3];
  float s2 = fmaf(yv[0], yv[0], fmaf(yv[1], yv[1],
             fmaf(yv[2], yv[2], yv[3] * yv[3])));
  s1 = red16(s1);
  s2 = red16(s2);
  float mean = s1 * (1.0f / 64.0f);
  float var  = s2 * (1.0f / 64.0f) - mean * mean;
  float inv  = rsqrtf(var + GN_EPS);
  float4 gw4 = *(const float4*)&gnw[h * 64 + l15 * 4];
  float4 gb4 = *(const float4*)&gnb[h * 64 + l15 * 4];
  float4 vb4 = *(const float4*)&vb[base];
  float4 gv4 = *(const float4*)&gvb[base];
  float gw[4] = {gw4.x, gw4.y, gw4.z, gw4.w};
  float gb[4] = {gb4.x, gb4.y, gb4.z, gb4.w};
  float vbv[4] = {vb4.x, vb4.y, vb4.z, vb4.w};
  float gvv[4] = {gv4.x, gv4.y, gv4.z, gv4.w};
  float bo = bonb[bt * HH + h];
  ushort4 hv, lv;
  unsigned short* ph = (unsigned short*)&hv;
  unsigned short* pl = (unsigned short*)&lv;
#pragma unroll
  for (int j = 0; j < 4; ++j) {
    float x = fmaf((yv[j] - mean) * inv, gw[j], gb[j]) + bo * vbv[j];
    splitu(x * gvv[j], ph[j], pl[j]);
  }
  *(ushort4*)&xoh[base] = hv;
  *(ushort4*)&xol[base] = lv;
}

// ---------------------------------------------------------------------------
extern "C" void kernel_launch(void* const* d_in, const int* in_sizes, int n_in,
                              void* d_out, int out_size, void* d_ws, size_t ws_size,
                              hipStream_t stream) {
  (void)in_sizes; (void)n_in; (void)out_size; (void)ws_size;
  const float* hid    = (const float*)d_in[0];
  const float* shift  = (const float*)d_in[1];
  const float* st0    = (const float*)d_in[2];
  const float* vfirst = (const float*)d_in[3];
  const float* xrc = (const float*)d_in[4];
  const float* xwc = (const float*)d_in[5];
  const float* xkc = (const float*)d_in[6];
  const float* xvc = (const float*)d_in[7];
  const float* xac = (const float*)d_in[8];
  const float* xgc = (const float*)d_in[9];
  const float* w0  = (const float*)d_in[10];
  const float* w1  = (const float*)d_in[11];
  const float* w2  = (const float*)d_in[12];
  const float* a0  = (const float*)d_in[13];
  const float* a1  = (const float*)d_in[14];
  const float* a2  = (const float*)d_in[15];
  const float* v0  = (const float*)d_in[16];
  const float* v1  = (const float*)d_in[17];
  const float* v2  = (const float*)d_in[18];
  const float* g1  = (const float*)d_in[19];
  const float* g2  = (const float*)d_in[20];
  const float* kkc = (const float*)d_in[21];
  const float* kac = (const float*)d_in[22];
  const float* rk  = (const float*)d_in[23];
  const float* Wr  = (const float*)d_in[24];
  const float* Wk  = (const float*)d_in[25];
  const float* Wv  = (const float*)d_in[26];
  const float* Wo  = (const float*)d_in[27];
  const float* gnw = (const float*)d_in[28];
  const float* gnb = (const float*)d_in[29];
  float* out = (float*)d_out;

  char* p = (char*)d_ws;
  auto alloc = [&](size_t n) { char* q = p; p += (n + 255) & ~(size_t)255; return q; };
  const size_t EL = (size_t)BT * CC;

  // --- alias pool: xrh..xvl + Wrh,Wrl dead by k_gate time; db/awb/bwb +
  //     h2g (the old gvb slot) overlay them.
  char* pool = p;
  __hip_bfloat16* xrh = (__hip_bfloat16*)alloc(EL * 2);
  __hip_bfloat16* xrl = (__hip_bfloat16*)alloc(EL * 2);
  __hip_bfloat16* xkh = (__hip_bfloat16*)alloc(EL * 2);
  __hip_bfloat16* xkl = (__hip_bfloat16*)alloc(EL * 2);
  __hip_bfloat16* xvh = (__hip_bfloat16*)alloc(EL * 2);
  __hip_bfloat16* xvl = (__hip_bfloat16*)alloc(EL * 2);
  __hip_bfloat16* Wrh = (__hip_bfloat16*)alloc((size_t)CC * CC * 2);
  __hip_bfloat16* Wrl = (__hip_bfloat16*)alloc((size_t)CC * CC * 2);
  float* db  = (float*)pool;           // overlays xrh+xrl
  float* awb = db + EL;                // overlays xkh+xkl
  float* bwb = db + 2 * EL;            // overlays xvh+xvl
  float* h2g = db + 3 * EL;            // overlays Wrh+Wrl (old gvb slot)

  __hip_bfloat16* Wkh = (__hip_bfloat16*)alloc((size_t)CC * CC * 2);
  __hip_bfloat16* Wkl = (__hip_bfloat16*)alloc((size_t)CC * CC * 2);
  float* ybuf = (float*)Wkh;           // overlays Wkh+Wkl (dead after k-GEMM)
  float* h2v  = (float*)Wkh;           // same region, read by k_gate BEFORE scan writes ybuf

  __hip_bfloat16* Wvh = (__hip_bfloat16*)alloc((size_t)CC * CC * 2);
  __hip_bfloat16* Wvl = (__hip_bfloat16*)alloc((size_t)CC * CC * 2);
  __hip_bfloat16* Woh = (__hip_bfloat16*)alloc((size_t)CC * CC * 2);
  __hip_bfloat16* Wol = (__hip_bfloat16*)alloc((size_t)CC * CC * 2);
  __hip_bfloat16* xw  = (__hip_bfloat16*)alloc(EL * 2);
  __hip_bfloat16* xa  = (__hip_bfloat16*)alloc(EL * 2);
  __hip_bfloat16* xg  = (__hip_bfloat16*)alloc(EL * 2);
  float* h2w = (float*)xw;             // overlays xw+xa (dead after stage-1 GEMMs)
  __hip_bfloat16* w1t = (__hip_bfloat16*)alloc((size_t)64  * CC * 2);
  __hip_bfloat16* a1t = (__hip_bfloat16*)alloc((size_t)64  * CC * 2);
  __hip_bfloat16* v1t = (__hip_bfloat16*)alloc((size_t)64  * CC * 2);
  __hip_bfloat16* g1t = (__hip_bfloat16*)alloc((size_t)128 * CC * 2);
  float* rb  = (float*)alloc(EL * 4);
  float* kb  = (float*)alloc(EL * 4);  // raw k, then k_final in place
  float* vb  = (float*)alloc(EL * 4);  // raw v, then v_mix in place
  float* h1w = (float*)alloc((size_t)BT * 64  * 4);
  float* h1a = (float*)alloc((size_t)BT * 64  * 4);
  float* h1v = (float*)alloc((size_t)BT * 64  * 4);
  float* h1g = (float*)alloc((size_t)BT * 128 * 4);
  __hip_bfloat16* xoh = (__hip_bfloat16*)alloc(EL * 2);
  __hip_bfloat16* xol = (__hip_bfloat16*)alloc(EL * 2);
  float* h2a = (float*)xoh;            // overlays xoh+xol (k_post writes them AFTER k_gate)
  float* bonb = (float*)alloc((size_t)BT * HH * 4);   // per-(token,head) bonus
  // stage-2 split operands (small, fresh):
  __hip_bfloat16* h1wh = (__hip_bfloat16*)alloc((size_t)BT * 64 * 2);
  __hip_bfloat16* h1wl = (__hip_bfloat16*)alloc((size_t)BT * 64 * 2);
  __hip_bfloat16* h1ah = (__hip_bfloat16*)alloc((size_t)BT * 64 * 2);
  __hip_bfloat16* h1al = (__hip_bfloat16*)alloc((size_t)BT * 64 * 2);
  __hip_bfloat16* h1vh = (__hip_bfloat16*)alloc((size_t)BT * 64 * 2);
  __hip_bfloat16* h1vl = (__hip_bfloat16*)alloc((size_t)BT * 64 * 2);
  __hip_bfloat16* h1gh = (__hip_bfloat16*)alloc((size_t)BT * 128 * 2);
  __hip_bfloat16* h1gl = (__hip_bfloat16*)alloc((size_t)BT * 128 * 2);
  __hip_bfloat16* w2th = (__hip_bfloat16*)alloc((size_t)CC * 64 * 2);
  __hip_bfloat16* w2tl = (__hip_bfloat16*)alloc((size_t)CC * 64 * 2);
  __hip_bfloat16* a2th = (__hip_bfloat16*)alloc((size_t)CC * 64 * 2);
  __hip_bfloat16* a2tl = (__hip_bfloat16*)alloc((size_t)CC * 64 * 2);
  __hip_bfloat16* v2th = (__hip_bfloat16*)alloc((size_t)CC * 64 * 2);
  __hip_bfloat16* v2tl = (__hip_bfloat16*)alloc((size_t)CC * 64 * 2);
  __hip_bfloat16* g2th = (__hip_bfloat16*)alloc((size_t)CC * 128 * 2);
  __hip_bfloat16* g2tl = (__hip_bfloat16*)alloc((size_t)CC * 128 * 2);
  // total ~210 MiB (known-OK envelope: 220 OK, 268 crashed)

  k_prepx<<<4096, 256, 0, stream>>>(hid, shift, xrc, xwc, xkc, xvc, xac, xgc,
                                    xrh, xrl, xw, xkh, xkl, xvh, xvl, xa, xg);
  k_cvt2x4<<<dim3(4096, 4), 256, 0, stream>>>(Wr, Wk, Wv, Wo,
                                              Wrh, Wrl, Wkh, Wkl,
                                              Wvh, Wvl, Woh, Wol);
  k_tr4<<<dim3(1024, 4), 256, 0, stream>>>(w1, a1, v1, g1, w1t, a1t, v1t, g1t);
  k_trs4<<<dim3(1024, 4), 256, 0, stream>>>(w2, a2, v2, g2,
                                            w2th, w2tl, a2th, a2tl,
                                            v2th, v2tl, g2th, g2tl);

  k_gemm_big3<<<dim3(32, 16, 3), 256, 0, stream>>>(
      xrh, xrl, Wrh, Wrl, rb,
      xkh, xkl, Wkh, Wkl, kb,
      xvh, xvl, Wvh, Wvl, vb);
  k_lora1<<<dim3(32, 5), 256, 0, stream>>>(xw, xa, xvh, xg, w1t, a1t, v1t, g1t,
                                           h1w, h1a, h1v, h1g);

  k_act2<<<256, 256, 0, stream>>>(h1w, h1a, h1v, h1g,
                                  h1wh, h1wl, h1ah, h1al,
                                  h1vh, h1vl, h1gh, h1gl);
  // stage-2 LoRA dots on MFMA (split precision), fused 4-in-1. Overlays:
  //   h2w->xw+xa, h2a->xoh+xol, h2v->Wkh+Wkl, h2g->Wrh+Wrl.
  k_gemm_s2x4<<<dim3(32, 16, 4), 256, 0, stream>>>(
      h1wh, h1wl, h1ah, h1al, h1vh, h1vl, h1gh, h1gl,
      w2th, w2tl, a2th, a2tl, v2th, v2tl, g2th, g2tl,
      h2w, h2a, h2v, h2g);

  k_gate<<<4096, 256, 0, stream>>>(h2w, h2a, h2v, w0, a0, v0, kkc, kac,
                                   kb, vb, vfirst, rb, rk, db, awb, bwb, bonb);
  k_scan<<<1024, 64, 0, stream>>>(rb, kb, db, awb, bwb, vb, st0, ybuf);
  k_post<<<4096, 256, 0, stream>>>(ybuf, vb, h2g, bonb, gnw, gnb, xoh, xol);
  k_gemm_bt3<<<dim3(32, 16), 256, 0, stream>>>(xoh, xol, Woh, Wol, out, BT, CC, CC);
}